// Round 13
// baseline (1448.465 us; speedup 1.0000x reference)
//
#include <hip/hip_runtime.h>
#include <hip/hip_bf16.h>

typedef __hip_bfloat16 bf16;
typedef __attribute__((ext_vector_type(8))) short short8v;
typedef __attribute__((ext_vector_type(4))) float float4v;

#define NCONS 50000
#define NVARS 50000
#define NEDGE 600000

__device__ __forceinline__ float b2f(const bf16 v){ return __bfloat162float(v); }
__device__ __forceinline__ float shflf(float v, int lane){ return __shfl(v, lane, 64); }
__device__ __forceinline__ unsigned short f2b(float v){
  return __builtin_bit_cast(unsigned short, __float2bfloat16(v));
}

// ---- input-dtype sniffer (bf16 pairs vs f32) ----
__global__ void detect_k(const unsigned int* __restrict__ x, int* __restrict__ mode){
  int t = threadIdx.x;
  int hits = 0;
  for (int i=0;i<4;++i){
    unsigned w = x[t*4+i];
    unsigned e = (w>>7)&0xFFu;
    if (e >= 0x70u && e <= 0x8Fu) hits++;
  }
  for (int off=32; off>0; off>>=1) hits += __shfl_down(hits, off);
  if (t==0) *mode = (hits > 128) ? 1 : 0;
}

// ---- convert ALL 36 float inputs to f32 workspace in one launch ----
struct CvtArgs { const void* p[36]; int ofs[37]; };
__global__ void convert_all_k(CvtArgs a, float* __restrict__ dst, const int* __restrict__ mode){
  int m = *mode;
  int i = blockIdx.x*blockDim.x + threadIdx.x;
  int stride = gridDim.x*blockDim.x;
  int total = a.ofs[36];
  for (; i<total; i+=stride){
    int s = 0;
#pragma unroll
    for (int k=1;k<36;++k) s += (i >= a.ofs[k]) ? 1 : 0;
    int off = i - a.ofs[s];
    float v;
    if (m) v = b2f(((const bf16*)a.p[s])[off]);
    else   v = ((const float*)a.p[s])[off];
    dst[i] = v;
  }
}

__global__ void zero_k(float* __restrict__ p, int n){
  int i = blockIdx.x*blockDim.x + threadIdx.x;
  int stride = gridDim.x*blockDim.x;
  for (; i<n; i+=stride) p[i] = 0.f;
}

// ---- CSR build: histogram, single-block scan (cnt becomes cursor), scatter ----
__global__ void hist_k(const int* __restrict__ ei, int* __restrict__ cntc, int* __restrict__ cntv){
  int i = blockIdx.x*blockDim.x + threadIdx.x;
  int stride = gridDim.x*blockDim.x;
  for (; i<2*NEDGE; i+=stride){
    int id = ei[i];
    if (i < NEDGE) atomicAdd(&cntc[id], 1);
    else           atomicAdd(&cntv[id], 1);
  }
}

__global__ void __launch_bounds__(1024) scan_k(int* __restrict__ cnt, int* __restrict__ offs, int n){
  __shared__ int part[1024];
  int t = threadIdx.x;
  int chunk = (n + 1023) >> 10;
  int b = t*chunk;
  int e = b + chunk; if (e > n) e = n;
  int s = 0;
  for (int i=b; i<e; ++i) s += cnt[i];
  part[t] = s;
  __syncthreads();
  for (int off=1; off<1024; off<<=1){
    int v = (t >= off) ? part[t-off] : 0;
    __syncthreads();
    part[t] += v;
    __syncthreads();
  }
  int run = (t==0) ? 0 : part[t-1];
  for (int i=b; i<e; ++i){
    int c = cnt[i];
    offs[i] = run; cnt[i] = run;   // cnt becomes cursor
    run += c;
  }
  if (t==1023) offs[n] = part[1023];
}

// scatter: write dst-sorted src ids and dst-sorted bf16 edge attrs directly
__global__ void scat_k(const int* __restrict__ ei, const float* __restrict__ ea,
                       int* __restrict__ curc, int* __restrict__ curv,
                       int* __restrict__ srtc, int* __restrict__ srtv,
                       bf16* __restrict__ eac, bf16* __restrict__ eav){
  int i = blockIdx.x*blockDim.x + threadIdx.x;
  int stride = gridDim.x*blockDim.x;
  for (; i<2*NEDGE; i+=stride){
    int id = ei[i];
    if (i < NEDGE){
      int p = atomicAdd(&curc[id],1);
      srtc[p] = ei[NEDGE+i];                 // variable endpoint
      eac[p] = __float2bfloat16(ea[i]);
    } else {
      int e = i - NEDGE;
      int p = atomicAdd(&curv[id],1);
      srtv[p] = ei[e];                       // constraint endpoint
      eav[p] = __float2bfloat16(ea[e]);
    }
  }
}

// ---- per-column sums / sumsq for BN folding ----
__global__ void col_stats_k(const float* __restrict__ x, int rows, int cols, float* __restrict__ sums){
  int tid = blockIdx.x*blockDim.x + threadIdx.x;
  int stride = gridDim.x*blockDim.x;
  float s[5], ss[5];
  for (int c=0;c<5;++c){ s[c]=0.f; ss[c]=0.f; }
  for (int r=tid; r<rows; r+=stride){
    for (int c=0;c<cols;++c){
      float v = x[r*cols+c];
      s[c]+=v; ss[c]+=v*v;
    }
  }
  for (int c=0;c<cols;++c){
    float a=s[c], b=ss[c];
    for (int off=32; off>0; off>>=1){ a+=__shfl_down(a,off); b+=__shfl_down(b,off); }
    if ((threadIdx.x & 63)==0){ atomicAdd(&sums[c],a); atomicAdd(&sums[cols+c],b); }
  }
}

// stats float layout in ST (floats): see round-5 comment (unchanged)
__global__ void fin_input_k(float* __restrict__ st,
                            const float* __restrict__ cw, const float* __restrict__ cb,
                            const float* __restrict__ vw, const float* __restrict__ vb,
                            const float* __restrict__ ew, const float* __restrict__ eb){
  int t = threadIdx.x;
  if (t < 3){
    float m = st[t]/(float)NCONS, q = st[3+t]/(float)NCONS;
    float A = rsqrtf(fmaxf(q - m*m, 0.f) + 1e-5f)*cw[t];
    st[18+t] = A; st[21+t] = cb[t] - m*A;
  } else if (t < 8){
    int c = t-3;
    float m = st[6+c]/(float)NVARS, q = st[11+c]/(float)NVARS;
    float A = rsqrtf(fmaxf(q - m*m, 0.f) + 1e-5f)*vw[c];
    st[24+c] = A; st[29+c] = vb[c] - m*A;
  } else if (t == 8){
    float m = st[16]/(float)NEDGE, q = st[17]/(float)NEDGE;
    float A = rsqrtf(fmaxf(q - m*m, 0.f) + 1e-5f)*ew[0];
    st[34] = A; st[35] = eb[0] - m*A;
  }
}

// ---- merged embedding for BOTH node sets: one wave = one node-job ----
__global__ void embed2_k(const float* __restrict__ xc, const float* __restrict__ xv,
                         const float* __restrict__ st,
                         const float* __restrict__ cW1, const float* __restrict__ cb1,
                         const float* __restrict__ cW2, const float* __restrict__ cb2,
                         const float* __restrict__ vW1, const float* __restrict__ vb1,
                         const float* __restrict__ vW2, const float* __restrict__ vb2,
                         bf16* __restrict__ outc, bf16* __restrict__ outv){
  int t = threadIdx.x & 63;
  int w = (blockIdx.x*blockDim.x + threadIdx.x) >> 6;
  int nw = (gridDim.x*blockDim.x) >> 6;
  for (int j = w; j < NCONS + NVARS; j += nw){
    bool isv = (j >= NCONS);
    int n = isv ? j - NCONS : j;
    const float* x  = isv ? xv : xc;
    int cin         = isv ? 5 : 3;
    const float* pA = isv ? st+24 : st+18;
    const float* pB = isv ? st+29 : st+21;
    const float* W1 = isv ? vW1 : cW1;
    const float* b1 = isv ? vb1 : cb1;
    const float* W2 = isv ? vW2 : cW2;
    const float* b2 = isv ? vb2 : cb2;
    bf16* out       = isv ? outv : outc;
    float acc = b1[t];
    for (int k=0;k<cin;++k){
      float xb = x[n*cin+k]*pA[k] + pB[k];
      acc += xb*W1[k*64+t];
    }
    float h1 = fmaxf(acc, 0.f);
    float acc2 = b2[t];
#pragma unroll
    for (int j2=0;j2<64;++j2) acc2 += shflf(h1,j2)*W2[j2*64+t];
    out[n*64+t] = __float2bfloat16(fmaxf(acc2, 0.f));
  }
}

// ---- all 16 conv-weight fragment jobs in one launch ----
__global__ void frag_all_k(const float* __restrict__ fmW1, const float* __restrict__ fmW2,
                           const float* __restrict__ omW1, const float* __restrict__ omW2,
                           unsigned short* __restrict__ W1Fb, unsigned short* __restrict__ W2Fb,
                           unsigned short* __restrict__ OW1Fb, unsigned short* __restrict__ OW2Fb){
  int i = blockIdx.x*blockDim.x + threadIdx.x;
  if (i >= 4*24576) return;
  int l = i / 24576, r = i % 24576;
  const float* src; unsigned short* dst; int e; int skip;
  if (r < 8192){       src = fmW1 + (size_t)l*129*64; dst = W1Fb  + l*8192; e = r;       skip = 64; }
  else if (r < 12288){ src = fmW2 + (size_t)l*64*64;  dst = W2Fb  + l*4096; e = r-8192;  skip = -1; }
  else if (r < 20480){ src = omW1 + (size_t)l*128*64; dst = OW1Fb + l*8192; e = r-12288; skip = -1; }
  else {               src = omW2 + (size_t)l*64*64;  dst = OW2Fb + l*4096; e = r-20480; skip = -1; }
  int j = e & 7, lane = (e>>3)&63, n = (e>>9)&3, kc = e>>11;
  int k = kc*32 + (lane>>4)*8 + j;
  int col = n*16 + (lane&15);
  int srcrow = (skip>=0 && k>=skip) ? k+1 : k;
  dst[e] = f2b(src[srcrow*64 + col]);
}

// ---- hi/lo fragmenter for final-MLP weights ----
__global__ void frag2_k(const float* __restrict__ Wsrc, unsigned short* __restrict__ Whi,
                        unsigned short* __restrict__ Wlo, int ntiles, int ncols, int tot){
  int i = blockIdx.x*blockDim.x + threadIdx.x;
  if (i>=tot) return;
  int j = i & 7, lane = (i>>3)&63, rem = i>>9;
  int nt = rem % ntiles, kc = rem / ntiles;
  int k = kc*32 + (lane>>4)*8 + j;
  int col = nt*16 + (lane&15);
  float w = Wsrc[k*ncols + col];
  unsigned short hi = f2b(w);
  float rec = __builtin_bit_cast(float, (unsigned int)hi << 16);
  Whi[i] = hi;
  Wlo[i] = f2b(w - rec);
}

// ---- CSR MFMA layer-1 edge kernel: S[node] = mean_e relu(h1_e).
// W2 factored OUT of the edge loop (linear through the mean). No LDS
// roundtrip, no W2 MFMAs per edge, no atomics. ----
__global__ void __launch_bounds__(256) msg_csr_k(
    const bf16* __restrict__ left, const bf16* __restrict__ right,
    const int* __restrict__ srt, const bf16* __restrict__ eas,
    const float* __restrict__ est, const int* __restrict__ offs,
    const unsigned short* __restrict__ W1F,
    const float* __restrict__ b1, const float* __restrict__ w1e,
    float* __restrict__ S, int nn)
{
  __shared__ __align__(16) unsigned short w1l[8192];
  {
    const float4* s1 = (const float4*)W1F; float4* d1 = (float4*)w1l;
    for (int i=threadIdx.x; i<1024; i+=256) d1[i] = s1[i];
  }
  __syncthreads();
  const short8v* W1v = (const short8v*)w1l;
  const unsigned short* rgt = (const unsigned short*)right;
  const unsigned short* lft = (const unsigned short*)left;
  int t = threadIdx.x & 63;
  int gw = (blockIdx.x*blockDim.x + threadIdx.x) >> 6;
  int nw = (gridDim.x*blockDim.x) >> 6;
  int r16 = t & 15, kg = t >> 4;
  float eA = est[0], eB = est[1];
  float bb1[4], we[4];
#pragma unroll
  for (int n=0;n<4;++n){ bb1[n]=b1[n*16+r16]; we[n]=w1e[n*16+r16]; }

  int chunk = (nn + nw - 1) / nw;
  int nbeg = gw * chunk;
  int nend = nbeg + chunk; if (nend > nn) nend = nn;

  for (int node = nbeg; node < nend; ++node){
    int beg = offs[node], end = offs[node+1];
    int deg = end - beg;
    float4v acc[4];
#pragma unroll
    for (int n=0;n<4;++n) acc[n] = (float4v){0.f,0.f,0.f,0.f};
    if (deg > 0){
      short8v rr0 = *(const short8v*)(rgt + (size_t)node*64 + kg*8);
      short8v rr1 = *(const short8v*)(rgt + (size_t)node*64 + 32 + kg*8);
      float4v crt[4];
#pragma unroll
      for (int n=0;n<4;++n) crt[n] = (float4v){bb1[n],bb1[n],bb1[n],bb1[n]};
#pragma unroll
      for (int n=0;n<4;++n){
        crt[n] = __builtin_amdgcn_mfma_f32_16x16x32_bf16(rr0, W1v[(0+n)*64+t], crt[n], 0,0,0);
        crt[n] = __builtin_amdgcn_mfma_f32_16x16x32_bf16(rr1, W1v[(4+n)*64+t], crt[n], 0,0,0);
      }
      for (int base = beg; base < end; base += 16){
        int idx = base + r16;
        int ic = idx < end ? idx : beg;
        int sI = srt[ic];
        float ef = b2f(eas[ic])*eA + eB;
        short8v al0 = *(const short8v*)(lft + (size_t)sI*64 + kg*8);
        short8v al1 = *(const short8v*)(lft + (size_t)sI*64 + 32 + kg*8);
        float efr[4];
#pragma unroll
        for (int r=0;r<4;++r) efr[r] = shflf(ef, kg*4+r);
        float4v c[4];
#pragma unroll
        for (int n=0;n<4;++n){
#pragma unroll
          for (int r=0;r<4;++r) c[n][r] = crt[n][r] + efr[r]*we[n];
        }
#pragma unroll
        for (int n=0;n<4;++n){
          c[n] = __builtin_amdgcn_mfma_f32_16x16x32_bf16(al0, W1v[( 8+n)*64+t], c[n], 0,0,0);
          c[n] = __builtin_amdgcn_mfma_f32_16x16x32_bf16(al1, W1v[(12+n)*64+t], c[n], 0,0,0);
        }
        // relu + masked accumulate (row kg*4+r is edge base+kg*4+r)
#pragma unroll
        for (int r=0;r<4;++r){
          float mrow = (base + kg*4 + r < end) ? 1.f : 0.f;
#pragma unroll
          for (int n=0;n<4;++n) acc[n][r] += mrow * fmaxf(c[n][r], 0.f);
        }
      }
    }
    float tot[4];
#pragma unroll
    for (int n=0;n<4;++n){
      tot[n] = acc[n][0]+acc[n][1]+acc[n][2]+acc[n][3];
      tot[n] += __shfl_xor(tot[n], 16, 64);
      tot[n] += __shfl_xor(tot[n], 32, 64);
    }
    if (kg == 0){
      float inv = (deg>0) ? 1.f/(float)deg : 0.f;
#pragma unroll
      for (int n=0;n<4;++n)
        S[(size_t)node*64 + n*16 + r16] = tot[n]*inv;   // 0 for deg==0
    }
  }
}

// ---- AGG = S @ W2 + b2 (in place), deg-0 rows -> 0, fused BN column stats ----
__global__ void __launch_bounds__(256) agg2_k(
    float* __restrict__ AGG, const int* __restrict__ offs,
    const unsigned short* __restrict__ W2F, const float* __restrict__ b2,
    float* __restrict__ slot, int nn)
{
  __shared__ __align__(16) unsigned short w2l[4096];
  __shared__ float bstat[128];
  {
    const float4* s2 = (const float4*)W2F; float4* d2 = (float4*)w2l;
    for (int i=threadIdx.x; i<512; i+=256) d2[i] = s2[i];
    if (threadIdx.x < 128) bstat[threadIdx.x] = 0.f;
  }
  __syncthreads();
  const short8v* W2v = (const short8v*)w2l;
  int t = threadIdx.x & 63;
  int gw = (blockIdx.x*blockDim.x + threadIdx.x) >> 6;
  int nw = (gridDim.x*blockDim.x) >> 6;
  int r16 = t & 15, kg = t >> 4;
  float bb2[4];
#pragma unroll
  for (int n=0;n<4;++n) bb2[n]=b2[n*16+r16];
  float sacc[4] = {0.f,0.f,0.f,0.f}, ssacc[4] = {0.f,0.f,0.f,0.f};

  for (int g = gw*16; g < nn; g += nw*16){
    int node = g + r16;
    int deg = offs[node+1] - offs[node];
    const float* sp = AGG + (size_t)node*64;
    float4 f0 = *(const float4*)(sp + kg*8);
    float4 f1 = *(const float4*)(sp + kg*8 + 4);
    float4 f2 = *(const float4*)(sp + 32 + kg*8);
    float4 f3 = *(const float4*)(sp + 32 + kg*8 + 4);
    float v0[8] = {f0.x,f0.y,f0.z,f0.w,f1.x,f1.y,f1.z,f1.w};
    float v1[8] = {f2.x,f2.y,f2.z,f2.w,f3.x,f3.y,f3.z,f3.w};
    short8v ap0, ap1;
#pragma unroll
    for (int j=0;j<8;++j){
      ((unsigned short*)&ap0)[j] = f2b(v0[j]);
      ((unsigned short*)&ap1)[j] = f2b(v1[j]);
    }
    float4v c[4];
#pragma unroll
    for (int n=0;n<4;++n) c[n] = (float4v){bb2[n],bb2[n],bb2[n],bb2[n]};
#pragma unroll
    for (int n=0;n<4;++n){
      c[n] = __builtin_amdgcn_mfma_f32_16x16x32_bf16(ap0, W2v[(0+n)*64+t], c[n], 0,0,0);
      c[n] = __builtin_amdgcn_mfma_f32_16x16x32_bf16(ap1, W2v[(4+n)*64+t], c[n], 0,0,0);
    }
#pragma unroll
    for (int r=0;r<4;++r){
      int degr = __shfl(deg, kg*4+r, 64);
      size_t base = (size_t)(g + kg*4 + r)*64 + r16;
#pragma unroll
      for (int n=0;n<4;++n){
        float val = (degr>0) ? c[n][r] : 0.f;   // PyG: mean of empty = 0
        AGG[base + n*16] = val;
        sacc[n] += val; ssacc[n] += val*val;
      }
    }
  }
#pragma unroll
  for (int n=0;n<4;++n){
    atomicAdd(&bstat[n*16+r16], sacc[n]);
    atomicAdd(&bstat[64+n*16+r16], ssacc[n]);
  }
  __syncthreads();
  if (threadIdx.x < 128) atomicAdd(&slot[threadIdx.x], bstat[threadIdx.x]);
}

__global__ void fin_bn_k(float* __restrict__ slot, const float* __restrict__ w,
                         const float* __restrict__ b, float n){
  int c = threadIdx.x;
  float m = slot[c]/n, q = slot[64+c]/n;
  float rs = rsqrtf(fmaxf(q - m*m, 0.f) + 1e-5f) * w[c];
  slot[128+c] = rs;
  slot[192+c] = b[c] - m*rs;
}

// ---- MFMA node-output MLP + fused GraphNorm column stats. ----
__global__ void __launch_bounds__(256) node_mfma_k(
    const float* __restrict__ agg, const bf16* __restrict__ right,
    const float* __restrict__ slot,
    const unsigned short* __restrict__ W1F, const unsigned short* __restrict__ W2F,
    const float* __restrict__ b1, const float* __restrict__ b2,
    bf16* __restrict__ out, float* __restrict__ gslot, int nn)
{
  __shared__ __align__(16) unsigned short w1l[8192];
  __shared__ __align__(16) unsigned short w2l[4096];
  __shared__ __align__(16) unsigned short h1l[4][16*72];
  __shared__ float bstat[128];
  {
    const float4* s1 = (const float4*)W1F; float4* d1 = (float4*)w1l;
    for (int i=threadIdx.x; i<1024; i+=256) d1[i] = s1[i];
    const float4* s2 = (const float4*)W2F; float4* d2 = (float4*)w2l;
    for (int i=threadIdx.x; i<512; i+=256) d2[i] = s2[i];
    if (threadIdx.x < 128) bstat[threadIdx.x] = 0.f;
  }
  __syncthreads();
  const short8v* W1v = (const short8v*)w1l;
  const short8v* W2v = (const short8v*)w2l;
  const unsigned short* rgt = (const unsigned short*)right;
  int t = threadIdx.x & 63;
  int wv = threadIdx.x >> 6;
  int gw = (blockIdx.x*blockDim.x + threadIdx.x) >> 6;
  int nw = (gridDim.x*blockDim.x) >> 6;
  int r16 = t & 15, kg = t >> 4;
  float pA0[8], pB0[8], pA1[8], pB1[8];
#pragma unroll
  for (int j=0;j<8;++j){
    pA0[j]=slot[128+kg*8+j]; pB0[j]=slot[192+kg*8+j];
    pA1[j]=slot[160+kg*8+j]; pB1[j]=slot[224+kg*8+j];
  }
  float bb1[4], bb2[4];
#pragma unroll
  for (int n=0;n<4;++n){ bb1[n]=b1[n*16+r16]; bb2[n]=b2[n*16+r16]; }
  unsigned short* h1w = &h1l[wv][0];
  float sacc[4] = {0.f,0.f,0.f,0.f}, ssacc[4] = {0.f,0.f,0.f,0.f};

  for (int g = gw*16; g < nn; g += nw*16){
    int node = g + r16;
    const float* ag = agg + (size_t)node*64;
    float4 f0 = *(const float4*)(ag + kg*8);
    float4 f1 = *(const float4*)(ag + kg*8 + 4);
    float4 f2 = *(const float4*)(ag + 32 + kg*8);
    float4 f3 = *(const float4*)(ag + 32 + kg*8 + 4);
    float v0[8] = {f0.x,f0.y,f0.z,f0.w,f1.x,f1.y,f1.z,f1.w};
    float v1[8] = {f2.x,f2.y,f2.z,f2.w,f3.x,f3.y,f3.z,f3.w};
    short8v ap0, ap1;
#pragma unroll
    for (int j=0;j<8;++j){
      ((unsigned short*)&ap0)[j] = f2b(v0[j]*pA0[j] + pB0[j]);
      ((unsigned short*)&ap1)[j] = f2b(v1[j]*pA1[j] + pB1[j]);
    }
    short8v ar0 = *(const short8v*)(rgt + (size_t)node*64 + kg*8);
    short8v ar1 = *(const short8v*)(rgt + (size_t)node*64 + 32 + kg*8);
    float4v c[4];
#pragma unroll
    for (int n=0;n<4;++n) c[n] = (float4v){bb1[n],bb1[n],bb1[n],bb1[n]};
#pragma unroll
    for (int n=0;n<4;++n){
      c[n] = __builtin_amdgcn_mfma_f32_16x16x32_bf16(ap0, W1v[( 0+n)*64+t], c[n], 0,0,0);
      c[n] = __builtin_amdgcn_mfma_f32_16x16x32_bf16(ap1, W1v[( 4+n)*64+t], c[n], 0,0,0);
      c[n] = __builtin_amdgcn_mfma_f32_16x16x32_bf16(ar0, W1v[( 8+n)*64+t], c[n], 0,0,0);
      c[n] = __builtin_amdgcn_mfma_f32_16x16x32_bf16(ar1, W1v[(12+n)*64+t], c[n], 0,0,0);
    }
#pragma unroll
    for (int n=0;n<4;++n){
#pragma unroll
      for (int r=0;r<4;++r)
        h1w[(kg*4+r)*72 + n*16 + r16] = f2b(fmaxf(c[n][r], 0.f));
    }
    asm volatile("s_waitcnt lgkmcnt(0)" ::: "memory");
    __builtin_amdgcn_sched_barrier(0);
    short8v a20 = *(const short8v*)(h1w + r16*72 + kg*8);
    short8v a21 = *(const short8v*)(h1w + r16*72 + 32 + kg*8);
    float4v d[4];
#pragma unroll
    for (int n=0;n<4;++n) d[n] = (float4v){bb2[n],bb2[n],bb2[n],bb2[n]};
#pragma unroll
    for (int n=0;n<4;++n){
      d[n] = __builtin_amdgcn_mfma_f32_16x16x32_bf16(a20, W2v[(0+n)*64+t], d[n], 0,0,0);
      d[n] = __builtin_amdgcn_mfma_f32_16x16x32_bf16(a21, W2v[(4+n)*64+t], d[n], 0,0,0);
    }
    unsigned short* op = (unsigned short*)out;
#pragma unroll
    for (int r=0;r<4;++r){
      size_t base = (size_t)(g + kg*4 + r)*64 + r16;
#pragma unroll
      for (int n=0;n<4;++n){
        float val = d[n][r];
        op[base + n*16] = f2b(val);
        sacc[n] += val; ssacc[n] += val*val;
      }
    }
  }
#pragma unroll
  for (int n=0;n<4;++n){
    atomicAdd(&bstat[n*16+r16], sacc[n]);
    atomicAdd(&bstat[64+n*16+r16], ssacc[n]);
  }
  __syncthreads();
  if (threadIdx.x < 128) atomicAdd(&gslot[threadIdx.x], bstat[threadIdx.x]);
}

// ---- merged graphnorm finalize (both slots) and apply (both buffers) ----
__global__ void fin_gn2_k(float* __restrict__ sA, float* __restrict__ sB,
                          const float* __restrict__ w, const float* __restrict__ b,
                          const float* __restrict__ al, int ga, int gb, float n){
  int t = threadIdx.x; if (t >= 128) return;
  float* slot = (t < 64) ? sA : sB;
  int g = (t < 64) ? ga : gb;
  int c = t & 63;
  float m = slot[c]/n, q = slot[64+c]/n;
  float a = al[g*64+c];
  float var = q - 2.f*a*m*m + a*a*m*m;
  float A = rsqrtf(fmaxf(var, 0.f) + 1e-5f) * w[g*64+c];
  slot[128+c] = A;
  slot[192+c] = b[g*64+c] - a*m*A;
}

__global__ void affine2_k(bf16* __restrict__ x1, const float* __restrict__ s1,
                          bf16* __restrict__ x2, const float* __restrict__ s2, int nn){
  int i = blockIdx.x*blockDim.x + threadIdx.x;
  int stride = gridDim.x*blockDim.x;
  int tot = nn*64;
  for (; i<2*tot; i+=stride){
    if (i < tot){
      int c = i & 63;
      x1[i] = __float2bfloat16(b2f(x1[i])*s1[128+c] + s1[192+c]);
    } else {
      int j = i - tot;
      int c = j & 63;
      x2[j] = __float2bfloat16(b2f(x2[j])*s2[128+c] + s2[192+c]);
    }
  }
}

// ---- MFMA final MLP, race-free (one 16-node tile per wave, __syncthreads) ----
__global__ void __launch_bounds__(256) final_mfma_k(
    const bf16* __restrict__ vf0, const bf16* __restrict__ vf1, const bf16* __restrict__ vf2,
    const unsigned short* __restrict__ W1hi, const unsigned short* __restrict__ W1lo,
    const unsigned short* __restrict__ W2hi, const unsigned short* __restrict__ W2lo,
    const float* __restrict__ B1, const float* __restrict__ B2,
    const float* __restrict__ W3, const float* __restrict__ B3,
    void* __restrict__ out, int nn, const int* __restrict__ mode)
{
  __shared__ float h1l[4][16*260];
  const short8v* W1h = (const short8v*)W1hi;
  const short8v* W1l = (const short8v*)W1lo;
  const short8v* W2h = (const short8v*)W2hi;
  const short8v* W2l = (const short8v*)W2lo;
  const unsigned short* v0p = (const unsigned short*)vf0;
  const unsigned short* v1p = (const unsigned short*)vf1;
  const unsigned short* v2p = (const unsigned short*)vf2;
  int t = threadIdx.x & 63;
  int wv = threadIdx.x >> 6;
  int r16 = t & 15, kg = t >> 4;
  int tile = blockIdx.x*4 + wv;
  bool act = (tile*16 < nn);
  int g = act ? tile*16 : 0;
  float* h1w = &h1l[wv][0];
  float b2v[8], w3v[8];
#pragma unroll
  for (int n=0;n<8;++n){ b2v[n] = B2[n*16+r16]; w3v[n] = W3[n*16+r16]; }
  float bb3 = B3[0];
  int md = *mode;

  int node = g + r16;
  short8v A1[6];
  A1[0] = *(const short8v*)(v0p + (size_t)node*64 + kg*8);
  A1[1] = *(const short8v*)(v0p + (size_t)node*64 + 32 + kg*8);
  A1[2] = *(const short8v*)(v1p + (size_t)node*64 + kg*8);
  A1[3] = *(const short8v*)(v1p + (size_t)node*64 + 32 + kg*8);
  A1[4] = *(const short8v*)(v2p + (size_t)node*64 + kg*8);
  A1[5] = *(const short8v*)(v2p + (size_t)node*64 + 32 + kg*8);
  float4v D[8];
#pragma unroll
  for (int n=0;n<8;++n) D[n] = (float4v){b2v[n],b2v[n],b2v[n],b2v[n]};

  for (int half=0; half<2; ++half){
    if (half) __syncthreads();
    for (int nt=0; nt<16; ++nt){
      int ntg = half*16 + nt;
      float bb = B1[ntg*16 + r16];
      float4v C = (float4v){bb,bb,bb,bb};
#pragma unroll
      for (int kc=0; kc<6; ++kc){
        C = __builtin_amdgcn_mfma_f32_16x16x32_bf16(A1[kc], W1h[(kc*32+ntg)*64+t], C, 0,0,0);
        C = __builtin_amdgcn_mfma_f32_16x16x32_bf16(A1[kc], W1l[(kc*32+ntg)*64+t], C, 0,0,0);
      }
#pragma unroll
      for (int r=0;r<4;++r)
        h1w[(kg*4+r)*260 + nt*16 + r16] = fmaxf(C[r], 0.f);
    }
    __syncthreads();
    short8v Ahi[8], Alo[8];
#pragma unroll
    for (int kc=0; kc<8; ++kc){
      const float* hp = h1w + r16*260 + kc*32 + kg*8;
      float4 x0 = *(const float4*)(hp);
      float4 x1 = *(const float4*)(hp+4);
      float vv[8] = {x0.x,x0.y,x0.z,x0.w,x1.x,x1.y,x1.z,x1.w};
#pragma unroll
      for (int j=0;j<8;++j){
        unsigned short hi = f2b(vv[j]);
        float rec = __builtin_bit_cast(float, (unsigned int)hi<<16);
        ((unsigned short*)&Ahi[kc])[j] = hi;
        ((unsigned short*)&Alo[kc])[j] = f2b(vv[j] - rec);
      }
    }
#pragma unroll
    for (int nt2=0; nt2<8; ++nt2){
#pragma unroll
      for (int kc=0; kc<8; ++kc){
        int kcg = half*8 + kc;
        short8v bh = W2h[(kcg*8+nt2)*64+t];
        D[nt2] = __builtin_amdgcn_mfma_f32_16x16x32_bf16(Ahi[kc], bh, D[nt2], 0,0,0);
        D[nt2] = __builtin_amdgcn_mfma_f32_16x16x32_bf16(Alo[kc], bh, D[nt2], 0,0,0);
        D[nt2] = __builtin_amdgcn_mfma_f32_16x16x32_bf16(Ahi[kc], W2l[(kcg*8+nt2)*64+t], D[nt2], 0,0,0);
      }
    }
  }
  float part[4] = {0.f,0.f,0.f,0.f};
#pragma unroll
  for (int n=0;n<8;++n){
#pragma unroll
    for (int r=0;r<4;++r) part[r] += fmaxf(D[n][r],0.f)*w3v[n];
  }
#pragma unroll
  for (int r=0;r<4;++r){
#pragma unroll
    for (int off=1; off<16; off<<=1) part[r] += __shfl_xor(part[r], off, 64);
  }
  if (act && r16==0){
#pragma unroll
    for (int r=0;r<4;++r){
      int node_o = g + kg*4 + r;
      float val = part[r] + bb3;
      if (md) ((bf16*)out)[node_o] = __float2bfloat16(val);
      else    ((float*)out)[node_o] = val;
    }
  }
}

extern "C" void kernel_launch(void* const* d_in, const int* in_sizes, int n_in,
                              void* d_out, int out_size, void* d_ws, size_t ws_size,
                              hipStream_t stream){
  const int* ei = (const int*)d_in[36];

  char* ws = (char*)d_ws;
  float* ST = (float*)ws;                       // 4096 floats = 16 KB
  int* MODE = (int*)(ws + 16384);
  float* FBASE = (float*)(ws + 32768);
  CvtArgs ca;
  float* F[36];
  {
    int off = 0;
    for (int i=0;i<36;++i){
      ca.p[i] = d_in[i];
      ca.ofs[i] = off;
      F[i] = FBASE + off;
      off += in_sizes[i];
    }
    ca.ofs[36] = off;
  }
  unsigned short* W1Fb  = (unsigned short*)(ws + 7u*1024*1024);
  unsigned short* W2Fb  = W1Fb + 4*8192;
  unsigned short* OW1Fb = W2Fb + 4*4096;
  unsigned short* OW2Fb = OW1Fb + 4*8192;
  unsigned short* FW1H  = OW2Fb + 4*4096;
  unsigned short* FW1L  = FW1H + 98304;
  unsigned short* FW2H  = FW1L + 98304;
  unsigned short* FW2L  = FW2H + 65536;
  size_t o = 8u*1024*1024;
  float* AGG = (float*)(ws + o); o += (size_t)NCONS*64*sizeof(float);
  bf16* CFA = (bf16*)(ws + o); o += (size_t)NCONS*64*sizeof(bf16);
  bf16* CFB = (bf16*)(ws + o); o += (size_t)NCONS*64*sizeof(bf16);
  bf16* VF0 = (bf16*)(ws + o); o += (size_t)NVARS*64*sizeof(bf16);
  bf16* VF1 = (bf16*)(ws + o); o += (size_t)NVARS*64*sizeof(bf16);
  bf16* VF2 = (bf16*)(ws + o); o += (size_t)NVARS*64*sizeof(bf16);
  int* CNTCI = (int*)(ws + o); o += (size_t)NCONS*sizeof(int);
  int* CNTVI = (int*)(ws + o); o += (size_t)NVARS*sizeof(int);
  int* OFFC  = (int*)(ws + o); o += (size_t)(NCONS+1)*sizeof(int);
  int* OFFV  = (int*)(ws + o); o += (size_t)(NVARS+1)*sizeof(int);
  int* SRTC  = (int*)(ws + o); o += (size_t)NEDGE*sizeof(int);
  int* SRTV  = (int*)(ws + o); o += (size_t)NEDGE*sizeof(int);
  bf16* EAC  = (bf16*)(ws + o); o += (size_t)NEDGE*sizeof(bf16);
  bf16* EAV  = (bf16*)(ws + o); o += (size_t)NEDGE*sizeof(bf16);

  detect_k<<<1,64,0,stream>>>((const unsigned int*)d_in[0], MODE);
  convert_all_k<<<512,256,0,stream>>>(ca, FBASE, MODE);
  frag_all_k<<<384,256,0,stream>>>(F[17], F[19], F[23], F[25], W1Fb, W2Fb, OW1Fb, OW2Fb);
  frag2_k<<<384,256,0,stream>>>(F[30], FW1H, FW1L, 32, 512, 98304);
  frag2_k<<<256,256,0,stream>>>(F[32], FW2H, FW2L, 8, 128, 65536);

  zero_k<<<8,256,0,stream>>>(ST, 4096);
  zero_k<<<128,256,0,stream>>>((float*)CNTCI, NCONS + NVARS);
  hist_k<<<1024,256,0,stream>>>(ei, CNTCI, CNTVI);
  scan_k<<<1,1024,0,stream>>>(CNTCI, OFFC, NCONS);
  scan_k<<<1,1024,0,stream>>>(CNTVI, OFFV, NVARS);
  scat_k<<<1024,256,0,stream>>>(ei, F[1], CNTCI, CNTVI, SRTC, SRTV, EAC, EAV);

  col_stats_k<<<256,256,0,stream>>>(F[0], NCONS, 3, ST+0);
  col_stats_k<<<256,256,0,stream>>>(F[2], NVARS, 5, ST+6);
  col_stats_k<<<512,256,0,stream>>>(F[1], NEDGE, 1, ST+16);
  fin_input_k<<<1,64,0,stream>>>(ST, F[3], F[4], F[11], F[12], F[9], F[10]);
  embed2_k<<<1024,256,0,stream>>>(F[0], F[2], ST,
                                  F[5], F[6], F[7], F[8],
                                  F[13], F[14], F[15], F[16], CFA, VF0);

  const bf16* lefts[4]  = {VF0, CFB, VF1, CFA};
  const bf16* rights[4] = {CFA, VF0, CFB, VF1};
  bf16*       outs[4]   = {CFB, VF1, CFA, VF2};
  const int*  srts[4]   = {SRTC, SRTV, SRTC, SRTV};
  const bf16* eass[4]   = {EAC, EAV, EAC, EAV};
  const int*  offss[4]  = {OFFC, OFFV, OFFC, OFFV};

  for (int l=0; l<4; ++l){
    float* slot = ST + 36 + l*256;
    float* gslot = ST + 36 + 1024 + l*256;
    msg_csr_k<<<1024,256,0,stream>>>(lefts[l], rights[l], srts[l], eass[l], ST+34,
                                     offss[l],
                                     W1Fb + l*8192,
                                     F[18] + l*64,
                                     F[17] + (size_t)l*129*64 + 64*64,
                                     AGG, NCONS);
    agg2_k<<<782,256,0,stream>>>(AGG, offss[l], W2Fb + l*4096, F[20] + l*64, slot, NCONS);
    fin_bn_k<<<1,64,0,stream>>>(slot, F[21] + l*64, F[22] + l*64, (float)NCONS);
    node_mfma_k<<<782,256,0,stream>>>(AGG, rights[l], slot,
                                      OW1Fb + l*8192, OW2Fb + l*4096,
                                      F[24] + l*64, F[26] + l*64, outs[l], gslot, NCONS);
    if (l == 1 || l == 3){
      bf16* cfbuf = outs[l-1];
      bf16* vfbuf = outs[l];
      int ga = l-1, gb = l;
      float* gsA = ST + 36 + 1024 + ga*256;
      float* gsB = ST + 36 + 1024 + gb*256;
      fin_gn2_k<<<1,128,0,stream>>>(gsA, gsB, F[27], F[28], F[29], ga, gb, 50000.f);
      affine2_k<<<1024,256,0,stream>>>(cfbuf, gsA, vfbuf, gsB, NCONS);
    }
  }
  final_mfma_k<<<782,256,0,stream>>>(VF0, VF1, VF2,
                                     FW1H, FW1L, FW2H, FW2L,
                                     F[31], F[33], F[34], F[35],
                                     d_out, NVARS, MODE);
}

// Round 14
// 1367.326 us; speedup vs baseline: 1.0593x; 1.0593x over previous
//
#include <hip/hip_runtime.h>
#include <hip/hip_bf16.h>

typedef __hip_bfloat16 bf16;
typedef __attribute__((ext_vector_type(8))) short short8v;
typedef __attribute__((ext_vector_type(4))) float float4v;

#define NCONS 50000
#define NVARS 50000
#define NEDGE 600000

__device__ __forceinline__ float b2f(const bf16 v){ return __bfloat162float(v); }
__device__ __forceinline__ float shflf(float v, int lane){ return __shfl(v, lane, 64); }
__device__ __forceinline__ unsigned short f2b(float v){
  return __builtin_bit_cast(unsigned short, __float2bfloat16(v));
}

// ---- input-dtype sniffer (bf16 pairs vs f32) ----
__global__ void detect_k(const unsigned int* __restrict__ x, int* __restrict__ mode){
  int t = threadIdx.x;
  int hits = 0;
  for (int i=0;i<4;++i){
    unsigned w = x[t*4+i];
    unsigned e = (w>>7)&0xFFu;
    if (e >= 0x70u && e <= 0x8Fu) hits++;
  }
  for (int off=32; off>0; off>>=1) hits += __shfl_down(hits, off);
  if (t==0) *mode = (hits > 128) ? 1 : 0;
}

// ---- convert ALL 36 float inputs to f32 workspace in one launch ----
struct CvtArgs { const void* p[36]; int ofs[37]; };
__global__ void convert_all_k(CvtArgs a, float* __restrict__ dst, const int* __restrict__ mode){
  int m = *mode;
  int i = blockIdx.x*blockDim.x + threadIdx.x;
  int stride = gridDim.x*blockDim.x;
  int total = a.ofs[36];
  for (; i<total; i+=stride){
    int s = 0;
#pragma unroll
    for (int k=1;k<36;++k) s += (i >= a.ofs[k]) ? 1 : 0;
    int off = i - a.ofs[s];
    float v;
    if (m) v = b2f(((const bf16*)a.p[s])[off]);
    else   v = ((const float*)a.p[s])[off];
    dst[i] = v;
  }
}

// ---- zero ST (na floats) and CNT (nb ints) in one launch ----
__global__ void zero2_k(float* __restrict__ a, int na, float* __restrict__ b, int nb){
  int i = blockIdx.x*blockDim.x + threadIdx.x;
  int stride = gridDim.x*blockDim.x;
  for (; i<na+nb; i+=stride){
    if (i < na) a[i] = 0.f;
    else        b[i-na] = 0.f;
  }
}

// ---- CSR build: histogram, single-block scan (cnt becomes cursor), scatter ----
__global__ void hist_k(const int* __restrict__ ei, int* __restrict__ cntc, int* __restrict__ cntv){
  int i = blockIdx.x*blockDim.x + threadIdx.x;
  int stride = gridDim.x*blockDim.x;
  for (; i<2*NEDGE; i+=stride){
    int id = ei[i];
    if (i < NEDGE) atomicAdd(&cntc[id], 1);
    else           atomicAdd(&cntv[id], 1);
  }
}

__global__ void __launch_bounds__(1024) scan_k(int* __restrict__ cnt, int* __restrict__ offs, int n){
  __shared__ int part[1024];
  int t = threadIdx.x;
  int chunk = (n + 1023) >> 10;
  int b = t*chunk;
  int e = b + chunk; if (e > n) e = n;
  int s = 0;
  for (int i=b; i<e; ++i) s += cnt[i];
  part[t] = s;
  __syncthreads();
  for (int off=1; off<1024; off<<=1){
    int v = (t >= off) ? part[t-off] : 0;
    __syncthreads();
    part[t] += v;
    __syncthreads();
  }
  int run = (t==0) ? 0 : part[t-1];
  for (int i=b; i<e; ++i){
    int c = cnt[i];
    offs[i] = run; cnt[i] = run;   // cnt becomes cursor
    run += c;
  }
  if (t==1023) offs[n] = part[1023];
}

// scatter: write dst-sorted src ids and dst-sorted bf16 edge attrs directly
__global__ void scat_k(const int* __restrict__ ei, const float* __restrict__ ea,
                       int* __restrict__ curc, int* __restrict__ curv,
                       int* __restrict__ srtc, int* __restrict__ srtv,
                       bf16* __restrict__ eac, bf16* __restrict__ eav){
  int i = blockIdx.x*blockDim.x + threadIdx.x;
  int stride = gridDim.x*blockDim.x;
  for (; i<2*NEDGE; i+=stride){
    int id = ei[i];
    if (i < NEDGE){
      int p = atomicAdd(&curc[id],1);
      srtc[p] = ei[NEDGE+i];                 // variable endpoint
      eac[p] = __float2bfloat16(ea[i]);
    } else {
      int e = i - NEDGE;
      int p = atomicAdd(&curv[id],1);
      srtv[p] = ei[e];                       // constraint endpoint
      eav[p] = __float2bfloat16(ea[e]);
    }
  }
}

// ---- all three input col-stats jobs in one launch ----
__device__ __forceinline__ void col_stats_body(const float* __restrict__ x, int rows, int cols,
                                               float* __restrict__ sums, int tid, int stride){
  float s[5], ss[5];
  for (int c=0;c<5;++c){ s[c]=0.f; ss[c]=0.f; }
  for (int r=tid; r<rows; r+=stride){
    for (int c=0;c<cols;++c){
      float v = x[r*cols+c];
      s[c]+=v; ss[c]+=v*v;
    }
  }
  for (int c=0;c<cols;++c){
    float a=s[c], b=ss[c];
    for (int off=32; off>0; off>>=1){ a+=__shfl_down(a,off); b+=__shfl_down(b,off); }
    if ((threadIdx.x & 63)==0){ atomicAdd(&sums[c],a); atomicAdd(&sums[cols+c],b); }
  }
}

__global__ void col_stats3_k(const float* __restrict__ xc, const float* __restrict__ xv,
                             const float* __restrict__ xe, float* __restrict__ ST){
  int b = blockIdx.x;
  if (b < 256)      col_stats_body(xc, NCONS, 3, ST+0,  b*256+threadIdx.x,       256*256);
  else if (b < 512) col_stats_body(xv, NVARS, 5, ST+6,  (b-256)*256+threadIdx.x, 256*256);
  else              col_stats_body(xe, NEDGE, 1, ST+16, (b-512)*256+threadIdx.x, 512*256);
}

// ---- merged embedding for BOTH node sets; input-BN finalize in prologue ----
__global__ void embed2_k(const float* __restrict__ xc, const float* __restrict__ xv,
                         const float* __restrict__ st,
                         const float* __restrict__ cbnw, const float* __restrict__ cbnb,
                         const float* __restrict__ vbnw, const float* __restrict__ vbnb,
                         const float* __restrict__ cW1, const float* __restrict__ cb1,
                         const float* __restrict__ cW2, const float* __restrict__ cb2,
                         const float* __restrict__ vW1, const float* __restrict__ vb1,
                         const float* __restrict__ vW2, const float* __restrict__ vb2,
                         bf16* __restrict__ outc, bf16* __restrict__ outv){
  __shared__ float aff[16];   // consA[3]@0 consB[3]@3 varA[5]@6 varB[5]@11
  {
    int tt = threadIdx.x;
    if (tt < 3){
      float m = st[tt]/(float)NCONS, q = st[3+tt]/(float)NCONS;
      float A = rsqrtf(fmaxf(q - m*m, 0.f) + 1e-5f)*cbnw[tt];
      aff[tt] = A; aff[3+tt] = cbnb[tt] - m*A;
    } else if (tt < 8){
      int c = tt-3;
      float m = st[6+c]/(float)NVARS, q = st[11+c]/(float)NVARS;
      float A = rsqrtf(fmaxf(q - m*m, 0.f) + 1e-5f)*vbnw[c];
      aff[6+c] = A; aff[11+c] = vbnb[c] - m*A;
    }
  }
  __syncthreads();
  int t = threadIdx.x & 63;
  int w = (blockIdx.x*blockDim.x + threadIdx.x) >> 6;
  int nw = (gridDim.x*blockDim.x) >> 6;
  for (int j = w; j < NCONS + NVARS; j += nw){
    bool isv = (j >= NCONS);
    int n = isv ? j - NCONS : j;
    const float* x  = isv ? xv : xc;
    int cin         = isv ? 5 : 3;
    const float* pA = isv ? aff+6 : aff+0;
    const float* pB = isv ? aff+11 : aff+3;
    const float* W1 = isv ? vW1 : cW1;
    const float* b1 = isv ? vb1 : cb1;
    const float* W2 = isv ? vW2 : cW2;
    const float* b2 = isv ? vb2 : cb2;
    bf16* out       = isv ? outv : outc;
    float acc = b1[t];
    for (int k=0;k<cin;++k){
      float xb = x[n*cin+k]*pA[k] + pB[k];
      acc += xb*W1[k*64+t];
    }
    float h1 = fmaxf(acc, 0.f);
    float acc2 = b2[t];
#pragma unroll
    for (int j2=0;j2<64;++j2) acc2 += shflf(h1,j2)*W2[j2*64+t];
    out[n*64+t] = __float2bfloat16(fmaxf(acc2, 0.f));
  }
}

// ---- all 16 conv-weight fragment jobs in one launch ----
__global__ void frag_all_k(const float* __restrict__ fmW1, const float* __restrict__ fmW2,
                           const float* __restrict__ omW1, const float* __restrict__ omW2,
                           unsigned short* __restrict__ W1Fb, unsigned short* __restrict__ W2Fb,
                           unsigned short* __restrict__ OW1Fb, unsigned short* __restrict__ OW2Fb){
  int i = blockIdx.x*blockDim.x + threadIdx.x;
  if (i >= 4*24576) return;
  int l = i / 24576, r = i % 24576;
  const float* src; unsigned short* dst; int e; int skip;
  if (r < 8192){       src = fmW1 + (size_t)l*129*64; dst = W1Fb  + l*8192; e = r;       skip = 64; }
  else if (r < 12288){ src = fmW2 + (size_t)l*64*64;  dst = W2Fb  + l*4096; e = r-8192;  skip = -1; }
  else if (r < 20480){ src = omW1 + (size_t)l*128*64; dst = OW1Fb + l*8192; e = r-12288; skip = -1; }
  else {               src = omW2 + (size_t)l*64*64;  dst = OW2Fb + l*4096; e = r-20480; skip = -1; }
  int j = e & 7, lane = (e>>3)&63, n = (e>>9)&3, kc = e>>11;
  int k = kc*32 + (lane>>4)*8 + j;
  int col = n*16 + (lane&15);
  int srcrow = (skip>=0 && k>=skip) ? k+1 : k;
  dst[e] = f2b(src[srcrow*64 + col]);
}

// ---- hi/lo fragmenter for final-MLP weights ----
__global__ void frag2_k(const float* __restrict__ Wsrc, unsigned short* __restrict__ Whi,
                        unsigned short* __restrict__ Wlo, int ntiles, int ncols, int tot){
  int i = blockIdx.x*blockDim.x + threadIdx.x;
  if (i>=tot) return;
  int j = i & 7, lane = (i>>3)&63, rem = i>>9;
  int nt = rem % ntiles, kc = rem / ntiles;
  int k = kc*32 + (lane>>4)*8 + j;
  int col = nt*16 + (lane&15);
  float w = Wsrc[k*ncols + col];
  unsigned short hi = f2b(w);
  float rec = __builtin_bit_cast(float, (unsigned int)hi << 16);
  Whi[i] = hi;
  Wlo[i] = f2b(w - rec);
}

// ---- CSR MFMA edge-message kernel + fused BN column stats (round-12 form);
// edge-BN finalize computed in prologue from raw sums. ----
__global__ void __launch_bounds__(256) msg_csr_k(
    const bf16* __restrict__ left, const bf16* __restrict__ right,
    const int* __restrict__ srt, const bf16* __restrict__ eas,
    const float* __restrict__ est, const float* __restrict__ ebnw, const float* __restrict__ ebnb,
    const int* __restrict__ offs,
    const unsigned short* __restrict__ W1F, const unsigned short* __restrict__ W2F,
    const float* __restrict__ b1, const float* __restrict__ w1e, const float* __restrict__ b2,
    float* __restrict__ agg, float* __restrict__ slot, int nn)
{
  __shared__ __align__(16) unsigned short w1l[8192];
  __shared__ __align__(16) unsigned short w2l[4096];
  __shared__ __align__(16) unsigned short h1l[4][16*72];
  __shared__ float bstat[128];
  {
    const float4* s1 = (const float4*)W1F; float4* d1 = (float4*)w1l;
    for (int i=threadIdx.x; i<1024; i+=256) d1[i] = s1[i];
    const float4* s2 = (const float4*)W2F; float4* d2 = (float4*)w2l;
    for (int i=threadIdx.x; i<512; i+=256) d2[i] = s2[i];
    if (threadIdx.x < 128) bstat[threadIdx.x] = 0.f;
  }
  __syncthreads();
  const short8v* W1v = (const short8v*)w1l;
  const short8v* W2v = (const short8v*)w2l;
  const unsigned short* rgt = (const unsigned short*)right;
  const unsigned short* lft = (const unsigned short*)left;
  int t = threadIdx.x & 63;
  int wv = threadIdx.x >> 6;
  int gw = (blockIdx.x*blockDim.x + threadIdx.x) >> 6;
  int nw = (gridDim.x*blockDim.x) >> 6;
  int r16 = t & 15, kg = t >> 4;
  // edge-BN finalize from raw sums (identical float ops in every thread)
  float em = est[0]/(float)NEDGE, eq = est[1]/(float)NEDGE;
  float eA = rsqrtf(fmaxf(eq - em*em, 0.f) + 1e-5f)*ebnw[0];
  float eB = ebnb[0] - em*eA;
  float bb1[4], we[4], bb2[4];
#pragma unroll
  for (int n=0;n<4;++n){ bb1[n]=b1[n*16+r16]; we[n]=w1e[n*16+r16]; bb2[n]=b2[n*16+r16]; }
  unsigned short* h1w = &h1l[wv][0];
  float sacc[4] = {0.f,0.f,0.f,0.f}, ssacc[4] = {0.f,0.f,0.f,0.f};

  int chunk = (nn + nw - 1) / nw;
  int nbeg = gw * chunk;
  int nend = nbeg + chunk; if (nend > nn) nend = nn;

  for (int node = nbeg; node < nend; ++node){
    int beg = offs[node], end = offs[node+1];
    int deg = end - beg;
    float4v acc[4];
#pragma unroll
    for (int n=0;n<4;++n) acc[n] = (float4v){0.f,0.f,0.f,0.f};
    if (deg > 0){
      short8v rr0 = *(const short8v*)(rgt + (size_t)node*64 + kg*8);
      short8v rr1 = *(const short8v*)(rgt + (size_t)node*64 + 32 + kg*8);
      float4v crt[4];
#pragma unroll
      for (int n=0;n<4;++n) crt[n] = (float4v){bb1[n],bb1[n],bb1[n],bb1[n]};
#pragma unroll
      for (int n=0;n<4;++n){
        crt[n] = __builtin_amdgcn_mfma_f32_16x16x32_bf16(rr0, W1v[(0+n)*64+t], crt[n], 0,0,0);
        crt[n] = __builtin_amdgcn_mfma_f32_16x16x32_bf16(rr1, W1v[(4+n)*64+t], crt[n], 0,0,0);
      }
      for (int base = beg; base < end; base += 16){
        int idx = base + r16;
        int ic = idx < end ? idx : beg;
        int sI = srt[ic];
        float ef = b2f(eas[ic])*eA + eB;
        short8v al0 = *(const short8v*)(lft + (size_t)sI*64 + kg*8);
        short8v al1 = *(const short8v*)(lft + (size_t)sI*64 + 32 + kg*8);
        float efr[4];
#pragma unroll
        for (int r=0;r<4;++r) efr[r] = shflf(ef, kg*4+r);
        float4v c[4];
#pragma unroll
        for (int n=0;n<4;++n){
#pragma unroll
          for (int r=0;r<4;++r) c[n][r] = crt[n][r] + efr[r]*we[n];
        }
#pragma unroll
        for (int n=0;n<4;++n){
          c[n] = __builtin_amdgcn_mfma_f32_16x16x32_bf16(al0, W1v[( 8+n)*64+t], c[n], 0,0,0);
          c[n] = __builtin_amdgcn_mfma_f32_16x16x32_bf16(al1, W1v[(12+n)*64+t], c[n], 0,0,0);
        }
#pragma unroll
        for (int n=0;n<4;++n){
#pragma unroll
          for (int r=0;r<4;++r)
            h1w[(kg*4+r)*72 + n*16 + r16] = f2b(fmaxf(c[n][r], 0.f));
        }
        asm volatile("s_waitcnt lgkmcnt(0)" ::: "memory");
        __builtin_amdgcn_sched_barrier(0);
        short8v a20 = *(const short8v*)(h1w + r16*72 + kg*8);
        short8v a21 = *(const short8v*)(h1w + r16*72 + 32 + kg*8);
        float4v d[4];
#pragma unroll
        for (int n=0;n<4;++n) d[n] = (float4v){0.f,0.f,0.f,0.f};
#pragma unroll
        for (int n=0;n<4;++n){
          d[n] = __builtin_amdgcn_mfma_f32_16x16x32_bf16(a20, W2v[(0+n)*64+t], d[n], 0,0,0);
          d[n] = __builtin_amdgcn_mfma_f32_16x16x32_bf16(a21, W2v[(4+n)*64+t], d[n], 0,0,0);
        }
#pragma unroll
        for (int r=0;r<4;++r){
          float mrow = (base + kg*4 + r < end) ? 1.f : 0.f;
#pragma unroll
          for (int n=0;n<4;++n) acc[n][r] += mrow * d[n][r];
        }
      }
    }
    float tot[4];
#pragma unroll
    for (int n=0;n<4;++n){
      tot[n] = acc[n][0]+acc[n][1]+acc[n][2]+acc[n][3];
      tot[n] += __shfl_xor(tot[n], 16, 64);
      tot[n] += __shfl_xor(tot[n], 32, 64);
    }
    if (kg == 0){
      float inv = (deg>0) ? 1.f/(float)deg : 0.f;
#pragma unroll
      for (int n=0;n<4;++n){
        float val = (deg>0) ? tot[n]*inv + bb2[n] : 0.f;
        agg[(size_t)node*64 + n*16 + r16] = val;
        sacc[n] += val; ssacc[n] += val*val;
      }
    }
  }
  if (kg == 0){
#pragma unroll
    for (int n=0;n<4;++n){
      atomicAdd(&bstat[n*16+r16], sacc[n]);
      atomicAdd(&bstat[64+n*16+r16], ssacc[n]);
    }
  }
  __syncthreads();
  if (threadIdx.x < 128) atomicAdd(&slot[threadIdx.x], bstat[threadIdx.x]);
}

// ---- MFMA node-output MLP + fused GraphNorm stats; BN finalize in prologue ----
__global__ void __launch_bounds__(256) node_mfma_k(
    const float* __restrict__ agg, const bf16* __restrict__ right,
    const float* __restrict__ slot, const float* __restrict__ bnw, const float* __restrict__ bnb,
    const unsigned short* __restrict__ W1F, const unsigned short* __restrict__ W2F,
    const float* __restrict__ b1, const float* __restrict__ b2,
    bf16* __restrict__ out, float* __restrict__ gslot, int nn)
{
  __shared__ __align__(16) unsigned short w1l[8192];
  __shared__ __align__(16) unsigned short w2l[4096];
  __shared__ __align__(16) unsigned short h1l[4][16*72];
  __shared__ float bstat[128];
  __shared__ float bnAB[128];
  {
    const float4* s1 = (const float4*)W1F; float4* d1 = (float4*)w1l;
    for (int i=threadIdx.x; i<1024; i+=256) d1[i] = s1[i];
    const float4* s2 = (const float4*)W2F; float4* d2 = (float4*)w2l;
    for (int i=threadIdx.x; i<512; i+=256) d2[i] = s2[i];
    if (threadIdx.x < 128) bstat[threadIdx.x] = 0.f;
    if (threadIdx.x < 64){
      int c = threadIdx.x;
      float m = slot[c]/(float)NCONS, q = slot[64+c]/(float)NCONS;
      float A = rsqrtf(fmaxf(q - m*m, 0.f) + 1e-5f) * bnw[c];
      bnAB[c] = A; bnAB[64+c] = bnb[c] - m*A;
    }
  }
  __syncthreads();
  const short8v* W1v = (const short8v*)w1l;
  const short8v* W2v = (const short8v*)w2l;
  const unsigned short* rgt = (const unsigned short*)right;
  int t = threadIdx.x & 63;
  int wv = threadIdx.x >> 6;
  int gw = (blockIdx.x*blockDim.x + threadIdx.x) >> 6;
  int nw = (gridDim.x*blockDim.x) >> 6;
  int r16 = t & 15, kg = t >> 4;
  float pA0[8], pB0[8], pA1[8], pB1[8];
#pragma unroll
  for (int j=0;j<8;++j){
    pA0[j]=bnAB[kg*8+j];    pB0[j]=bnAB[64+kg*8+j];
    pA1[j]=bnAB[32+kg*8+j]; pB1[j]=bnAB[96+kg*8+j];
  }
  float bb1[4], bb2[4];
#pragma unroll
  for (int n=0;n<4;++n){ bb1[n]=b1[n*16+r16]; bb2[n]=b2[n*16+r16]; }
  unsigned short* h1w = &h1l[wv][0];
  float sacc[4] = {0.f,0.f,0.f,0.f}, ssacc[4] = {0.f,0.f,0.f,0.f};

  for (int g = gw*16; g < nn; g += nw*16){
    int node = g + r16;
    const float* ag = agg + (size_t)node*64;
    float4 f0 = *(const float4*)(ag + kg*8);
    float4 f1 = *(const float4*)(ag + kg*8 + 4);
    float4 f2 = *(const float4*)(ag + 32 + kg*8);
    float4 f3 = *(const float4*)(ag + 32 + kg*8 + 4);
    float v0[8] = {f0.x,f0.y,f0.z,f0.w,f1.x,f1.y,f1.z,f1.w};
    float v1[8] = {f2.x,f2.y,f2.z,f2.w,f3.x,f3.y,f3.z,f3.w};
    short8v ap0, ap1;
#pragma unroll
    for (int j=0;j<8;++j){
      ((unsigned short*)&ap0)[j] = f2b(v0[j]*pA0[j] + pB0[j]);
      ((unsigned short*)&ap1)[j] = f2b(v1[j]*pA1[j] + pB1[j]);
    }
    short8v ar0 = *(const short8v*)(rgt + (size_t)node*64 + kg*8);
    short8v ar1 = *(const short8v*)(rgt + (size_t)node*64 + 32 + kg*8);
    float4v c[4];
#pragma unroll
    for (int n=0;n<4;++n) c[n] = (float4v){bb1[n],bb1[n],bb1[n],bb1[n]};
#pragma unroll
    for (int n=0;n<4;++n){
      c[n] = __builtin_amdgcn_mfma_f32_16x16x32_bf16(ap0, W1v[( 0+n)*64+t], c[n], 0,0,0);
      c[n] = __builtin_amdgcn_mfma_f32_16x16x32_bf16(ap1, W1v[( 4+n)*64+t], c[n], 0,0,0);
      c[n] = __builtin_amdgcn_mfma_f32_16x16x32_bf16(ar0, W1v[( 8+n)*64+t], c[n], 0,0,0);
      c[n] = __builtin_amdgcn_mfma_f32_16x16x32_bf16(ar1, W1v[(12+n)*64+t], c[n], 0,0,0);
    }
#pragma unroll
    for (int n=0;n<4;++n){
#pragma unroll
      for (int r=0;r<4;++r)
        h1w[(kg*4+r)*72 + n*16 + r16] = f2b(fmaxf(c[n][r], 0.f));
    }
    asm volatile("s_waitcnt lgkmcnt(0)" ::: "memory");
    __builtin_amdgcn_sched_barrier(0);
    short8v a20 = *(const short8v*)(h1w + r16*72 + kg*8);
    short8v a21 = *(const short8v*)(h1w + r16*72 + 32 + kg*8);
    float4v d[4];
#pragma unroll
    for (int n=0;n<4;++n) d[n] = (float4v){bb2[n],bb2[n],bb2[n],bb2[n]};
#pragma unroll
    for (int n=0;n<4;++n){
      d[n] = __builtin_amdgcn_mfma_f32_16x16x32_bf16(a20, W2v[(0+n)*64+t], d[n], 0,0,0);
      d[n] = __builtin_amdgcn_mfma_f32_16x16x32_bf16(a21, W2v[(4+n)*64+t], d[n], 0,0,0);
    }
    unsigned short* op = (unsigned short*)out;
#pragma unroll
    for (int r=0;r<4;++r){
      size_t base = (size_t)(g + kg*4 + r)*64 + r16;
#pragma unroll
      for (int n=0;n<4;++n){
        float val = d[n][r];
        op[base + n*16] = f2b(val);
        sacc[n] += val; ssacc[n] += val*val;
      }
    }
  }
#pragma unroll
  for (int n=0;n<4;++n){
    atomicAdd(&bstat[n*16+r16], sacc[n]);
    atomicAdd(&bstat[64+n*16+r16], ssacc[n]);
  }
  __syncthreads();
  if (threadIdx.x < 128) atomicAdd(&gslot[threadIdx.x], bstat[threadIdx.x]);
}

// ---- graphnorm apply on both buffers; GN finalize in prologue ----
__global__ void affine2_k(bf16* __restrict__ x1, const float* __restrict__ s1,
                          bf16* __restrict__ x2, const float* __restrict__ s2,
                          const float* __restrict__ gw, const float* __restrict__ gb,
                          const float* __restrict__ gal, int ga, int gb2, int nn){
  __shared__ float ab[256];   // s1A 0-63, s1B 64-127, s2A 128-191, s2B 192-255
  {
    int tt = threadIdx.x;
    if (tt < 128){
      const float* sl = (tt < 64) ? s1 : s2;
      int g = (tt < 64) ? ga : gb2;
      int c = tt & 63;
      float m = sl[c]/(float)NCONS, q = sl[64+c]/(float)NCONS;
      float a = gal[g*64+c];
      float var = q - 2.f*a*m*m + a*a*m*m;
      float A = rsqrtf(fmaxf(var, 0.f) + 1e-5f) * gw[g*64+c];
      ab[(tt<64?0:128)+c] = A;
      ab[(tt<64?64:192)+c] = gb[g*64+c] - a*m*A;
    }
  }
  __syncthreads();
  int i = blockIdx.x*blockDim.x + threadIdx.x;
  int stride = gridDim.x*blockDim.x;
  int tot = nn*64;
  for (; i<2*tot; i+=stride){
    if (i < tot){
      int c = i & 63;
      x1[i] = __float2bfloat16(b2f(x1[i])*ab[c] + ab[64+c]);
    } else {
      int j = i - tot;
      int c = j & 63;
      x2[j] = __float2bfloat16(b2f(x2[j])*ab[128+c] + ab[192+c]);
    }
  }
}

// ---- MFMA final MLP, race-free (one 16-node tile per wave, __syncthreads) ----
__global__ void __launch_bounds__(256) final_mfma_k(
    const bf16* __restrict__ vf0, const bf16* __restrict__ vf1, const bf16* __restrict__ vf2,
    const unsigned short* __restrict__ W1hi, const unsigned short* __restrict__ W1lo,
    const unsigned short* __restrict__ W2hi, const unsigned short* __restrict__ W2lo,
    const float* __restrict__ B1, const float* __restrict__ B2,
    const float* __restrict__ W3, const float* __restrict__ B3,
    void* __restrict__ out, int nn, const int* __restrict__ mode)
{
  __shared__ float h1l[4][16*260];
  const short8v* W1h = (const short8v*)W1hi;
  const short8v* W1l = (const short8v*)W1lo;
  const short8v* W2h = (const short8v*)W2hi;
  const short8v* W2l = (const short8v*)W2lo;
  const unsigned short* v0p = (const unsigned short*)vf0;
  const unsigned short* v1p = (const unsigned short*)vf1;
  const unsigned short* v2p = (const unsigned short*)vf2;
  int t = threadIdx.x & 63;
  int wv = threadIdx.x >> 6;
  int r16 = t & 15, kg = t >> 4;
  int tile = blockIdx.x*4 + wv;
  bool act = (tile*16 < nn);
  int g = act ? tile*16 : 0;
  float* h1w = &h1l[wv][0];
  float b2v[8], w3v[8];
#pragma unroll
  for (int n=0;n<8;++n){ b2v[n] = B2[n*16+r16]; w3v[n] = W3[n*16+r16]; }
  float bb3 = B3[0];
  int md = *mode;

  int node = g + r16;
  short8v A1[6];
  A1[0] = *(const short8v*)(v0p + (size_t)node*64 + kg*8);
  A1[1] = *(const short8v*)(v0p + (size_t)node*64 + 32 + kg*8);
  A1[2] = *(const short8v*)(v1p + (size_t)node*64 + kg*8);
  A1[3] = *(const short8v*)(v1p + (size_t)node*64 + 32 + kg*8);
  A1[4] = *(const short8v*)(v2p + (size_t)node*64 + kg*8);
  A1[5] = *(const short8v*)(v2p + (size_t)node*64 + 32 + kg*8);
  float4v D[8];
#pragma unroll
  for (int n=0;n<8;++n) D[n] = (float4v){b2v[n],b2v[n],b2v[n],b2v[n]};

  for (int half=0; half<2; ++half){
    if (half) __syncthreads();
    for (int nt=0; nt<16; ++nt){
      int ntg = half*16 + nt;
      float bb = B1[ntg*16 + r16];
      float4v C = (float4v){bb,bb,bb,bb};
#pragma unroll
      for (int kc=0; kc<6; ++kc){
        C = __builtin_amdgcn_mfma_f32_16x16x32_bf16(A1[kc], W1h[(kc*32+ntg)*64+t], C, 0,0,0);
        C = __builtin_amdgcn_mfma_f32_16x16x32_bf16(A1[kc], W1l[(kc*32+ntg)*64+t], C, 0,0,0);
      }
#pragma unroll
      for (int r=0;r<4;++r)
        h1w[(kg*4+r)*260 + nt*16 + r16] = fmaxf(C[r], 0.f);
    }
    __syncthreads();
    short8v Ahi[8], Alo[8];
#pragma unroll
    for (int kc=0; kc<8; ++kc){
      const float* hp = h1w + r16*260 + kc*32 + kg*8;
      float4 x0 = *(const float4*)(hp);
      float4 x1 = *(const float4*)(hp+4);
      float vv[8] = {x0.x,x0.y,x0.z,x0.w,x1.x,x1.y,x1.z,x1.w};
#pragma unroll
      for (int j=0;j<8;++j){
        unsigned short hi = f2b(vv[j]);
        float rec = __builtin_bit_cast(float, (unsigned int)hi<<16);
        ((unsigned short*)&Ahi[kc])[j] = hi;
        ((unsigned short*)&Alo[kc])[j] = f2b(vv[j] - rec);
      }
    }
#pragma unroll
    for (int nt2=0; nt2<8; ++nt2){
#pragma unroll
      for (int kc=0; kc<8; ++kc){
        int kcg = half*8 + kc;
        short8v bh = W2h[(kcg*8+nt2)*64+t];
        D[nt2] = __builtin_amdgcn_mfma_f32_16x16x32_bf16(Ahi[kc], bh, D[nt2], 0,0,0);
        D[nt2] = __builtin_amdgcn_mfma_f32_16x16x32_bf16(Alo[kc], bh, D[nt2], 0,0,0);
        D[nt2] = __builtin_amdgcn_mfma_f32_16x16x32_bf16(Ahi[kc], W2l[(kcg*8+nt2)*64+t], D[nt2], 0,0,0);
      }
    }
  }
  float part[4] = {0.f,0.f,0.f,0.f};
#pragma unroll
  for (int n=0;n<8;++n){
#pragma unroll
    for (int r=0;r<4;++r) part[r] += fmaxf(D[n][r],0.f)*w3v[n];
  }
#pragma unroll
  for (int r=0;r<4;++r){
#pragma unroll
    for (int off=1; off<16; off<<=1) part[r] += __shfl_xor(part[r], off, 64);
  }
  if (act && r16==0){
#pragma unroll
    for (int r=0;r<4;++r){
      int node_o = g + kg*4 + r;
      float val = part[r] + bb3;
      if (md) ((bf16*)out)[node_o] = __float2bfloat16(val);
      else    ((float*)out)[node_o] = val;
    }
  }
}

extern "C" void kernel_launch(void* const* d_in, const int* in_sizes, int n_in,
                              void* d_out, int out_size, void* d_ws, size_t ws_size,
                              hipStream_t stream){
  const int* ei = (const int*)d_in[36];

  char* ws = (char*)d_ws;
  float* ST = (float*)ws;                       // 4096 floats = 16 KB
  int* MODE = (int*)(ws + 16384);
  float* FBASE = (float*)(ws + 32768);
  CvtArgs ca;
  float* F[36];
  {
    int off = 0;
    for (int i=0;i<36;++i){
      ca.p[i] = d_in[i];
      ca.ofs[i] = off;
      F[i] = FBASE + off;
      off += in_sizes[i];
    }
    ca.ofs[36] = off;
  }
  unsigned short* W1Fb  = (unsigned short*)(ws + 7u*1024*1024);
  unsigned short* W2Fb  = W1Fb + 4*8192;
  unsigned short* OW1Fb = W2Fb + 4*4096;
  unsigned short* OW2Fb = OW1Fb + 4*8192;
  unsigned short* FW1H  = OW2Fb + 4*4096;
  unsigned short* FW1L  = FW1H + 98304;
  unsigned short* FW2H  = FW1L + 98304;
  unsigned short* FW2L  = FW2H + 65536;
  size_t o = 8u*1024*1024;
  float* AGG = (float*)(ws + o); o += (size_t)NCONS*64*sizeof(float);
  bf16* CFA = (bf16*)(ws + o); o += (size_t)NCONS*64*sizeof(bf16);
  bf16* CFB = (bf16*)(ws + o); o += (size_t)NCONS*64*sizeof(bf16);
  bf16* VF0 = (bf16*)(ws + o); o += (size_t)NVARS*64*sizeof(bf16);
  bf16* VF1 = (bf16*)(ws + o); o += (size_t)NVARS*64*sizeof(bf16);
  bf16* VF2 = (bf16*)(ws + o); o += (size_t)NVARS*64*sizeof(bf16);
  int* CNTCI = (int*)(ws + o); o += (size_t)NCONS*sizeof(int);
  int* CNTVI = (int*)(ws + o); o += (size_t)NVARS*sizeof(int);
  int* OFFC  = (int*)(ws + o); o += (size_t)(NCONS+1)*sizeof(int);
  int* OFFV  = (int*)(ws + o); o += (size_t)(NVARS+1)*sizeof(int);
  int* SRTC  = (int*)(ws + o); o += (size_t)NEDGE*sizeof(int);
  int* SRTV  = (int*)(ws + o); o += (size_t)NEDGE*sizeof(int);
  bf16* EAC  = (bf16*)(ws + o); o += (size_t)NEDGE*sizeof(bf16);
  bf16* EAV  = (bf16*)(ws + o); o += (size_t)NEDGE*sizeof(bf16);

  detect_k<<<1,64,0,stream>>>((const unsigned int*)d_in[0], MODE);
  convert_all_k<<<512,256,0,stream>>>(ca, FBASE, MODE);
  frag_all_k<<<384,256,0,stream>>>(F[17], F[19], F[23], F[25], W1Fb, W2Fb, OW1Fb, OW2Fb);
  frag2_k<<<384,256,0,stream>>>(F[30], FW1H, FW1L, 32, 512, 98304);
  frag2_k<<<256,256,0,stream>>>(F[32], FW2H, FW2L, 8, 128, 65536);

  zero2_k<<<128,256,0,stream>>>(ST, 4096, (float*)CNTCI, NCONS + NVARS);
  hist_k<<<1024,256,0,stream>>>(ei, CNTCI, CNTVI);
  scan_k<<<1,1024,0,stream>>>(CNTCI, OFFC, NCONS);
  scan_k<<<1,1024,0,stream>>>(CNTVI, OFFV, NVARS);
  scat_k<<<1024,256,0,stream>>>(ei, F[1], CNTCI, CNTVI, SRTC, SRTV, EAC, EAV);

  col_stats3_k<<<1024,256,0,stream>>>(F[0], F[2], F[1], ST);
  embed2_k<<<1024,256,0,stream>>>(F[0], F[2], ST, F[3], F[4], F[11], F[12],
                                  F[5], F[6], F[7], F[8],
                                  F[13], F[14], F[15], F[16], CFA, VF0);

  const bf16* lefts[4]  = {VF0, CFB, VF1, CFA};
  const bf16* rights[4] = {CFA, VF0, CFB, VF1};
  bf16*       outs[4]   = {CFB, VF1, CFA, VF2};
  const int*  srts[4]   = {SRTC, SRTV, SRTC, SRTV};
  const bf16* eass[4]   = {EAC, EAV, EAC, EAV};
  const int*  offss[4]  = {OFFC, OFFV, OFFC, OFFV};

  for (int l=0; l<4; ++l){
    float* slot = ST + 36 + l*256;
    float* gslot = ST + 36 + 1024 + l*256;
    msg_csr_k<<<1024,256,0,stream>>>(lefts[l], rights[l], srts[l], eass[l],
                                     ST+16, F[9], F[10], offss[l],
                                     W1Fb + l*8192, W2Fb + l*4096,
                                     F[18] + l*64,
                                     F[17] + (size_t)l*129*64 + 64*64,
                                     F[20] + l*64, AGG, slot, NCONS);
    node_mfma_k<<<782,256,0,stream>>>(AGG, rights[l], slot, F[21]+l*64, F[22]+l*64,
                                      OW1Fb + l*8192, OW2Fb + l*4096,
                                      F[24] + l*64, F[26] + l*64, outs[l], gslot, NCONS);
    if (l == 1 || l == 3){
      bf16* cfbuf = outs[l-1];
      bf16* vfbuf = outs[l];
      int ga = l-1, gb = l;
      float* gsA = ST + 36 + 1024 + ga*256;
      float* gsB = ST + 36 + 1024 + gb*256;
      affine2_k<<<1024,256,0,stream>>>(cfbuf, gsA, vfbuf, gsB,
                                       F[27], F[28], F[29], ga, gb, NCONS);
    }
  }
  final_mfma_k<<<782,256,0,stream>>>(VF0, VF1, VF2,
                                     FW1H, FW1L, FW2H, FW2L,
                                     F[31], F[33], F[34], F[35],
                                     d_out, NVARS, MODE);
}

// Round 15
// 1266.766 us; speedup vs baseline: 1.1434x; 1.0794x over previous
//
#include <hip/hip_runtime.h>
#include <hip/hip_bf16.h>

typedef __hip_bfloat16 bf16;
typedef __attribute__((ext_vector_type(8))) short short8v;
typedef __attribute__((ext_vector_type(4))) float float4v;

#define NCONS 50000
#define NVARS 50000
#define NEDGE 600000

__device__ __forceinline__ float b2f(const bf16 v){ return __bfloat162float(v); }
__device__ __forceinline__ float shflf(float v, int lane){ return __shfl(v, lane, 64); }
__device__ __forceinline__ unsigned short f2b(float v){
  return __builtin_bit_cast(unsigned short, __float2bfloat16(v));
}

// ---- input-dtype sniffer (bf16 pairs vs f32) ----
__global__ void detect_k(const unsigned int* __restrict__ x, int* __restrict__ mode){
  int t = threadIdx.x;
  int hits = 0;
  for (int i=0;i<4;++i){
    unsigned w = x[t*4+i];
    unsigned e = (w>>7)&0xFFu;
    if (e >= 0x70u && e <= 0x8Fu) hits++;
  }
  for (int off=32; off>0; off>>=1) hits += __shfl_down(hits, off);
  if (t==0) *mode = (hits > 128) ? 1 : 0;
}

// ---- convert ALL 36 float inputs to f32 workspace in one launch ----
struct CvtArgs { const void* p[36]; int ofs[37]; };
__global__ void convert_all_k(CvtArgs a, float* __restrict__ dst, const int* __restrict__ mode){
  int m = *mode;
  int i = blockIdx.x*blockDim.x + threadIdx.x;
  int stride = gridDim.x*blockDim.x;
  int total = a.ofs[36];
  for (; i<total; i+=stride){
    int s = 0;
#pragma unroll
    for (int k=1;k<36;++k) s += (i >= a.ofs[k]) ? 1 : 0;
    int off = i - a.ofs[s];
    float v;
    if (m) v = b2f(((const bf16*)a.p[s])[off]);
    else   v = ((const float*)a.p[s])[off];
    dst[i] = v;
  }
}

// ---- zero ST (na floats) and CNT (nb ints) in one launch ----
__global__ void zero2_k(float* __restrict__ a, int na, float* __restrict__ b, int nb){
  int i = blockIdx.x*blockDim.x + threadIdx.x;
  int stride = gridDim.x*blockDim.x;
  for (; i<na+nb; i+=stride){
    if (i < na) a[i] = 0.f;
    else        b[i-na] = 0.f;
  }
}

// ---- CSR build: histogram, 2-block scan (cnt becomes cursor), scatter ----
__global__ void hist_k(const int* __restrict__ ei, int* __restrict__ cntc, int* __restrict__ cntv){
  int i = blockIdx.x*blockDim.x + threadIdx.x;
  int stride = gridDim.x*blockDim.x;
  for (; i<2*NEDGE; i+=stride){
    int id = ei[i];
    if (i < NEDGE) atomicAdd(&cntc[id], 1);
    else           atomicAdd(&cntv[id], 1);
  }
}

// block 0 scans cnt0/offs0[n0], block 1 scans cnt1/offs1[n1]
__global__ void __launch_bounds__(1024) scan2_k(int* __restrict__ cnt0, int* __restrict__ offs0, int n0,
                                                int* __restrict__ cnt1, int* __restrict__ offs1, int n1){
  __shared__ int part[1024];
  int* cnt  = blockIdx.x ? cnt1  : cnt0;
  int* offs = blockIdx.x ? offs1 : offs0;
  int n     = blockIdx.x ? n1    : n0;
  int t = threadIdx.x;
  int chunk = (n + 1023) >> 10;
  int b = t*chunk;
  int e = b + chunk; if (e > n) e = n;
  int s = 0;
  for (int i=b; i<e; ++i) s += cnt[i];
  part[t] = s;
  __syncthreads();
  for (int off=1; off<1024; off<<=1){
    int v = (t >= off) ? part[t-off] : 0;
    __syncthreads();
    part[t] += v;
    __syncthreads();
  }
  int run = (t==0) ? 0 : part[t-1];
  for (int i=b; i<e; ++i){
    int c = cnt[i];
    offs[i] = run; cnt[i] = run;   // cnt becomes cursor
    run += c;
  }
  if (t==1023) offs[n] = part[1023];
}

// scatter: write dst-sorted src ids and dst-sorted bf16 edge attrs directly
__global__ void scat_k(const int* __restrict__ ei, const float* __restrict__ ea,
                       int* __restrict__ curc, int* __restrict__ curv,
                       int* __restrict__ srtc, int* __restrict__ srtv,
                       bf16* __restrict__ eac, bf16* __restrict__ eav){
  int i = blockIdx.x*blockDim.x + threadIdx.x;
  int stride = gridDim.x*blockDim.x;
  for (; i<2*NEDGE; i+=stride){
    int id = ei[i];
    if (i < NEDGE){
      int p = atomicAdd(&curc[id],1);
      srtc[p] = ei[NEDGE+i];                 // variable endpoint
      eac[p] = __float2bfloat16(ea[i]);
    } else {
      int e = i - NEDGE;
      int p = atomicAdd(&curv[id],1);
      srtv[p] = ei[e];                       // constraint endpoint
      eav[p] = __float2bfloat16(ea[e]);
    }
  }
}

// ---- all three input col-stats jobs in one launch; COLS compile-time so
// accumulators stay in REGISTERS (runtime-indexed arrays spill to scratch) ----
template<int COLS>
__device__ __forceinline__ void col_stats_body(const float* __restrict__ x, int rows,
                                               float* __restrict__ sums, int tid, int stride){
  float s[COLS], ss[COLS];
#pragma unroll
  for (int c=0;c<COLS;++c){ s[c]=0.f; ss[c]=0.f; }
  for (int r=tid; r<rows; r+=stride){
#pragma unroll
    for (int c=0;c<COLS;++c){
      float v = x[r*COLS+c];
      s[c]+=v; ss[c]+=v*v;
    }
  }
#pragma unroll
  for (int c=0;c<COLS;++c){
    float a=s[c], b=ss[c];
    for (int off=32; off>0; off>>=1){ a+=__shfl_down(a,off); b+=__shfl_down(b,off); }
    if ((threadIdx.x & 63)==0){ atomicAdd(&sums[c],a); atomicAdd(&sums[COLS+c],b); }
  }
}

__global__ void col_stats3_k(const float* __restrict__ xc, const float* __restrict__ xv,
                             const float* __restrict__ xe, float* __restrict__ ST){
  int b = blockIdx.x;
  if (b < 256)      col_stats_body<3>(xc, NCONS, ST+0,  b*256+threadIdx.x,       256*256);
  else if (b < 512) col_stats_body<5>(xv, NVARS, ST+6,  (b-256)*256+threadIdx.x, 256*256);
  else              col_stats_body<1>(xe, NEDGE, ST+16, (b-512)*256+threadIdx.x, 512*256);
}

// ---- merged embedding for BOTH node sets; input-BN finalize in prologue ----
__global__ void embed2_k(const float* __restrict__ xc, const float* __restrict__ xv,
                         const float* __restrict__ st,
                         const float* __restrict__ cbnw, const float* __restrict__ cbnb,
                         const float* __restrict__ vbnw, const float* __restrict__ vbnb,
                         const float* __restrict__ cW1, const float* __restrict__ cb1,
                         const float* __restrict__ cW2, const float* __restrict__ cb2,
                         const float* __restrict__ vW1, const float* __restrict__ vb1,
                         const float* __restrict__ vW2, const float* __restrict__ vb2,
                         bf16* __restrict__ outc, bf16* __restrict__ outv){
  __shared__ float aff[16];   // consA[3]@0 consB[3]@3 varA[5]@6 varB[5]@11
  {
    int tt = threadIdx.x;
    if (tt < 3){
      float m = st[tt]/(float)NCONS, q = st[3+tt]/(float)NCONS;
      float A = rsqrtf(fmaxf(q - m*m, 0.f) + 1e-5f)*cbnw[tt];
      aff[tt] = A; aff[3+tt] = cbnb[tt] - m*A;
    } else if (tt < 8){
      int c = tt-3;
      float m = st[6+c]/(float)NVARS, q = st[11+c]/(float)NVARS;
      float A = rsqrtf(fmaxf(q - m*m, 0.f) + 1e-5f)*vbnw[c];
      aff[6+c] = A; aff[11+c] = vbnb[c] - m*A;
    }
  }
  __syncthreads();
  int t = threadIdx.x & 63;
  int w = (blockIdx.x*blockDim.x + threadIdx.x) >> 6;
  int nw = (gridDim.x*blockDim.x) >> 6;
  for (int j = w; j < NCONS + NVARS; j += nw){
    bool isv = (j >= NCONS);
    int n = isv ? j - NCONS : j;
    const float* x  = isv ? xv : xc;
    int cin         = isv ? 5 : 3;
    const float* pA = isv ? aff+6 : aff+0;
    const float* pB = isv ? aff+11 : aff+3;
    const float* W1 = isv ? vW1 : cW1;
    const float* b1 = isv ? vb1 : cb1;
    const float* W2 = isv ? vW2 : cW2;
    const float* b2 = isv ? vb2 : cb2;
    bf16* out       = isv ? outv : outc;
    float acc = b1[t];
    for (int k=0;k<cin;++k){
      float xb = x[n*cin+k]*pA[k] + pB[k];
      acc += xb*W1[k*64+t];
    }
    float h1 = fmaxf(acc, 0.f);
    float acc2 = b2[t];
#pragma unroll
    for (int j2=0;j2<64;++j2) acc2 += shflf(h1,j2)*W2[j2*64+t];
    out[n*64+t] = __float2bfloat16(fmaxf(acc2, 0.f));
  }
}

// ---- all 16 conv-weight fragment jobs in one launch ----
__global__ void frag_all_k(const float* __restrict__ fmW1, const float* __restrict__ fmW2,
                           const float* __restrict__ omW1, const float* __restrict__ omW2,
                           unsigned short* __restrict__ W1Fb, unsigned short* __restrict__ W2Fb,
                           unsigned short* __restrict__ OW1Fb, unsigned short* __restrict__ OW2Fb){
  int i = blockIdx.x*blockDim.x + threadIdx.x;
  if (i >= 4*24576) return;
  int l = i / 24576, r = i % 24576;
  const float* src; unsigned short* dst; int e; int skip;
  if (r < 8192){       src = fmW1 + (size_t)l*129*64; dst = W1Fb  + l*8192; e = r;       skip = 64; }
  else if (r < 12288){ src = fmW2 + (size_t)l*64*64;  dst = W2Fb  + l*4096; e = r-8192;  skip = -1; }
  else if (r < 20480){ src = omW1 + (size_t)l*128*64; dst = OW1Fb + l*8192; e = r-12288; skip = -1; }
  else {               src = omW2 + (size_t)l*64*64;  dst = OW2Fb + l*4096; e = r-20480; skip = -1; }
  int j = e & 7, lane = (e>>3)&63, n = (e>>9)&3, kc = e>>11;
  int k = kc*32 + (lane>>4)*8 + j;
  int col = n*16 + (lane&15);
  int srcrow = (skip>=0 && k>=skip) ? k+1 : k;
  dst[e] = f2b(src[srcrow*64 + col]);
}

// ---- hi/lo fragmenter for final-MLP weights ----
__global__ void frag2_k(const float* __restrict__ Wsrc, unsigned short* __restrict__ Whi,
                        unsigned short* __restrict__ Wlo, int ntiles, int ncols, int tot){
  int i = blockIdx.x*blockDim.x + threadIdx.x;
  if (i>=tot) return;
  int j = i & 7, lane = (i>>3)&63, rem = i>>9;
  int nt = rem % ntiles, kc = rem / ntiles;
  int k = kc*32 + (lane>>4)*8 + j;
  int col = nt*16 + (lane&15);
  float w = Wsrc[k*ncols + col];
  unsigned short hi = f2b(w);
  float rec = __builtin_bit_cast(float, (unsigned int)hi << 16);
  Whi[i] = hi;
  Wlo[i] = f2b(w - rec);
}

// ---- CSR MFMA edge-message kernel + fused BN column stats;
// edge-BN finalize computed in prologue from raw sums. ----
__global__ void __launch_bounds__(256) msg_csr_k(
    const bf16* __restrict__ left, const bf16* __restrict__ right,
    const int* __restrict__ srt, const bf16* __restrict__ eas,
    const float* __restrict__ est, const float* __restrict__ ebnw, const float* __restrict__ ebnb,
    const int* __restrict__ offs,
    const unsigned short* __restrict__ W1F, const unsigned short* __restrict__ W2F,
    const float* __restrict__ b1, const float* __restrict__ w1e, const float* __restrict__ b2,
    float* __restrict__ agg, float* __restrict__ slot, int nn)
{
  __shared__ __align__(16) unsigned short w1l[8192];
  __shared__ __align__(16) unsigned short w2l[4096];
  __shared__ __align__(16) unsigned short h1l[4][16*72];
  __shared__ float bstat[128];
  {
    const float4* s1 = (const float4*)W1F; float4* d1 = (float4*)w1l;
    for (int i=threadIdx.x; i<1024; i+=256) d1[i] = s1[i];
    const float4* s2 = (const float4*)W2F; float4* d2 = (float4*)w2l;
    for (int i=threadIdx.x; i<512; i+=256) d2[i] = s2[i];
    if (threadIdx.x < 128) bstat[threadIdx.x] = 0.f;
  }
  __syncthreads();
  const short8v* W1v = (const short8v*)w1l;
  const short8v* W2v = (const short8v*)w2l;
  const unsigned short* rgt = (const unsigned short*)right;
  const unsigned short* lft = (const unsigned short*)left;
  int t = threadIdx.x & 63;
  int wv = threadIdx.x >> 6;
  int gw = (blockIdx.x*blockDim.x + threadIdx.x) >> 6;
  int nw = (gridDim.x*blockDim.x) >> 6;
  int r16 = t & 15, kg = t >> 4;
  float em = est[0]/(float)NEDGE, eq = est[1]/(float)NEDGE;
  float eA = rsqrtf(fmaxf(eq - em*em, 0.f) + 1e-5f)*ebnw[0];
  float eB = ebnb[0] - em*eA;
  float bb1[4], we[4], bb2[4];
#pragma unroll
  for (int n=0;n<4;++n){ bb1[n]=b1[n*16+r16]; we[n]=w1e[n*16+r16]; bb2[n]=b2[n*16+r16]; }
  unsigned short* h1w = &h1l[wv][0];
  float sacc[4] = {0.f,0.f,0.f,0.f}, ssacc[4] = {0.f,0.f,0.f,0.f};

  int chunk = (nn + nw - 1) / nw;
  int nbeg = gw * chunk;
  int nend = nbeg + chunk; if (nend > nn) nend = nn;

  for (int node = nbeg; node < nend; ++node){
    int beg = offs[node], end = offs[node+1];
    int deg = end - beg;
    float4v acc[4];
#pragma unroll
    for (int n=0;n<4;++n) acc[n] = (float4v){0.f,0.f,0.f,0.f};
    if (deg > 0){
      short8v rr0 = *(const short8v*)(rgt + (size_t)node*64 + kg*8);
      short8v rr1 = *(const short8v*)(rgt + (size_t)node*64 + 32 + kg*8);
      float4v crt[4];
#pragma unroll
      for (int n=0;n<4;++n) crt[n] = (float4v){bb1[n],bb1[n],bb1[n],bb1[n]};
#pragma unroll
      for (int n=0;n<4;++n){
        crt[n] = __builtin_amdgcn_mfma_f32_16x16x32_bf16(rr0, W1v[(0+n)*64+t], crt[n], 0,0,0);
        crt[n] = __builtin_amdgcn_mfma_f32_16x16x32_bf16(rr1, W1v[(4+n)*64+t], crt[n], 0,0,0);
      }
      for (int base = beg; base < end; base += 16){
        int idx = base + r16;
        int ic = idx < end ? idx : beg;
        int sI = srt[ic];
        float ef = b2f(eas[ic])*eA + eB;
        short8v al0 = *(const short8v*)(lft + (size_t)sI*64 + kg*8);
        short8v al1 = *(const short8v*)(lft + (size_t)sI*64 + 32 + kg*8);
        float efr[4];
#pragma unroll
        for (int r=0;r<4;++r) efr[r] = shflf(ef, kg*4+r);
        float4v c[4];
#pragma unroll
        for (int n=0;n<4;++n){
#pragma unroll
          for (int r=0;r<4;++r) c[n][r] = crt[n][r] + efr[r]*we[n];
        }
#pragma unroll
        for (int n=0;n<4;++n){
          c[n] = __builtin_amdgcn_mfma_f32_16x16x32_bf16(al0, W1v[( 8+n)*64+t], c[n], 0,0,0);
          c[n] = __builtin_amdgcn_mfma_f32_16x16x32_bf16(al1, W1v[(12+n)*64+t], c[n], 0,0,0);
        }
#pragma unroll
        for (int n=0;n<4;++n){
#pragma unroll
          for (int r=0;r<4;++r)
            h1w[(kg*4+r)*72 + n*16 + r16] = f2b(fmaxf(c[n][r], 0.f));
        }
        asm volatile("s_waitcnt lgkmcnt(0)" ::: "memory");
        __builtin_amdgcn_sched_barrier(0);
        short8v a20 = *(const short8v*)(h1w + r16*72 + kg*8);
        short8v a21 = *(const short8v*)(h1w + r16*72 + 32 + kg*8);
        float4v d[4];
#pragma unroll
        for (int n=0;n<4;++n) d[n] = (float4v){0.f,0.f,0.f,0.f};
#pragma unroll
        for (int n=0;n<4;++n){
          d[n] = __builtin_amdgcn_mfma_f32_16x16x32_bf16(a20, W2v[(0+n)*64+t], d[n], 0,0,0);
          d[n] = __builtin_amdgcn_mfma_f32_16x16x32_bf16(a21, W2v[(4+n)*64+t], d[n], 0,0,0);
        }
#pragma unroll
        for (int r=0;r<4;++r){
          float mrow = (base + kg*4 + r < end) ? 1.f : 0.f;
#pragma unroll
          for (int n=0;n<4;++n) acc[n][r] += mrow * d[n][r];
        }
      }
    }
    float tot[4];
#pragma unroll
    for (int n=0;n<4;++n){
      tot[n] = acc[n][0]+acc[n][1]+acc[n][2]+acc[n][3];
      tot[n] += __shfl_xor(tot[n], 16, 64);
      tot[n] += __shfl_xor(tot[n], 32, 64);
    }
    if (kg == 0){
      float inv = (deg>0) ? 1.f/(float)deg : 0.f;
#pragma unroll
      for (int n=0;n<4;++n){
        float val = (deg>0) ? tot[n]*inv + bb2[n] : 0.f;
        agg[(size_t)node*64 + n*16 + r16] = val;
        sacc[n] += val; ssacc[n] += val*val;
      }
    }
  }
  if (kg == 0){
#pragma unroll
    for (int n=0;n<4;++n){
      atomicAdd(&bstat[n*16+r16], sacc[n]);
      atomicAdd(&bstat[64+n*16+r16], ssacc[n]);
    }
  }
  __syncthreads();
  if (threadIdx.x < 128) atomicAdd(&slot[threadIdx.x], bstat[threadIdx.x]);
}

// ---- MFMA node-output MLP + fused GraphNorm stats; BN finalize in prologue ----
__global__ void __launch_bounds__(256) node_mfma_k(
    const float* __restrict__ agg, const bf16* __restrict__ right,
    const float* __restrict__ slot, const float* __restrict__ bnw, const float* __restrict__ bnb,
    const unsigned short* __restrict__ W1F, const unsigned short* __restrict__ W2F,
    const float* __restrict__ b1, const float* __restrict__ b2,
    bf16* __restrict__ out, float* __restrict__ gslot, int nn)
{
  __shared__ __align__(16) unsigned short w1l[8192];
  __shared__ __align__(16) unsigned short w2l[4096];
  __shared__ __align__(16) unsigned short h1l[4][16*72];
  __shared__ float bstat[128];
  __shared__ float bnAB[128];
  {
    const float4* s1 = (const float4*)W1F; float4* d1 = (float4*)w1l;
    for (int i=threadIdx.x; i<1024; i+=256) d1[i] = s1[i];
    const float4* s2 = (const float4*)W2F; float4* d2 = (float4*)w2l;
    for (int i=threadIdx.x; i<512; i+=256) d2[i] = s2[i];
    if (threadIdx.x < 128) bstat[threadIdx.x] = 0.f;
    if (threadIdx.x < 64){
      int c = threadIdx.x;
      float m = slot[c]/(float)NCONS, q = slot[64+c]/(float)NCONS;
      float A = rsqrtf(fmaxf(q - m*m, 0.f) + 1e-5f) * bnw[c];
      bnAB[c] = A; bnAB[64+c] = bnb[c] - m*A;
    }
  }
  __syncthreads();
  const short8v* W1v = (const short8v*)w1l;
  const short8v* W2v = (const short8v*)w2l;
  const unsigned short* rgt = (const unsigned short*)right;
  int t = threadIdx.x & 63;
  int wv = threadIdx.x >> 6;
  int gw = (blockIdx.x*blockDim.x + threadIdx.x) >> 6;
  int nw = (gridDim.x*blockDim.x) >> 6;
  int r16 = t & 15, kg = t >> 4;
  float pA0[8], pB0[8], pA1[8], pB1[8];
#pragma unroll
  for (int j=0;j<8;++j){
    pA0[j]=bnAB[kg*8+j];    pB0[j]=bnAB[64+kg*8+j];
    pA1[j]=bnAB[32+kg*8+j]; pB1[j]=bnAB[96+kg*8+j];
  }
  float bb1[4], bb2[4];
#pragma unroll
  for (int n=0;n<4;++n){ bb1[n]=b1[n*16+r16]; bb2[n]=b2[n*16+r16]; }
  unsigned short* h1w = &h1l[wv][0];
  float sacc[4] = {0.f,0.f,0.f,0.f}, ssacc[4] = {0.f,0.f,0.f,0.f};

  for (int g = gw*16; g < nn; g += nw*16){
    int node = g + r16;
    const float* ag = agg + (size_t)node*64;
    float4 f0 = *(const float4*)(ag + kg*8);
    float4 f1 = *(const float4*)(ag + kg*8 + 4);
    float4 f2 = *(const float4*)(ag + 32 + kg*8);
    float4 f3 = *(const float4*)(ag + 32 + kg*8 + 4);
    float v0[8] = {f0.x,f0.y,f0.z,f0.w,f1.x,f1.y,f1.z,f1.w};
    float v1[8] = {f2.x,f2.y,f2.z,f2.w,f3.x,f3.y,f3.z,f3.w};
    short8v ap0, ap1;
#pragma unroll
    for (int j=0;j<8;++j){
      ((unsigned short*)&ap0)[j] = f2b(v0[j]*pA0[j] + pB0[j]);
      ((unsigned short*)&ap1)[j] = f2b(v1[j]*pA1[j] + pB1[j]);
    }
    short8v ar0 = *(const short8v*)(rgt + (size_t)node*64 + kg*8);
    short8v ar1 = *(const short8v*)(rgt + (size_t)node*64 + 32 + kg*8);
    float4v c[4];
#pragma unroll
    for (int n=0;n<4;++n) c[n] = (float4v){bb1[n],bb1[n],bb1[n],bb1[n]};
#pragma unroll
    for (int n=0;n<4;++n){
      c[n] = __builtin_amdgcn_mfma_f32_16x16x32_bf16(ap0, W1v[( 0+n)*64+t], c[n], 0,0,0);
      c[n] = __builtin_amdgcn_mfma_f32_16x16x32_bf16(ap1, W1v[( 4+n)*64+t], c[n], 0,0,0);
      c[n] = __builtin_amdgcn_mfma_f32_16x16x32_bf16(ar0, W1v[( 8+n)*64+t], c[n], 0,0,0);
      c[n] = __builtin_amdgcn_mfma_f32_16x16x32_bf16(ar1, W1v[(12+n)*64+t], c[n], 0,0,0);
    }
#pragma unroll
    for (int n=0;n<4;++n){
#pragma unroll
      for (int r=0;r<4;++r)
        h1w[(kg*4+r)*72 + n*16 + r16] = f2b(fmaxf(c[n][r], 0.f));
    }
    asm volatile("s_waitcnt lgkmcnt(0)" ::: "memory");
    __builtin_amdgcn_sched_barrier(0);
    short8v a20 = *(const short8v*)(h1w + r16*72 + kg*8);
    short8v a21 = *(const short8v*)(h1w + r16*72 + 32 + kg*8);
    float4v d[4];
#pragma unroll
    for (int n=0;n<4;++n) d[n] = (float4v){bb2[n],bb2[n],bb2[n],bb2[n]};
#pragma unroll
    for (int n=0;n<4;++n){
      d[n] = __builtin_amdgcn_mfma_f32_16x16x32_bf16(a20, W2v[(0+n)*64+t], d[n], 0,0,0);
      d[n] = __builtin_amdgcn_mfma_f32_16x16x32_bf16(a21, W2v[(4+n)*64+t], d[n], 0,0,0);
    }
    unsigned short* op = (unsigned short*)out;
#pragma unroll
    for (int r=0;r<4;++r){
      size_t base = (size_t)(g + kg*4 + r)*64 + r16;
#pragma unroll
      for (int n=0;n<4;++n){
        float val = d[n][r];
        op[base + n*16] = f2b(val);
        sacc[n] += val; ssacc[n] += val*val;
      }
    }
  }
#pragma unroll
  for (int n=0;n<4;++n){
    atomicAdd(&bstat[n*16+r16], sacc[n]);
    atomicAdd(&bstat[64+n*16+r16], ssacc[n]);
  }
  __syncthreads();
  if (threadIdx.x < 128) atomicAdd(&gslot[threadIdx.x], bstat[threadIdx.x]);
}

// ---- graphnorm apply on both buffers; GN finalize in prologue ----
__global__ void affine2_k(bf16* __restrict__ x1, const float* __restrict__ s1,
                          bf16* __restrict__ x2, const float* __restrict__ s2,
                          const float* __restrict__ gw, const float* __restrict__ gb,
                          const float* __restrict__ gal, int ga, int gb2, int nn){
  __shared__ float ab[256];   // s1A 0-63, s1B 64-127, s2A 128-191, s2B 192-255
  {
    int tt = threadIdx.x;
    if (tt < 128){
      const float* sl = (tt < 64) ? s1 : s2;
      int g = (tt < 64) ? ga : gb2;
      int c = tt & 63;
      float m = sl[c]/(float)NCONS, q = sl[64+c]/(float)NCONS;
      float a = gal[g*64+c];
      float var = q - 2.f*a*m*m + a*a*m*m;
      float A = rsqrtf(fmaxf(var, 0.f) + 1e-5f) * gw[g*64+c];
      ab[(tt<64?0:128)+c] = A;
      ab[(tt<64?64:192)+c] = gb[g*64+c] - a*m*A;
    }
  }
  __syncthreads();
  int i = blockIdx.x*blockDim.x + threadIdx.x;
  int stride = gridDim.x*blockDim.x;
  int tot = nn*64;
  for (; i<2*tot; i+=stride){
    if (i < tot){
      int c = i & 63;
      x1[i] = __float2bfloat16(b2f(x1[i])*ab[c] + ab[64+c]);
    } else {
      int j = i - tot;
      int c = j & 63;
      x2[j] = __float2bfloat16(b2f(x2[j])*ab[128+c] + ab[192+c]);
    }
  }
}

// ---- MFMA final MLP, race-free (one 16-node tile per wave, __syncthreads) ----
__global__ void __launch_bounds__(256) final_mfma_k(
    const bf16* __restrict__ vf0, const bf16* __restrict__ vf1, const bf16* __restrict__ vf2,
    const unsigned short* __restrict__ W1hi, const unsigned short* __restrict__ W1lo,
    const unsigned short* __restrict__ W2hi, const unsigned short* __restrict__ W2lo,
    const float* __restrict__ B1, const float* __restrict__ B2,
    const float* __restrict__ W3, const float* __restrict__ B3,
    void* __restrict__ out, int nn, const int* __restrict__ mode)
{
  __shared__ float h1l[4][16*260];
  const short8v* W1h = (const short8v*)W1hi;
  const short8v* W1l = (const short8v*)W1lo;
  const short8v* W2h = (const short8v*)W2hi;
  const short8v* W2l = (const short8v*)W2lo;
  const unsigned short* v0p = (const unsigned short*)vf0;
  const unsigned short* v1p = (const unsigned short*)vf1;
  const unsigned short* v2p = (const unsigned short*)vf2;
  int t = threadIdx.x & 63;
  int wv = threadIdx.x >> 6;
  int r16 = t & 15, kg = t >> 4;
  int tile = blockIdx.x*4 + wv;
  bool act = (tile*16 < nn);
  int g = act ? tile*16 : 0;
  float* h1w = &h1l[wv][0];
  float b2v[8], w3v[8];
#pragma unroll
  for (int n=0;n<8;++n){ b2v[n] = B2[n*16+r16]; w3v[n] = W3[n*16+r16]; }
  float bb3 = B3[0];
  int md = *mode;

  int node = g + r16;
  short8v A1[6];
  A1[0] = *(const short8v*)(v0p + (size_t)node*64 + kg*8);
  A1[1] = *(const short8v*)(v0p + (size_t)node*64 + 32 + kg*8);
  A1[2] = *(const short8v*)(v1p + (size_t)node*64 + kg*8);
  A1[3] = *(const short8v*)(v1p + (size_t)node*64 + 32 + kg*8);
  A1[4] = *(const short8v*)(v2p + (size_t)node*64 + kg*8);
  A1[5] = *(const short8v*)(v2p + (size_t)node*64 + 32 + kg*8);
  float4v D[8];
#pragma unroll
  for (int n=0;n<8;++n) D[n] = (float4v){b2v[n],b2v[n],b2v[n],b2v[n]};

  for (int half=0; half<2; ++half){
    if (half) __syncthreads();
    for (int nt=0; nt<16; ++nt){
      int ntg = half*16 + nt;
      float bb = B1[ntg*16 + r16];
      float4v C = (float4v){bb,bb,bb,bb};
#pragma unroll
      for (int kc=0; kc<6; ++kc){
        C = __builtin_amdgcn_mfma_f32_16x16x32_bf16(A1[kc], W1h[(kc*32+ntg)*64+t], C, 0,0,0);
        C = __builtin_amdgcn_mfma_f32_16x16x32_bf16(A1[kc], W1l[(kc*32+ntg)*64+t], C, 0,0,0);
      }
#pragma unroll
      for (int r=0;r<4;++r)
        h1w[(kg*4+r)*260 + nt*16 + r16] = fmaxf(C[r], 0.f);
    }
    __syncthreads();
    short8v Ahi[8], Alo[8];
#pragma unroll
    for (int kc=0; kc<8; ++kc){
      const float* hp = h1w + r16*260 + kc*32 + kg*8;
      float4 x0 = *(const float4*)(hp);
      float4 x1 = *(const float4*)(hp+4);
      float vv[8] = {x0.x,x0.y,x0.z,x0.w,x1.x,x1.y,x1.z,x1.w};
#pragma unroll
      for (int j=0;j<8;++j){
        unsigned short hi = f2b(vv[j]);
        float rec = __builtin_bit_cast(float, (unsigned int)hi<<16);
        ((unsigned short*)&Ahi[kc])[j] = hi;
        ((unsigned short*)&Alo[kc])[j] = f2b(vv[j] - rec);
      }
    }
#pragma unroll
    for (int nt2=0; nt2<8; ++nt2){
#pragma unroll
      for (int kc=0; kc<8; ++kc){
        int kcg = half*8 + kc;
        short8v bh = W2h[(kcg*8+nt2)*64+t];
        D[nt2] = __builtin_amdgcn_mfma_f32_16x16x32_bf16(Ahi[kc], bh, D[nt2], 0,0,0);
        D[nt2] = __builtin_amdgcn_mfma_f32_16x16x32_bf16(Alo[kc], bh, D[nt2], 0,0,0);
        D[nt2] = __builtin_amdgcn_mfma_f32_16x16x32_bf16(Ahi[kc], W2l[(kcg*8+nt2)*64+t], D[nt2], 0,0,0);
      }
    }
  }
  float part[4] = {0.f,0.f,0.f,0.f};
#pragma unroll
  for (int n=0;n<8;++n){
#pragma unroll
    for (int r=0;r<4;++r) part[r] += fmaxf(D[n][r],0.f)*w3v[n];
  }
#pragma unroll
  for (int r=0;r<4;++r){
#pragma unroll
    for (int off=1; off<16; off<<=1) part[r] += __shfl_xor(part[r], off, 64);
  }
  if (act && r16==0){
#pragma unroll
    for (int r=0;r<4;++r){
      int node_o = g + kg*4 + r;
      float val = part[r] + bb3;
      if (md) ((bf16*)out)[node_o] = __float2bfloat16(val);
      else    ((float*)out)[node_o] = val;
    }
  }
}

extern "C" void kernel_launch(void* const* d_in, const int* in_sizes, int n_in,
                              void* d_out, int out_size, void* d_ws, size_t ws_size,
                              hipStream_t stream){
  const int* ei = (const int*)d_in[36];

  char* ws = (char*)d_ws;
  float* ST = (float*)ws;                       // 4096 floats = 16 KB
  int* MODE = (int*)(ws + 16384);
  float* FBASE = (float*)(ws + 32768);
  CvtArgs ca;
  float* F[36];
  {
    int off = 0;
    for (int i=0;i<36;++i){
      ca.p[i] = d_in[i];
      ca.ofs[i] = off;
      F[i] = FBASE + off;
      off += in_sizes[i];
    }
    ca.ofs[36] = off;
  }
  unsigned short* W1Fb  = (unsigned short*)(ws + 7u*1024*1024);
  unsigned short* W2Fb  = W1Fb + 4*8192;
  unsigned short* OW1Fb = W2Fb + 4*4096;
  unsigned short* OW2Fb = OW1Fb + 4*8192;
  unsigned short* FW1H  = OW2Fb + 4*4096;
  unsigned short* FW1L  = FW1H + 98304;
  unsigned short* FW2H  = FW1L + 98304;
  unsigned short* FW2L  = FW2H + 65536;
  size_t o = 8u*1024*1024;
  float* AGG = (float*)(ws + o); o += (size_t)NCONS*64*sizeof(float);
  bf16* CFA = (bf16*)(ws + o); o += (size_t)NCONS*64*sizeof(bf16);
  bf16* CFB = (bf16*)(ws + o); o += (size_t)NCONS*64*sizeof(bf16);
  bf16* VF0 = (bf16*)(ws + o); o += (size_t)NVARS*64*sizeof(bf16);
  bf16* VF1 = (bf16*)(ws + o); o += (size_t)NVARS*64*sizeof(bf16);
  bf16* VF2 = (bf16*)(ws + o); o += (size_t)NVARS*64*sizeof(bf16);
  int* CNTCI = (int*)(ws + o); o += (size_t)NCONS*sizeof(int);
  int* CNTVI = (int*)(ws + o); o += (size_t)NVARS*sizeof(int);
  int* OFFC  = (int*)(ws + o); o += (size_t)(NCONS+1)*sizeof(int);
  int* OFFV  = (int*)(ws + o); o += (size_t)(NVARS+1)*sizeof(int);
  int* SRTC  = (int*)(ws + o); o += (size_t)NEDGE*sizeof(int);
  int* SRTV  = (int*)(ws + o); o += (size_t)NEDGE*sizeof(int);
  bf16* EAC  = (bf16*)(ws + o); o += (size_t)NEDGE*sizeof(bf16);
  bf16* EAV  = (bf16*)(ws + o); o += (size_t)NEDGE*sizeof(bf16);

  detect_k<<<1,64,0,stream>>>((const unsigned int*)d_in[0], MODE);
  convert_all_k<<<512,256,0,stream>>>(ca, FBASE, MODE);
  frag_all_k<<<384,256,0,stream>>>(F[17], F[19], F[23], F[25], W1Fb, W2Fb, OW1Fb, OW2Fb);
  frag2_k<<<384,256,0,stream>>>(F[30], FW1H, FW1L, 32, 512, 98304);
  frag2_k<<<256,256,0,stream>>>(F[32], FW2H, FW2L, 8, 128, 65536);

  zero2_k<<<128,256,0,stream>>>(ST, 4096, (float*)CNTCI, NCONS + NVARS);
  hist_k<<<1024,256,0,stream>>>(ei, CNTCI, CNTVI);
  scan2_k<<<2,1024,0,stream>>>(CNTCI, OFFC, NCONS, CNTVI, OFFV, NVARS);
  scat_k<<<1024,256,0,stream>>>(ei, F[1], CNTCI, CNTVI, SRTC, SRTV, EAC, EAV);

  col_stats3_k<<<1024,256,0,stream>>>(F[0], F[2], F[1], ST);
  embed2_k<<<1024,256,0,stream>>>(F[0], F[2], ST, F[3], F[4], F[11], F[12],
                                  F[5], F[6], F[7], F[8],
                                  F[13], F[14], F[15], F[16], CFA, VF0);

  const bf16* lefts[4]  = {VF0, CFB, VF1, CFA};
  const bf16* rights[4] = {CFA, VF0, CFB, VF1};
  bf16*       outs[4]   = {CFB, VF1, CFA, VF2};
  const int*  srts[4]   = {SRTC, SRTV, SRTC, SRTV};
  const bf16* eass[4]   = {EAC, EAV, EAC, EAV};
  const int*  offss[4]  = {OFFC, OFFV, OFFC, OFFV};

  for (int l=0; l<4; ++l){
    float* slot = ST + 36 + l*256;
    float* gslot = ST + 36 + 1024 + l*256;
    msg_csr_k<<<1024,256,0,stream>>>(lefts[l], rights[l], srts[l], eass[l],
                                     ST+16, F[9], F[10], offss[l],
                                     W1Fb + l*8192, W2Fb + l*4096,
                                     F[18] + l*64,
                                     F[17] + (size_t)l*129*64 + 64*64,
                                     F[20] + l*64, AGG, slot, NCONS);
    node_mfma_k<<<782,256,0,stream>>>(AGG, rights[l], slot, F[21]+l*64, F[22]+l*64,
                                      OW1Fb + l*8192, OW2Fb + l*4096,
                                      F[24] + l*64, F[26] + l*64, outs[l], gslot, NCONS);
    if (l == 1 || l == 3){
      bf16* cfbuf = outs[l-1];
      bf16* vfbuf = outs[l];
      int ga = l-1, gb = l;
      float* gsA = ST + 36 + 1024 + ga*256;
      float* gsB = ST + 36 + 1024 + gb*256;
      affine2_k<<<1024,256,0,stream>>>(cfbuf, gsA, vfbuf, gsB,
                                       F[27], F[28], F[29], ga, gb, NCONS);
    }
  }
  final_mfma_k<<<782,256,0,stream>>>(VF0, VF1, VF2,
                                     FW1H, FW1L, FW2H, FW2L,
                                     F[31], F[33], F[34], F[35],
                                     d_out, NVARS, MODE);
}

// Round 16
// 1058.303 us; speedup vs baseline: 1.3687x; 1.1970x over previous
//
#include <hip/hip_runtime.h>
#include <hip/hip_bf16.h>

typedef __hip_bfloat16 bf16;
typedef __attribute__((ext_vector_type(8))) short short8v;
typedef __attribute__((ext_vector_type(4))) float float4v;

#define NCONS 50000
#define NVARS 50000
#define NEDGE 600000

__device__ __forceinline__ float b2f(const bf16 v){ return __bfloat162float(v); }
__device__ __forceinline__ float shflf(float v, int lane){ return __shfl(v, lane, 64); }
__device__ __forceinline__ unsigned short f2b(float v){
  return __builtin_bit_cast(unsigned short, __float2bfloat16(v));
}

// ---- input-dtype sniffer (bf16 pairs vs f32) ----
__global__ void detect_k(const unsigned int* __restrict__ x, int* __restrict__ mode){
  int t = threadIdx.x;
  int hits = 0;
  for (int i=0;i<4;++i){
    unsigned w = x[t*4+i];
    unsigned e = (w>>7)&0xFFu;
    if (e >= 0x70u && e <= 0x8Fu) hits++;
  }
  for (int off=32; off>0; off>>=1) hits += __shfl_down(hits, off);
  if (t==0) *mode = (hits > 128) ? 1 : 0;
}

// ---- convert ALL 36 float inputs to f32 workspace in one launch ----
struct CvtArgs { const void* p[36]; int ofs[37]; };
__global__ void convert_all_k(CvtArgs a, float* __restrict__ dst, const int* __restrict__ mode){
  int m = *mode;
  int i = blockIdx.x*blockDim.x + threadIdx.x;
  int stride = gridDim.x*blockDim.x;
  int total = a.ofs[36];
  for (; i<total; i+=stride){
    int s = 0;
#pragma unroll
    for (int k=1;k<36;++k) s += (i >= a.ofs[k]) ? 1 : 0;
    int off = i - a.ofs[s];
    float v;
    if (m) v = b2f(((const bf16*)a.p[s])[off]);
    else   v = ((const float*)a.p[s])[off];
    dst[i] = v;
  }
}

// ---- zero ST (na floats) and CNT (nb ints) in one launch ----
__global__ void zero2_k(float* __restrict__ a, int na, float* __restrict__ b, int nb){
  int i = blockIdx.x*blockDim.x + threadIdx.x;
  int stride = gridDim.x*blockDim.x;
  for (; i<na+nb; i+=stride){
    if (i < na) a[i] = 0.f;
    else        b[i-na] = 0.f;
  }
}

// ---- CSR build: histogram, 2-block scan (cnt becomes cursor), scatter ----
__global__ void hist_k(const int* __restrict__ ei, int* __restrict__ cntc, int* __restrict__ cntv){
  int i = blockIdx.x*blockDim.x + threadIdx.x;
  int stride = gridDim.x*blockDim.x;
  for (; i<2*NEDGE; i+=stride){
    int id = ei[i];
    if (i < NEDGE) atomicAdd(&cntc[id], 1);
    else           atomicAdd(&cntv[id], 1);
  }
}

// block 0 scans cnt0/offs0[n0], block 1 scans cnt1/offs1[n1]
__global__ void __launch_bounds__(1024) scan2_k(int* __restrict__ cnt0, int* __restrict__ offs0, int n0,
                                                int* __restrict__ cnt1, int* __restrict__ offs1, int n1){
  __shared__ int part[1024];
  int* cnt  = blockIdx.x ? cnt1  : cnt0;
  int* offs = blockIdx.x ? offs1 : offs0;
  int n     = blockIdx.x ? n1    : n0;
  int t = threadIdx.x;
  int chunk = (n + 1023) >> 10;
  int b = t*chunk;
  int e = b + chunk; if (e > n) e = n;
  int s = 0;
  for (int i=b; i<e; ++i) s += cnt[i];
  part[t] = s;
  __syncthreads();
  for (int off=1; off<1024; off<<=1){
    int v = (t >= off) ? part[t-off] : 0;
    __syncthreads();
    part[t] += v;
    __syncthreads();
  }
  int run = (t==0) ? 0 : part[t-1];
  for (int i=b; i<e; ++i){
    int c = cnt[i];
    offs[i] = run; cnt[i] = run;   // cnt becomes cursor
    run += c;
  }
  if (t==1023) offs[n] = part[1023];
}

// scatter: write dst-sorted src ids and dst-sorted bf16 edge attrs directly
__global__ void scat_k(const int* __restrict__ ei, const float* __restrict__ ea,
                       int* __restrict__ curc, int* __restrict__ curv,
                       int* __restrict__ srtc, int* __restrict__ srtv,
                       bf16* __restrict__ eac, bf16* __restrict__ eav){
  int i = blockIdx.x*blockDim.x + threadIdx.x;
  int stride = gridDim.x*blockDim.x;
  for (; i<2*NEDGE; i+=stride){
    int id = ei[i];
    if (i < NEDGE){
      int p = atomicAdd(&curc[id],1);
      srtc[p] = ei[NEDGE+i];                 // variable endpoint
      eac[p] = __float2bfloat16(ea[i]);
    } else {
      int e = i - NEDGE;
      int p = atomicAdd(&curv[id],1);
      srtv[p] = ei[e];                       // constraint endpoint
      eav[p] = __float2bfloat16(ea[e]);
    }
  }
}

// ---- input col-stats: wave reduce -> block LDS reduce -> ONE atomic per
// block per address (same-address atomic chains were 2048-deep = 212 us) ----
template<int COLS>
__device__ __forceinline__ void col_stats_body(const float* __restrict__ x, int rows,
                                               float* __restrict__ sums, int tid, int stride,
                                               float* __restrict__ red){
  float s[COLS], ss[COLS];
#pragma unroll
  for (int c=0;c<COLS;++c){ s[c]=0.f; ss[c]=0.f; }
  for (int r=tid; r<rows; r+=stride){
#pragma unroll
    for (int c=0;c<COLS;++c){
      float v = x[r*COLS+c];
      s[c]+=v; ss[c]+=v*v;
    }
  }
#pragma unroll
  for (int c=0;c<COLS;++c){
    for (int off=32; off>0; off>>=1){ s[c]+=__shfl_down(s[c],off); ss[c]+=__shfl_down(ss[c],off); }
  }
  int wv = threadIdx.x >> 6;
  if ((threadIdx.x & 63)==0){
#pragma unroll
    for (int c=0;c<COLS;++c){ red[wv*2*COLS+c]=s[c]; red[wv*2*COLS+COLS+c]=ss[c]; }
  }
  __syncthreads();
  if (threadIdx.x < 2*COLS){
    float v = red[threadIdx.x] + red[2*COLS+threadIdx.x]
            + red[4*COLS+threadIdx.x] + red[6*COLS+threadIdx.x];
    atomicAdd(&sums[threadIdx.x], v);
  }
}

__global__ void col_stats3_k(const float* __restrict__ xc, const float* __restrict__ xv,
                             const float* __restrict__ xe, float* __restrict__ ST){
  __shared__ float red[40];
  int b = blockIdx.x;
  if (b < 32)       col_stats_body<3>(xc, NCONS, ST+0,  b*256+threadIdx.x,      32*256, red);
  else if (b < 64)  col_stats_body<5>(xv, NVARS, ST+6,  (b-32)*256+threadIdx.x, 32*256, red);
  else              col_stats_body<1>(xe, NEDGE, ST+16, (b-64)*256+threadIdx.x, 64*256, red);
}

// ---- merged embedding for BOTH node sets; input-BN finalize in prologue ----
__global__ void embed2_k(const float* __restrict__ xc, const float* __restrict__ xv,
                         const float* __restrict__ st,
                         const float* __restrict__ cbnw, const float* __restrict__ cbnb,
                         const float* __restrict__ vbnw, const float* __restrict__ vbnb,
                         const float* __restrict__ cW1, const float* __restrict__ cb1,
                         const float* __restrict__ cW2, const float* __restrict__ cb2,
                         const float* __restrict__ vW1, const float* __restrict__ vb1,
                         const float* __restrict__ vW2, const float* __restrict__ vb2,
                         bf16* __restrict__ outc, bf16* __restrict__ outv){
  __shared__ float aff[16];   // consA[3]@0 consB[3]@3 varA[5]@6 varB[5]@11
  {
    int tt = threadIdx.x;
    if (tt < 3){
      float m = st[tt]/(float)NCONS, q = st[3+tt]/(float)NCONS;
      float A = rsqrtf(fmaxf(q - m*m, 0.f) + 1e-5f)*cbnw[tt];
      aff[tt] = A; aff[3+tt] = cbnb[tt] - m*A;
    } else if (tt < 8){
      int c = tt-3;
      float m = st[6+c]/(float)NVARS, q = st[11+c]/(float)NVARS;
      float A = rsqrtf(fmaxf(q - m*m, 0.f) + 1e-5f)*vbnw[c];
      aff[6+c] = A; aff[11+c] = vbnb[c] - m*A;
    }
  }
  __syncthreads();
  int t = threadIdx.x & 63;
  int w = (blockIdx.x*blockDim.x + threadIdx.x) >> 6;
  int nw = (gridDim.x*blockDim.x) >> 6;
  for (int j = w; j < NCONS + NVARS; j += nw){
    bool isv = (j >= NCONS);
    int n = isv ? j - NCONS : j;
    const float* x  = isv ? xv : xc;
    int cin         = isv ? 5 : 3;
    const float* pA = isv ? aff+6 : aff+0;
    const float* pB = isv ? aff+11 : aff+3;
    const float* W1 = isv ? vW1 : cW1;
    const float* b1 = isv ? vb1 : cb1;
    const float* W2 = isv ? vW2 : cW2;
    const float* b2 = isv ? vb2 : cb2;
    bf16* out       = isv ? outv : outc;
    float acc = b1[t];
    for (int k=0;k<cin;++k){
      float xb = x[n*cin+k]*pA[k] + pB[k];
      acc += xb*W1[k*64+t];
    }
    float h1 = fmaxf(acc, 0.f);
    float acc2 = b2[t];
#pragma unroll
    for (int j2=0;j2<64;++j2) acc2 += shflf(h1,j2)*W2[j2*64+t];
    out[n*64+t] = __float2bfloat16(fmaxf(acc2, 0.f));
  }
}

// ---- all 16 conv-weight fragment jobs in one launch ----
__global__ void frag_all_k(const float* __restrict__ fmW1, const float* __restrict__ fmW2,
                           const float* __restrict__ omW1, const float* __restrict__ omW2,
                           unsigned short* __restrict__ W1Fb, unsigned short* __restrict__ W2Fb,
                           unsigned short* __restrict__ OW1Fb, unsigned short* __restrict__ OW2Fb){
  int i = blockIdx.x*blockDim.x + threadIdx.x;
  if (i >= 4*24576) return;
  int l = i / 24576, r = i % 24576;
  const float* src; unsigned short* dst; int e; int skip;
  if (r < 8192){       src = fmW1 + (size_t)l*129*64; dst = W1Fb  + l*8192; e = r;       skip = 64; }
  else if (r < 12288){ src = fmW2 + (size_t)l*64*64;  dst = W2Fb  + l*4096; e = r-8192;  skip = -1; }
  else if (r < 20480){ src = omW1 + (size_t)l*128*64; dst = OW1Fb + l*8192; e = r-12288; skip = -1; }
  else {               src = omW2 + (size_t)l*64*64;  dst = OW2Fb + l*4096; e = r-20480; skip = -1; }
  int j = e & 7, lane = (e>>3)&63, n = (e>>9)&3, kc = e>>11;
  int k = kc*32 + (lane>>4)*8 + j;
  int col = n*16 + (lane&15);
  int srcrow = (skip>=0 && k>=skip) ? k+1 : k;
  dst[e] = f2b(src[srcrow*64 + col]);
}

// ---- hi/lo fragmenter for final-MLP weights ----
__global__ void frag2_k(const float* __restrict__ Wsrc, unsigned short* __restrict__ Whi,
                        unsigned short* __restrict__ Wlo, int ntiles, int ncols, int tot){
  int i = blockIdx.x*blockDim.x + threadIdx.x;
  if (i>=tot) return;
  int j = i & 7, lane = (i>>3)&63, rem = i>>9;
  int nt = rem % ntiles, kc = rem / ntiles;
  int k = kc*32 + (lane>>4)*8 + j;
  int col = nt*16 + (lane&15);
  float w = Wsrc[k*ncols + col];
  unsigned short hi = f2b(w);
  float rec = __builtin_bit_cast(float, (unsigned int)hi << 16);
  Whi[i] = hi;
  Wlo[i] = f2b(w - rec);
}

// ---- CSR MFMA edge-message kernel + fused BN column stats;
// edge-BN finalize computed in prologue from raw sums. ----
__global__ void __launch_bounds__(256) msg_csr_k(
    const bf16* __restrict__ left, const bf16* __restrict__ right,
    const int* __restrict__ srt, const bf16* __restrict__ eas,
    const float* __restrict__ est, const float* __restrict__ ebnw, const float* __restrict__ ebnb,
    const int* __restrict__ offs,
    const unsigned short* __restrict__ W1F, const unsigned short* __restrict__ W2F,
    const float* __restrict__ b1, const float* __restrict__ w1e, const float* __restrict__ b2,
    float* __restrict__ agg, float* __restrict__ slot, int nn)
{
  __shared__ __align__(16) unsigned short w1l[8192];
  __shared__ __align__(16) unsigned short w2l[4096];
  __shared__ __align__(16) unsigned short h1l[4][16*72];
  __shared__ float bstat[128];
  {
    const float4* s1 = (const float4*)W1F; float4* d1 = (float4*)w1l;
    for (int i=threadIdx.x; i<1024; i+=256) d1[i] = s1[i];
    const float4* s2 = (const float4*)W2F; float4* d2 = (float4*)w2l;
    for (int i=threadIdx.x; i<512; i+=256) d2[i] = s2[i];
    if (threadIdx.x < 128) bstat[threadIdx.x] = 0.f;
  }
  __syncthreads();
  const short8v* W1v = (const short8v*)w1l;
  const short8v* W2v = (const short8v*)w2l;
  const unsigned short* rgt = (const unsigned short*)right;
  const unsigned short* lft = (const unsigned short*)left;
  int t = threadIdx.x & 63;
  int wv = threadIdx.x >> 6;
  int gw = (blockIdx.x*blockDim.x + threadIdx.x) >> 6;
  int nw = (gridDim.x*blockDim.x) >> 6;
  int r16 = t & 15, kg = t >> 4;
  float em = est[0]/(float)NEDGE, eq = est[1]/(float)NEDGE;
  float eA = rsqrtf(fmaxf(eq - em*em, 0.f) + 1e-5f)*ebnw[0];
  float eB = ebnb[0] - em*eA;
  float bb1[4], we[4], bb2[4];
#pragma unroll
  for (int n=0;n<4;++n){ bb1[n]=b1[n*16+r16]; we[n]=w1e[n*16+r16]; bb2[n]=b2[n*16+r16]; }
  unsigned short* h1w = &h1l[wv][0];
  float sacc[4] = {0.f,0.f,0.f,0.f}, ssacc[4] = {0.f,0.f,0.f,0.f};

  int chunk = (nn + nw - 1) / nw;
  int nbeg = gw * chunk;
  int nend = nbeg + chunk; if (nend > nn) nend = nn;

  for (int node = nbeg; node < nend; ++node){
    int beg = offs[node], end = offs[node+1];
    int deg = end - beg;
    float4v acc[4];
#pragma unroll
    for (int n=0;n<4;++n) acc[n] = (float4v){0.f,0.f,0.f,0.f};
    if (deg > 0){
      short8v rr0 = *(const short8v*)(rgt + (size_t)node*64 + kg*8);
      short8v rr1 = *(const short8v*)(rgt + (size_t)node*64 + 32 + kg*8);
      float4v crt[4];
#pragma unroll
      for (int n=0;n<4;++n) crt[n] = (float4v){bb1[n],bb1[n],bb1[n],bb1[n]};
#pragma unroll
      for (int n=0;n<4;++n){
        crt[n] = __builtin_amdgcn_mfma_f32_16x16x32_bf16(rr0, W1v[(0+n)*64+t], crt[n], 0,0,0);
        crt[n] = __builtin_amdgcn_mfma_f32_16x16x32_bf16(rr1, W1v[(4+n)*64+t], crt[n], 0,0,0);
      }
      for (int base = beg; base < end; base += 16){
        int idx = base + r16;
        int ic = idx < end ? idx : beg;
        int sI = srt[ic];
        float ef = b2f(eas[ic])*eA + eB;
        short8v al0 = *(const short8v*)(lft + (size_t)sI*64 + kg*8);
        short8v al1 = *(const short8v*)(lft + (size_t)sI*64 + 32 + kg*8);
        float efr[4];
#pragma unroll
        for (int r=0;r<4;++r) efr[r] = shflf(ef, kg*4+r);
        float4v c[4];
#pragma unroll
        for (int n=0;n<4;++n){
#pragma unroll
          for (int r=0;r<4;++r) c[n][r] = crt[n][r] + efr[r]*we[n];
        }
#pragma unroll
        for (int n=0;n<4;++n){
          c[n] = __builtin_amdgcn_mfma_f32_16x16x32_bf16(al0, W1v[( 8+n)*64+t], c[n], 0,0,0);
          c[n] = __builtin_amdgcn_mfma_f32_16x16x32_bf16(al1, W1v[(12+n)*64+t], c[n], 0,0,0);
        }
#pragma unroll
        for (int n=0;n<4;++n){
#pragma unroll
          for (int r=0;r<4;++r)
            h1w[(kg*4+r)*72 + n*16 + r16] = f2b(fmaxf(c[n][r], 0.f));
        }
        asm volatile("s_waitcnt lgkmcnt(0)" ::: "memory");
        __builtin_amdgcn_sched_barrier(0);
        short8v a20 = *(const short8v*)(h1w + r16*72 + kg*8);
        short8v a21 = *(const short8v*)(h1w + r16*72 + 32 + kg*8);
        float4v d[4];
#pragma unroll
        for (int n=0;n<4;++n) d[n] = (float4v){0.f,0.f,0.f,0.f};
#pragma unroll
        for (int n=0;n<4;++n){
          d[n] = __builtin_amdgcn_mfma_f32_16x16x32_bf16(a20, W2v[(0+n)*64+t], d[n], 0,0,0);
          d[n] = __builtin_amdgcn_mfma_f32_16x16x32_bf16(a21, W2v[(4+n)*64+t], d[n], 0,0,0);
        }
#pragma unroll
        for (int r=0;r<4;++r){
          float mrow = (base + kg*4 + r < end) ? 1.f : 0.f;
#pragma unroll
          for (int n=0;n<4;++n) acc[n][r] += mrow * d[n][r];
        }
      }
    }
    float tot[4];
#pragma unroll
    for (int n=0;n<4;++n){
      tot[n] = acc[n][0]+acc[n][1]+acc[n][2]+acc[n][3];
      tot[n] += __shfl_xor(tot[n], 16, 64);
      tot[n] += __shfl_xor(tot[n], 32, 64);
    }
    if (kg == 0){
      float inv = (deg>0) ? 1.f/(float)deg : 0.f;
#pragma unroll
      for (int n=0;n<4;++n){
        float val = (deg>0) ? tot[n]*inv + bb2[n] : 0.f;
        agg[(size_t)node*64 + n*16 + r16] = val;
        sacc[n] += val; ssacc[n] += val*val;
      }
    }
  }
  if (kg == 0){
#pragma unroll
    for (int n=0;n<4;++n){
      atomicAdd(&bstat[n*16+r16], sacc[n]);
      atomicAdd(&bstat[64+n*16+r16], ssacc[n]);
    }
  }
  __syncthreads();
  if (threadIdx.x < 128) atomicAdd(&slot[threadIdx.x], bstat[threadIdx.x]);
}

// ---- MFMA node-output MLP + fused GraphNorm stats; BN finalize in prologue ----
__global__ void __launch_bounds__(256) node_mfma_k(
    const float* __restrict__ agg, const bf16* __restrict__ right,
    const float* __restrict__ slot, const float* __restrict__ bnw, const float* __restrict__ bnb,
    const unsigned short* __restrict__ W1F, const unsigned short* __restrict__ W2F,
    const float* __restrict__ b1, const float* __restrict__ b2,
    bf16* __restrict__ out, float* __restrict__ gslot, int nn)
{
  __shared__ __align__(16) unsigned short w1l[8192];
  __shared__ __align__(16) unsigned short w2l[4096];
  __shared__ __align__(16) unsigned short h1l[4][16*72];
  __shared__ float bstat[128];
  __shared__ float bnAB[128];
  {
    const float4* s1 = (const float4*)W1F; float4* d1 = (float4*)w1l;
    for (int i=threadIdx.x; i<1024; i+=256) d1[i] = s1[i];
    const float4* s2 = (const float4*)W2F; float4* d2 = (float4*)w2l;
    for (int i=threadIdx.x; i<512; i+=256) d2[i] = s2[i];
    if (threadIdx.x < 128) bstat[threadIdx.x] = 0.f;
    if (threadIdx.x < 64){
      int c = threadIdx.x;
      float m = slot[c]/(float)NCONS, q = slot[64+c]/(float)NCONS;
      float A = rsqrtf(fmaxf(q - m*m, 0.f) + 1e-5f) * bnw[c];
      bnAB[c] = A; bnAB[64+c] = bnb[c] - m*A;
    }
  }
  __syncthreads();
  const short8v* W1v = (const short8v*)w1l;
  const short8v* W2v = (const short8v*)w2l;
  const unsigned short* rgt = (const unsigned short*)right;
  int t = threadIdx.x & 63;
  int wv = threadIdx.x >> 6;
  int gw = (blockIdx.x*blockDim.x + threadIdx.x) >> 6;
  int nw = (gridDim.x*blockDim.x) >> 6;
  int r16 = t & 15, kg = t >> 4;
  float pA0[8], pB0[8], pA1[8], pB1[8];
#pragma unroll
  for (int j=0;j<8;++j){
    pA0[j]=bnAB[kg*8+j];    pB0[j]=bnAB[64+kg*8+j];
    pA1[j]=bnAB[32+kg*8+j]; pB1[j]=bnAB[96+kg*8+j];
  }
  float bb1[4], bb2[4];
#pragma unroll
  for (int n=0;n<4;++n){ bb1[n]=b1[n*16+r16]; bb2[n]=b2[n*16+r16]; }
  unsigned short* h1w = &h1l[wv][0];
  float sacc[4] = {0.f,0.f,0.f,0.f}, ssacc[4] = {0.f,0.f,0.f,0.f};

  for (int g = gw*16; g < nn; g += nw*16){
    int node = g + r16;
    const float* ag = agg + (size_t)node*64;
    float4 f0 = *(const float4*)(ag + kg*8);
    float4 f1 = *(const float4*)(ag + kg*8 + 4);
    float4 f2 = *(const float4*)(ag + 32 + kg*8);
    float4 f3 = *(const float4*)(ag + 32 + kg*8 + 4);
    float v0[8] = {f0.x,f0.y,f0.z,f0.w,f1.x,f1.y,f1.z,f1.w};
    float v1[8] = {f2.x,f2.y,f2.z,f2.w,f3.x,f3.y,f3.z,f3.w};
    short8v ap0, ap1;
#pragma unroll
    for (int j=0;j<8;++j){
      ((unsigned short*)&ap0)[j] = f2b(v0[j]*pA0[j] + pB0[j]);
      ((unsigned short*)&ap1)[j] = f2b(v1[j]*pA1[j] + pB1[j]);
    }
    short8v ar0 = *(const short8v*)(rgt + (size_t)node*64 + kg*8);
    short8v ar1 = *(const short8v*)(rgt + (size_t)node*64 + 32 + kg*8);
    float4v c[4];
#pragma unroll
    for (int n=0;n<4;++n) c[n] = (float4v){bb1[n],bb1[n],bb1[n],bb1[n]};
#pragma unroll
    for (int n=0;n<4;++n){
      c[n] = __builtin_amdgcn_mfma_f32_16x16x32_bf16(ap0, W1v[( 0+n)*64+t], c[n], 0,0,0);
      c[n] = __builtin_amdgcn_mfma_f32_16x16x32_bf16(ap1, W1v[( 4+n)*64+t], c[n], 0,0,0);
      c[n] = __builtin_amdgcn_mfma_f32_16x16x32_bf16(ar0, W1v[( 8+n)*64+t], c[n], 0,0,0);
      c[n] = __builtin_amdgcn_mfma_f32_16x16x32_bf16(ar1, W1v[(12+n)*64+t], c[n], 0,0,0);
    }
#pragma unroll
    for (int n=0;n<4;++n){
#pragma unroll
      for (int r=0;r<4;++r)
        h1w[(kg*4+r)*72 + n*16 + r16] = f2b(fmaxf(c[n][r], 0.f));
    }
    asm volatile("s_waitcnt lgkmcnt(0)" ::: "memory");
    __builtin_amdgcn_sched_barrier(0);
    short8v a20 = *(const short8v*)(h1w + r16*72 + kg*8);
    short8v a21 = *(const short8v*)(h1w + r16*72 + 32 + kg*8);
    float4v d[4];
#pragma unroll
    for (int n=0;n<4;++n) d[n] = (float4v){bb2[n],bb2[n],bb2[n],bb2[n]};
#pragma unroll
    for (int n=0;n<4;++n){
      d[n] = __builtin_amdgcn_mfma_f32_16x16x32_bf16(a20, W2v[(0+n)*64+t], d[n], 0,0,0);
      d[n] = __builtin_amdgcn_mfma_f32_16x16x32_bf16(a21, W2v[(4+n)*64+t], d[n], 0,0,0);
    }
    unsigned short* op = (unsigned short*)out;
#pragma unroll
    for (int r=0;r<4;++r){
      size_t base = (size_t)(g + kg*4 + r)*64 + r16;
#pragma unroll
      for (int n=0;n<4;++n){
        float val = d[n][r];
        op[base + n*16] = f2b(val);
        sacc[n] += val; ssacc[n] += val*val;
      }
    }
  }
#pragma unroll
  for (int n=0;n<4;++n){
    atomicAdd(&bstat[n*16+r16], sacc[n]);
    atomicAdd(&bstat[64+n*16+r16], ssacc[n]);
  }
  __syncthreads();
  if (threadIdx.x < 128) atomicAdd(&gslot[threadIdx.x], bstat[threadIdx.x]);
}

// ---- graphnorm apply on both buffers; GN finalize in prologue ----
__global__ void affine2_k(bf16* __restrict__ x1, const float* __restrict__ s1,
                          bf16* __restrict__ x2, const float* __restrict__ s2,
                          const float* __restrict__ gw, const float* __restrict__ gb,
                          const float* __restrict__ gal, int ga, int gb2, int nn){
  __shared__ float ab[256];   // s1A 0-63, s1B 64-127, s2A 128-191, s2B 192-255
  {
    int tt = threadIdx.x;
    if (tt < 128){
      const float* sl = (tt < 64) ? s1 : s2;
      int g = (tt < 64) ? ga : gb2;
      int c = tt & 63;
      float m = sl[c]/(float)NCONS, q = sl[64+c]/(float)NCONS;
      float a = gal[g*64+c];
      float var = q - 2.f*a*m*m + a*a*m*m;
      float A = rsqrtf(fmaxf(var, 0.f) + 1e-5f) * gw[g*64+c];
      ab[(tt<64?0:128)+c] = A;
      ab[(tt<64?64:192)+c] = gb[g*64+c] - a*m*A;
    }
  }
  __syncthreads();
  int i = blockIdx.x*blockDim.x + threadIdx.x;
  int stride = gridDim.x*blockDim.x;
  int tot = nn*64;
  for (; i<2*tot; i+=stride){
    if (i < tot){
      int c = i & 63;
      x1[i] = __float2bfloat16(b2f(x1[i])*ab[c] + ab[64+c]);
    } else {
      int j = i - tot;
      int c = j & 63;
      x2[j] = __float2bfloat16(b2f(x2[j])*ab[128+c] + ab[192+c]);
    }
  }
}

// ---- MFMA final MLP, race-free (one 16-node tile per wave, __syncthreads) ----
__global__ void __launch_bounds__(256) final_mfma_k(
    const bf16* __restrict__ vf0, const bf16* __restrict__ vf1, const bf16* __restrict__ vf2,
    const unsigned short* __restrict__ W1hi, const unsigned short* __restrict__ W1lo,
    const unsigned short* __restrict__ W2hi, const unsigned short* __restrict__ W2lo,
    const float* __restrict__ B1, const float* __restrict__ B2,
    const float* __restrict__ W3, const float* __restrict__ B3,
    void* __restrict__ out, int nn, const int* __restrict__ mode)
{
  __shared__ float h1l[4][16*260];
  const short8v* W1h = (const short8v*)W1hi;
  const short8v* W1l = (const short8v*)W1lo;
  const short8v* W2h = (const short8v*)W2hi;
  const short8v* W2l = (const short8v*)W2lo;
  const unsigned short* v0p = (const unsigned short*)vf0;
  const unsigned short* v1p = (const unsigned short*)vf1;
  const unsigned short* v2p = (const unsigned short*)vf2;
  int t = threadIdx.x & 63;
  int wv = threadIdx.x >> 6;
  int r16 = t & 15, kg = t >> 4;
  int tile = blockIdx.x*4 + wv;
  bool act = (tile*16 < nn);
  int g = act ? tile*16 : 0;
  float* h1w = &h1l[wv][0];
  float b2v[8], w3v[8];
#pragma unroll
  for (int n=0;n<8;++n){ b2v[n] = B2[n*16+r16]; w3v[n] = W3[n*16+r16]; }
  float bb3 = B3[0];
  int md = *mode;

  int node = g + r16;
  short8v A1[6];
  A1[0] = *(const short8v*)(v0p + (size_t)node*64 + kg*8);
  A1[1] = *(const short8v*)(v0p + (size_t)node*64 + 32 + kg*8);
  A1[2] = *(const short8v*)(v1p + (size_t)node*64 + kg*8);
  A1[3] = *(const short8v*)(v1p + (size_t)node*64 + 32 + kg*8);
  A1[4] = *(const short8v*)(v2p + (size_t)node*64 + kg*8);
  A1[5] = *(const short8v*)(v2p + (size_t)node*64 + 32 + kg*8);
  float4v D[8];
#pragma unroll
  for (int n=0;n<8;++n) D[n] = (float4v){b2v[n],b2v[n],b2v[n],b2v[n]};

  for (int half=0; half<2; ++half){
    if (half) __syncthreads();
    for (int nt=0; nt<16; ++nt){
      int ntg = half*16 + nt;
      float bb = B1[ntg*16 + r16];
      float4v C = (float4v){bb,bb,bb,bb};
#pragma unroll
      for (int kc=0; kc<6; ++kc){
        C = __builtin_amdgcn_mfma_f32_16x16x32_bf16(A1[kc], W1h[(kc*32+ntg)*64+t], C, 0,0,0);
        C = __builtin_amdgcn_mfma_f32_16x16x32_bf16(A1[kc], W1l[(kc*32+ntg)*64+t], C, 0,0,0);
      }
#pragma unroll
      for (int r=0;r<4;++r)
        h1w[(kg*4+r)*260 + nt*16 + r16] = fmaxf(C[r], 0.f);
    }
    __syncthreads();
    short8v Ahi[8], Alo[8];
#pragma unroll
    for (int kc=0; kc<8; ++kc){
      const float* hp = h1w + r16*260 + kc*32 + kg*8;
      float4 x0 = *(const float4*)(hp);
      float4 x1 = *(const float4*)(hp+4);
      float vv[8] = {x0.x,x0.y,x0.z,x0.w,x1.x,x1.y,x1.z,x1.w};
#pragma unroll
      for (int j=0;j<8;++j){
        unsigned short hi = f2b(vv[j]);
        float rec = __builtin_bit_cast(float, (unsigned int)hi<<16);
        ((unsigned short*)&Ahi[kc])[j] = hi;
        ((unsigned short*)&Alo[kc])[j] = f2b(vv[j] - rec);
      }
    }
#pragma unroll
    for (int nt2=0; nt2<8; ++nt2){
#pragma unroll
      for (int kc=0; kc<8; ++kc){
        int kcg = half*8 + kc;
        short8v bh = W2h[(kcg*8+nt2)*64+t];
        D[nt2] = __builtin_amdgcn_mfma_f32_16x16x32_bf16(Ahi[kc], bh, D[nt2], 0,0,0);
        D[nt2] = __builtin_amdgcn_mfma_f32_16x16x32_bf16(Alo[kc], bh, D[nt2], 0,0,0);
        D[nt2] = __builtin_amdgcn_mfma_f32_16x16x32_bf16(Ahi[kc], W2l[(kcg*8+nt2)*64+t], D[nt2], 0,0,0);
      }
    }
  }
  float part[4] = {0.f,0.f,0.f,0.f};
#pragma unroll
  for (int n=0;n<8;++n){
#pragma unroll
    for (int r=0;r<4;++r) part[r] += fmaxf(D[n][r],0.f)*w3v[n];
  }
#pragma unroll
  for (int r=0;r<4;++r){
#pragma unroll
    for (int off=1; off<16; off<<=1) part[r] += __shfl_xor(part[r], off, 64);
  }
  if (act && r16==0){
#pragma unroll
    for (int r=0;r<4;++r){
      int node_o = g + kg*4 + r;
      float val = part[r] + bb3;
      if (md) ((bf16*)out)[node_o] = __float2bfloat16(val);
      else    ((float*)out)[node_o] = val;
    }
  }
}

extern "C" void kernel_launch(void* const* d_in, const int* in_sizes, int n_in,
                              void* d_out, int out_size, void* d_ws, size_t ws_size,
                              hipStream_t stream){
  const int* ei = (const int*)d_in[36];

  char* ws = (char*)d_ws;
  float* ST = (float*)ws;                       // 4096 floats = 16 KB
  int* MODE = (int*)(ws + 16384);
  float* FBASE = (float*)(ws + 32768);
  CvtArgs ca;
  float* F[36];
  {
    int off = 0;
    for (int i=0;i<36;++i){
      ca.p[i] = d_in[i];
      ca.ofs[i] = off;
      F[i] = FBASE + off;
      off += in_sizes[i];
    }
    ca.ofs[36] = off;
  }
  unsigned short* W1Fb  = (unsigned short*)(ws + 7u*1024*1024);
  unsigned short* W2Fb  = W1Fb + 4*8192;
  unsigned short* OW1Fb = W2Fb + 4*4096;
  unsigned short* OW2Fb = OW1Fb + 4*8192;
  unsigned short* FW1H  = OW2Fb + 4*4096;
  unsigned short* FW1L  = FW1H + 98304;
  unsigned short* FW2H  = FW1L + 98304;
  unsigned short* FW2L  = FW2H + 65536;
  size_t o = 8u*1024*1024;
  float* AGG = (float*)(ws + o); o += (size_t)NCONS*64*sizeof(float);
  bf16* CFA = (bf16*)(ws + o); o += (size_t)NCONS*64*sizeof(bf16);
  bf16* CFB = (bf16*)(ws + o); o += (size_t)NCONS*64*sizeof(bf16);
  bf16* VF0 = (bf16*)(ws + o); o += (size_t)NVARS*64*sizeof(bf16);
  bf16* VF1 = (bf16*)(ws + o); o += (size_t)NVARS*64*sizeof(bf16);
  bf16* VF2 = (bf16*)(ws + o); o += (size_t)NVARS*64*sizeof(bf16);
  int* CNTCI = (int*)(ws + o); o += (size_t)NCONS*sizeof(int);
  int* CNTVI = (int*)(ws + o); o += (size_t)NVARS*sizeof(int);
  int* OFFC  = (int*)(ws + o); o += (size_t)(NCONS+1)*sizeof(int);
  int* OFFV  = (int*)(ws + o); o += (size_t)(NVARS+1)*sizeof(int);
  int* SRTC  = (int*)(ws + o); o += (size_t)NEDGE*sizeof(int);
  int* SRTV  = (int*)(ws + o); o += (size_t)NEDGE*sizeof(int);
  bf16* EAC  = (bf16*)(ws + o); o += (size_t)NEDGE*sizeof(bf16);
  bf16* EAV  = (bf16*)(ws + o); o += (size_t)NEDGE*sizeof(bf16);

  detect_k<<<1,64,0,stream>>>((const unsigned int*)d_in[0], MODE);
  convert_all_k<<<512,256,0,stream>>>(ca, FBASE, MODE);
  frag_all_k<<<384,256,0,stream>>>(F[17], F[19], F[23], F[25], W1Fb, W2Fb, OW1Fb, OW2Fb);
  frag2_k<<<384,256,0,stream>>>(F[30], FW1H, FW1L, 32, 512, 98304);
  frag2_k<<<256,256,0,stream>>>(F[32], FW2H, FW2L, 8, 128, 65536);

  zero2_k<<<128,256,0,stream>>>(ST, 4096, (float*)CNTCI, NCONS + NVARS);
  hist_k<<<1024,256,0,stream>>>(ei, CNTCI, CNTVI);
  scan2_k<<<2,1024,0,stream>>>(CNTCI, OFFC, NCONS, CNTVI, OFFV, NVARS);
  scat_k<<<1024,256,0,stream>>>(ei, F[1], CNTCI, CNTVI, SRTC, SRTV, EAC, EAV);

  col_stats3_k<<<128,256,0,stream>>>(F[0], F[2], F[1], ST);
  embed2_k<<<1024,256,0,stream>>>(F[0], F[2], ST, F[3], F[4], F[11], F[12],
                                  F[5], F[6], F[7], F[8],
                                  F[13], F[14], F[15], F[16], CFA, VF0);

  const bf16* lefts[4]  = {VF0, CFB, VF1, CFA};
  const bf16* rights[4] = {CFA, VF0, CFB, VF1};
  bf16*       outs[4]   = {CFB, VF1, CFA, VF2};
  const int*  srts[4]   = {SRTC, SRTV, SRTC, SRTV};
  const bf16* eass[4]   = {EAC, EAV, EAC, EAV};
  const int*  offss[4]  = {OFFC, OFFV, OFFC, OFFV};

  for (int l=0; l<4; ++l){
    float* slot = ST + 36 + l*256;
    float* gslot = ST + 36 + 1024 + l*256;
    msg_csr_k<<<1024,256,0,stream>>>(lefts[l], rights[l], srts[l], eass[l],
                                     ST+16, F[9], F[10], offss[l],
                                     W1Fb + l*8192, W2Fb + l*4096,
                                     F[18] + l*64,
                                     F[17] + (size_t)l*129*64 + 64*64,
                                     F[20] + l*64, AGG, slot, NCONS);
    node_mfma_k<<<782,256,0,stream>>>(AGG, rights[l], slot, F[21]+l*64, F[22]+l*64,
                                      OW1Fb + l*8192, OW2Fb + l*4096,
                                      F[24] + l*64, F[26] + l*64, outs[l], gslot, NCONS);
    if (l == 1 || l == 3){
      bf16* cfbuf = outs[l-1];
      bf16* vfbuf = outs[l];
      int ga = l-1, gb = l;
      float* gsA = ST + 36 + 1024 + ga*256;
      float* gsB = ST + 36 + 1024 + gb*256;
      affine2_k<<<1024,256,0,stream>>>(cfbuf, gsA, vfbuf, gsB,
                                       F[27], F[28], F[29], ga, gb, NCONS);
    }
  }
  final_mfma_k<<<782,256,0,stream>>>(VF0, VF1, VF2,
                                     FW1H, FW1L, FW2H, FW2L,
                                     F[31], F[33], F[34], F[35],
                                     d_out, NVARS, MODE);
}

// Round 17
// 985.796 us; speedup vs baseline: 1.4693x; 1.0736x over previous
//
#include <hip/hip_runtime.h>
#include <hip/hip_bf16.h>

typedef __hip_bfloat16 bf16;
typedef __attribute__((ext_vector_type(8))) short short8v;
typedef __attribute__((ext_vector_type(4))) float float4v;

#define NCONS 50000
#define NVARS 50000
#define NEDGE 600000

__device__ __forceinline__ float b2f(const bf16 v){ return __bfloat162float(v); }
__device__ __forceinline__ float shflf(float v, int lane){ return __shfl(v, lane, 64); }
__device__ __forceinline__ unsigned short f2b(float v){
  return __builtin_bit_cast(unsigned short, __float2bfloat16(v));
}

// ---- input-dtype sniffer (bf16 pairs vs f32) ----
__global__ void detect_k(const unsigned int* __restrict__ x, int* __restrict__ mode){
  int t = threadIdx.x;
  int hits = 0;
  for (int i=0;i<4;++i){
    unsigned w = x[t*4+i];
    unsigned e = (w>>7)&0xFFu;
    if (e >= 0x70u && e <= 0x8Fu) hits++;
  }
  for (int off=32; off>0; off>>=1) hits += __shfl_down(hits, off);
  if (t==0) *mode = (hits > 128) ? 1 : 0;
}

// ---- convert ALL 36 float inputs to f32 workspace in one launch ----
struct CvtArgs { const void* p[36]; int ofs[37]; };
__global__ void convert_all_k(CvtArgs a, float* __restrict__ dst, const int* __restrict__ mode){
  int m = *mode;
  int i = blockIdx.x*blockDim.x + threadIdx.x;
  int stride = gridDim.x*blockDim.x;
  int total = a.ofs[36];
  for (; i<total; i+=stride){
    int s = 0;
#pragma unroll
    for (int k=1;k<36;++k) s += (i >= a.ofs[k]) ? 1 : 0;
    int off = i - a.ofs[s];
    float v;
    if (m) v = b2f(((const bf16*)a.p[s])[off]);
    else   v = ((const float*)a.p[s])[off];
    dst[i] = v;
  }
}

// ---- zero ST (na floats) and CNT (nb ints) in one launch ----
__global__ void zero2_k(float* __restrict__ a, int na, float* __restrict__ b, int nb){
  int i = blockIdx.x*blockDim.x + threadIdx.x;
  int stride = gridDim.x*blockDim.x;
  for (; i<na+nb; i+=stride){
    if (i < na) a[i] = 0.f;
    else        b[i-na] = 0.f;
  }
}

// ---- CSR build: histogram, 2-block scan (cnt becomes cursor), scatter ----
__global__ void hist_k(const int* __restrict__ ei, int* __restrict__ cntc, int* __restrict__ cntv){
  int i = blockIdx.x*blockDim.x + threadIdx.x;
  int stride = gridDim.x*blockDim.x;
  for (; i<2*NEDGE; i+=stride){
    int id = ei[i];
    if (i < NEDGE) atomicAdd(&cntc[id], 1);
    else           atomicAdd(&cntv[id], 1);
  }
}

// block 0 scans cnt0/offs0[n0], block 1 scans cnt1/offs1[n1]
__global__ void __launch_bounds__(1024) scan2_k(int* __restrict__ cnt0, int* __restrict__ offs0, int n0,
                                                int* __restrict__ cnt1, int* __restrict__ offs1, int n1){
  __shared__ int part[1024];
  int* cnt  = blockIdx.x ? cnt1  : cnt0;
  int* offs = blockIdx.x ? offs1 : offs0;
  int n     = blockIdx.x ? n1    : n0;
  int t = threadIdx.x;
  int chunk = (n + 1023) >> 10;
  int b = t*chunk;
  int e = b + chunk; if (e > n) e = n;
  int s = 0;
  for (int i=b; i<e; ++i) s += cnt[i];
  part[t] = s;
  __syncthreads();
  for (int off=1; off<1024; off<<=1){
    int v = (t >= off) ? part[t-off] : 0;
    __syncthreads();
    part[t] += v;
    __syncthreads();
  }
  int run = (t==0) ? 0 : part[t-1];
  for (int i=b; i<e; ++i){
    int c = cnt[i];
    offs[i] = run; cnt[i] = run;   // cnt becomes cursor
    run += c;
  }
  if (t==1023) offs[n] = part[1023];
}

// scatter: write dst-sorted src ids and dst-sorted bf16 edge attrs directly
__global__ void scat_k(const int* __restrict__ ei, const float* __restrict__ ea,
                       int* __restrict__ curc, int* __restrict__ curv,
                       int* __restrict__ srtc, int* __restrict__ srtv,
                       bf16* __restrict__ eac, bf16* __restrict__ eav){
  int i = blockIdx.x*blockDim.x + threadIdx.x;
  int stride = gridDim.x*blockDim.x;
  for (; i<2*NEDGE; i+=stride){
    int id = ei[i];
    if (i < NEDGE){
      int p = atomicAdd(&curc[id],1);
      srtc[p] = ei[NEDGE+i];                 // variable endpoint
      eac[p] = __float2bfloat16(ea[i]);
    } else {
      int e = i - NEDGE;
      int p = atomicAdd(&curv[id],1);
      srtv[p] = ei[e];                       // constraint endpoint
      eav[p] = __float2bfloat16(ea[e]);
    }
  }
}

// ---- input col-stats: wave reduce -> block LDS reduce -> ONE atomic per
// block per address ----
template<int COLS>
__device__ __forceinline__ void col_stats_body(const float* __restrict__ x, int rows,
                                               float* __restrict__ sums, int tid, int stride,
                                               float* __restrict__ red){
  float s[COLS], ss[COLS];
#pragma unroll
  for (int c=0;c<COLS;++c){ s[c]=0.f; ss[c]=0.f; }
  for (int r=tid; r<rows; r+=stride){
#pragma unroll
    for (int c=0;c<COLS;++c){
      float v = x[r*COLS+c];
      s[c]+=v; ss[c]+=v*v;
    }
  }
#pragma unroll
  for (int c=0;c<COLS;++c){
    for (int off=32; off>0; off>>=1){ s[c]+=__shfl_down(s[c],off); ss[c]+=__shfl_down(ss[c],off); }
  }
  int wv = threadIdx.x >> 6;
  if ((threadIdx.x & 63)==0){
#pragma unroll
    for (int c=0;c<COLS;++c){ red[wv*2*COLS+c]=s[c]; red[wv*2*COLS+COLS+c]=ss[c]; }
  }
  __syncthreads();
  if (threadIdx.x < 2*COLS){
    float v = red[threadIdx.x] + red[2*COLS+threadIdx.x]
            + red[4*COLS+threadIdx.x] + red[6*COLS+threadIdx.x];
    atomicAdd(&sums[threadIdx.x], v);
  }
}

__global__ void col_stats3_k(const float* __restrict__ xc, const float* __restrict__ xv,
                             const float* __restrict__ xe, float* __restrict__ ST){
  __shared__ float red[40];
  int b = blockIdx.x;
  if (b < 32)       col_stats_body<3>(xc, NCONS, ST+0,  b*256+threadIdx.x,      32*256, red);
  else if (b < 64)  col_stats_body<5>(xv, NVARS, ST+6,  (b-32)*256+threadIdx.x, 32*256, red);
  else              col_stats_body<1>(xe, NEDGE, ST+16, (b-64)*256+threadIdx.x, 64*256, red);
}

// ---- merged embedding for BOTH node sets; input-BN finalize in prologue ----
__global__ void embed2_k(const float* __restrict__ xc, const float* __restrict__ xv,
                         const float* __restrict__ st,
                         const float* __restrict__ cbnw, const float* __restrict__ cbnb,
                         const float* __restrict__ vbnw, const float* __restrict__ vbnb,
                         const float* __restrict__ cW1, const float* __restrict__ cb1,
                         const float* __restrict__ cW2, const float* __restrict__ cb2,
                         const float* __restrict__ vW1, const float* __restrict__ vb1,
                         const float* __restrict__ vW2, const float* __restrict__ vb2,
                         bf16* __restrict__ outc, bf16* __restrict__ outv){
  __shared__ float aff[16];   // consA[3]@0 consB[3]@3 varA[5]@6 varB[5]@11
  {
    int tt = threadIdx.x;
    if (tt < 3){
      float m = st[tt]/(float)NCONS, q = st[3+tt]/(float)NCONS;
      float A = rsqrtf(fmaxf(q - m*m, 0.f) + 1e-5f)*cbnw[tt];
      aff[tt] = A; aff[3+tt] = cbnb[tt] - m*A;
    } else if (tt < 8){
      int c = tt-3;
      float m = st[6+c]/(float)NVARS, q = st[11+c]/(float)NVARS;
      float A = rsqrtf(fmaxf(q - m*m, 0.f) + 1e-5f)*vbnw[c];
      aff[6+c] = A; aff[11+c] = vbnb[c] - m*A;
    }
  }
  __syncthreads();
  int t = threadIdx.x & 63;
  int w = (blockIdx.x*blockDim.x + threadIdx.x) >> 6;
  int nw = (gridDim.x*blockDim.x) >> 6;
  for (int j = w; j < NCONS + NVARS; j += nw){
    bool isv = (j >= NCONS);
    int n = isv ? j - NCONS : j;
    const float* x  = isv ? xv : xc;
    int cin         = isv ? 5 : 3;
    const float* pA = isv ? aff+6 : aff+0;
    const float* pB = isv ? aff+11 : aff+3;
    const float* W1 = isv ? vW1 : cW1;
    const float* b1 = isv ? vb1 : cb1;
    const float* W2 = isv ? vW2 : cW2;
    const float* b2 = isv ? vb2 : cb2;
    bf16* out       = isv ? outv : outc;
    float acc = b1[t];
    for (int k=0;k<cin;++k){
      float xb = x[n*cin+k]*pA[k] + pB[k];
      acc += xb*W1[k*64+t];
    }
    float h1 = fmaxf(acc, 0.f);
    float acc2 = b2[t];
#pragma unroll
    for (int j2=0;j2<64;++j2) acc2 += shflf(h1,j2)*W2[j2*64+t];
    out[n*64+t] = __float2bfloat16(fmaxf(acc2, 0.f));
  }
}

// ---- all 16 conv-weight fragment jobs in one launch ----
__global__ void frag_all_k(const float* __restrict__ fmW1, const float* __restrict__ fmW2,
                           const float* __restrict__ omW1, const float* __restrict__ omW2,
                           unsigned short* __restrict__ W1Fb, unsigned short* __restrict__ W2Fb,
                           unsigned short* __restrict__ OW1Fb, unsigned short* __restrict__ OW2Fb){
  int i = blockIdx.x*blockDim.x + threadIdx.x;
  if (i >= 4*24576) return;
  int l = i / 24576, r = i % 24576;
  const float* src; unsigned short* dst; int e; int skip;
  if (r < 8192){       src = fmW1 + (size_t)l*129*64; dst = W1Fb  + l*8192; e = r;       skip = 64; }
  else if (r < 12288){ src = fmW2 + (size_t)l*64*64;  dst = W2Fb  + l*4096; e = r-8192;  skip = -1; }
  else if (r < 20480){ src = omW1 + (size_t)l*128*64; dst = OW1Fb + l*8192; e = r-12288; skip = -1; }
  else {               src = omW2 + (size_t)l*64*64;  dst = OW2Fb + l*4096; e = r-20480; skip = -1; }
  int j = e & 7, lane = (e>>3)&63, n = (e>>9)&3, kc = e>>11;
  int k = kc*32 + (lane>>4)*8 + j;
  int col = n*16 + (lane&15);
  int srcrow = (skip>=0 && k>=skip) ? k+1 : k;
  dst[e] = f2b(src[srcrow*64 + col]);
}

// ---- hi/lo fragmenter for final-MLP weights ----
__global__ void frag2_k(const float* __restrict__ Wsrc, unsigned short* __restrict__ Whi,
                        unsigned short* __restrict__ Wlo, int ntiles, int ncols, int tot){
  int i = blockIdx.x*blockDim.x + threadIdx.x;
  if (i>=tot) return;
  int j = i & 7, lane = (i>>3)&63, rem = i>>9;
  int nt = rem % ntiles, kc = rem / ntiles;
  int k = kc*32 + (lane>>4)*8 + j;
  int col = nt*16 + (lane&15);
  float w = Wsrc[k*ncols + col];
  unsigned short hi = f2b(w);
  float rec = __builtin_bit_cast(float, (unsigned int)hi << 16);
  Whi[i] = hi;
  Wlo[i] = f2b(w - rec);
}

// ---- CSR MFMA edge-message kernel + fused BN column stats;
// edge-BN finalize computed in prologue from raw sums. ----
__global__ void __launch_bounds__(256) msg_csr_k(
    const bf16* __restrict__ left, const bf16* __restrict__ right,
    const int* __restrict__ srt, const bf16* __restrict__ eas,
    const float* __restrict__ est, const float* __restrict__ ebnw, const float* __restrict__ ebnb,
    const int* __restrict__ offs,
    const unsigned short* __restrict__ W1F, const unsigned short* __restrict__ W2F,
    const float* __restrict__ b1, const float* __restrict__ w1e, const float* __restrict__ b2,
    float* __restrict__ agg, float* __restrict__ slot, int nn)
{
  __shared__ __align__(16) unsigned short w1l[8192];
  __shared__ __align__(16) unsigned short w2l[4096];
  __shared__ __align__(16) unsigned short h1l[4][16*72];
  __shared__ float bstat[128];
  {
    const float4* s1 = (const float4*)W1F; float4* d1 = (float4*)w1l;
    for (int i=threadIdx.x; i<1024; i+=256) d1[i] = s1[i];
    const float4* s2 = (const float4*)W2F; float4* d2 = (float4*)w2l;
    for (int i=threadIdx.x; i<512; i+=256) d2[i] = s2[i];
    if (threadIdx.x < 128) bstat[threadIdx.x] = 0.f;
  }
  __syncthreads();
  const short8v* W1v = (const short8v*)w1l;
  const short8v* W2v = (const short8v*)w2l;
  const unsigned short* rgt = (const unsigned short*)right;
  const unsigned short* lft = (const unsigned short*)left;
  int t = threadIdx.x & 63;
  int wv = threadIdx.x >> 6;
  int gw = (blockIdx.x*blockDim.x + threadIdx.x) >> 6;
  int nw = (gridDim.x*blockDim.x) >> 6;
  int r16 = t & 15, kg = t >> 4;
  float em = est[0]/(float)NEDGE, eq = est[1]/(float)NEDGE;
  float eA = rsqrtf(fmaxf(eq - em*em, 0.f) + 1e-5f)*ebnw[0];
  float eB = ebnb[0] - em*eA;
  float bb1[4], we[4], bb2[4];
#pragma unroll
  for (int n=0;n<4;++n){ bb1[n]=b1[n*16+r16]; we[n]=w1e[n*16+r16]; bb2[n]=b2[n*16+r16]; }
  unsigned short* h1w = &h1l[wv][0];
  float sacc[4] = {0.f,0.f,0.f,0.f}, ssacc[4] = {0.f,0.f,0.f,0.f};

  int chunk = (nn + nw - 1) / nw;
  int nbeg = gw * chunk;
  int nend = nbeg + chunk; if (nend > nn) nend = nn;

  for (int node = nbeg; node < nend; ++node){
    int beg = offs[node], end = offs[node+1];
    int deg = end - beg;
    float4v acc[4];
#pragma unroll
    for (int n=0;n<4;++n) acc[n] = (float4v){0.f,0.f,0.f,0.f};
    if (deg > 0){
      short8v rr0 = *(const short8v*)(rgt + (size_t)node*64 + kg*8);
      short8v rr1 = *(const short8v*)(rgt + (size_t)node*64 + 32 + kg*8);
      float4v crt[4];
#pragma unroll
      for (int n=0;n<4;++n) crt[n] = (float4v){bb1[n],bb1[n],bb1[n],bb1[n]};
#pragma unroll
      for (int n=0;n<4;++n){
        crt[n] = __builtin_amdgcn_mfma_f32_16x16x32_bf16(rr0, W1v[(0+n)*64+t], crt[n], 0,0,0);
        crt[n] = __builtin_amdgcn_mfma_f32_16x16x32_bf16(rr1, W1v[(4+n)*64+t], crt[n], 0,0,0);
      }
      for (int base = beg; base < end; base += 16){
        int idx = base + r16;
        int ic = idx < end ? idx : beg;
        int sI = srt[ic];
        float ef = b2f(eas[ic])*eA + eB;
        short8v al0 = *(const short8v*)(lft + (size_t)sI*64 + kg*8);
        short8v al1 = *(const short8v*)(lft + (size_t)sI*64 + 32 + kg*8);
        float efr[4];
#pragma unroll
        for (int r=0;r<4;++r) efr[r] = shflf(ef, kg*4+r);
        float4v c[4];
#pragma unroll
        for (int n=0;n<4;++n){
#pragma unroll
          for (int r=0;r<4;++r) c[n][r] = crt[n][r] + efr[r]*we[n];
        }
#pragma unroll
        for (int n=0;n<4;++n){
          c[n] = __builtin_amdgcn_mfma_f32_16x16x32_bf16(al0, W1v[( 8+n)*64+t], c[n], 0,0,0);
          c[n] = __builtin_amdgcn_mfma_f32_16x16x32_bf16(al1, W1v[(12+n)*64+t], c[n], 0,0,0);
        }
#pragma unroll
        for (int n=0;n<4;++n){
#pragma unroll
          for (int r=0;r<4;++r)
            h1w[(kg*4+r)*72 + n*16 + r16] = f2b(fmaxf(c[n][r], 0.f));
        }
        asm volatile("s_waitcnt lgkmcnt(0)" ::: "memory");
        __builtin_amdgcn_sched_barrier(0);
        short8v a20 = *(const short8v*)(h1w + r16*72 + kg*8);
        short8v a21 = *(const short8v*)(h1w + r16*72 + 32 + kg*8);
        float4v d[4];
#pragma unroll
        for (int n=0;n<4;++n) d[n] = (float4v){0.f,0.f,0.f,0.f};
#pragma unroll
        for (int n=0;n<4;++n){
          d[n] = __builtin_amdgcn_mfma_f32_16x16x32_bf16(a20, W2v[(0+n)*64+t], d[n], 0,0,0);
          d[n] = __builtin_amdgcn_mfma_f32_16x16x32_bf16(a21, W2v[(4+n)*64+t], d[n], 0,0,0);
        }
#pragma unroll
        for (int r=0;r<4;++r){
          float mrow = (base + kg*4 + r < end) ? 1.f : 0.f;
#pragma unroll
          for (int n=0;n<4;++n) acc[n][r] += mrow * d[n][r];
        }
      }
    }
    float tot[4];
#pragma unroll
    for (int n=0;n<4;++n){
      tot[n] = acc[n][0]+acc[n][1]+acc[n][2]+acc[n][3];
      tot[n] += __shfl_xor(tot[n], 16, 64);
      tot[n] += __shfl_xor(tot[n], 32, 64);
    }
    if (kg == 0){
      float inv = (deg>0) ? 1.f/(float)deg : 0.f;
#pragma unroll
      for (int n=0;n<4;++n){
        float val = (deg>0) ? tot[n]*inv + bb2[n] : 0.f;
        agg[(size_t)node*64 + n*16 + r16] = val;
        sacc[n] += val; ssacc[n] += val*val;
      }
    }
  }
  if (kg == 0){
#pragma unroll
    for (int n=0;n<4;++n){
      atomicAdd(&bstat[n*16+r16], sacc[n]);
      atomicAdd(&bstat[64+n*16+r16], ssacc[n]);
    }
  }
  __syncthreads();
  if (threadIdx.x < 128) atomicAdd(&slot[threadIdx.x], bstat[threadIdx.x]);
}

// ---- MFMA node-output MLP + fused GraphNorm stats; BN finalize in prologue ----
__global__ void __launch_bounds__(256) node_mfma_k(
    const float* __restrict__ agg, const bf16* __restrict__ right,
    const float* __restrict__ slot, const float* __restrict__ bnw, const float* __restrict__ bnb,
    const unsigned short* __restrict__ W1F, const unsigned short* __restrict__ W2F,
    const float* __restrict__ b1, const float* __restrict__ b2,
    bf16* __restrict__ out, float* __restrict__ gslot, int nn)
{
  __shared__ __align__(16) unsigned short w1l[8192];
  __shared__ __align__(16) unsigned short w2l[4096];
  __shared__ __align__(16) unsigned short h1l[4][16*72];
  __shared__ float bstat[128];
  __shared__ float bnAB[128];
  {
    const float4* s1 = (const float4*)W1F; float4* d1 = (float4*)w1l;
    for (int i=threadIdx.x; i<1024; i+=256) d1[i] = s1[i];
    const float4* s2 = (const float4*)W2F; float4* d2 = (float4*)w2l;
    for (int i=threadIdx.x; i<512; i+=256) d2[i] = s2[i];
    if (threadIdx.x < 128) bstat[threadIdx.x] = 0.f;
    if (threadIdx.x < 64){
      int c = threadIdx.x;
      float m = slot[c]/(float)NCONS, q = slot[64+c]/(float)NCONS;
      float A = rsqrtf(fmaxf(q - m*m, 0.f) + 1e-5f) * bnw[c];
      bnAB[c] = A; bnAB[64+c] = bnb[c] - m*A;
    }
  }
  __syncthreads();
  const short8v* W1v = (const short8v*)w1l;
  const short8v* W2v = (const short8v*)w2l;
  const unsigned short* rgt = (const unsigned short*)right;
  int t = threadIdx.x & 63;
  int wv = threadIdx.x >> 6;
  int gw = (blockIdx.x*blockDim.x + threadIdx.x) >> 6;
  int nw = (gridDim.x*blockDim.x) >> 6;
  int r16 = t & 15, kg = t >> 4;
  float pA0[8], pB0[8], pA1[8], pB1[8];
#pragma unroll
  for (int j=0;j<8;++j){
    pA0[j]=bnAB[kg*8+j];    pB0[j]=bnAB[64+kg*8+j];
    pA1[j]=bnAB[32+kg*8+j]; pB1[j]=bnAB[96+kg*8+j];
  }
  float bb1[4], bb2[4];
#pragma unroll
  for (int n=0;n<4;++n){ bb1[n]=b1[n*16+r16]; bb2[n]=b2[n*16+r16]; }
  unsigned short* h1w = &h1l[wv][0];
  float sacc[4] = {0.f,0.f,0.f,0.f}, ssacc[4] = {0.f,0.f,0.f,0.f};

  for (int g = gw*16; g < nn; g += nw*16){
    int node = g + r16;
    const float* ag = agg + (size_t)node*64;
    float4 f0 = *(const float4*)(ag + kg*8);
    float4 f1 = *(const float4*)(ag + kg*8 + 4);
    float4 f2 = *(const float4*)(ag + 32 + kg*8);
    float4 f3 = *(const float4*)(ag + 32 + kg*8 + 4);
    float v0[8] = {f0.x,f0.y,f0.z,f0.w,f1.x,f1.y,f1.z,f1.w};
    float v1[8] = {f2.x,f2.y,f2.z,f2.w,f3.x,f3.y,f3.z,f3.w};
    short8v ap0, ap1;
#pragma unroll
    for (int j=0;j<8;++j){
      ((unsigned short*)&ap0)[j] = f2b(v0[j]*pA0[j] + pB0[j]);
      ((unsigned short*)&ap1)[j] = f2b(v1[j]*pA1[j] + pB1[j]);
    }
    short8v ar0 = *(const short8v*)(rgt + (size_t)node*64 + kg*8);
    short8v ar1 = *(const short8v*)(rgt + (size_t)node*64 + 32 + kg*8);
    float4v c[4];
#pragma unroll
    for (int n=0;n<4;++n) c[n] = (float4v){bb1[n],bb1[n],bb1[n],bb1[n]};
#pragma unroll
    for (int n=0;n<4;++n){
      c[n] = __builtin_amdgcn_mfma_f32_16x16x32_bf16(ap0, W1v[( 0+n)*64+t], c[n], 0,0,0);
      c[n] = __builtin_amdgcn_mfma_f32_16x16x32_bf16(ap1, W1v[( 4+n)*64+t], c[n], 0,0,0);
      c[n] = __builtin_amdgcn_mfma_f32_16x16x32_bf16(ar0, W1v[( 8+n)*64+t], c[n], 0,0,0);
      c[n] = __builtin_amdgcn_mfma_f32_16x16x32_bf16(ar1, W1v[(12+n)*64+t], c[n], 0,0,0);
    }
#pragma unroll
    for (int n=0;n<4;++n){
#pragma unroll
      for (int r=0;r<4;++r)
        h1w[(kg*4+r)*72 + n*16 + r16] = f2b(fmaxf(c[n][r], 0.f));
    }
    asm volatile("s_waitcnt lgkmcnt(0)" ::: "memory");
    __builtin_amdgcn_sched_barrier(0);
    short8v a20 = *(const short8v*)(h1w + r16*72 + kg*8);
    short8v a21 = *(const short8v*)(h1w + r16*72 + 32 + kg*8);
    float4v d[4];
#pragma unroll
    for (int n=0;n<4;++n) d[n] = (float4v){bb2[n],bb2[n],bb2[n],bb2[n]};
#pragma unroll
    for (int n=0;n<4;++n){
      d[n] = __builtin_amdgcn_mfma_f32_16x16x32_bf16(a20, W2v[(0+n)*64+t], d[n], 0,0,0);
      d[n] = __builtin_amdgcn_mfma_f32_16x16x32_bf16(a21, W2v[(4+n)*64+t], d[n], 0,0,0);
    }
    unsigned short* op = (unsigned short*)out;
#pragma unroll
    for (int r=0;r<4;++r){
      size_t base = (size_t)(g + kg*4 + r)*64 + r16;
#pragma unroll
      for (int n=0;n<4;++n){
        float val = d[n][r];
        op[base + n*16] = f2b(val);
        sacc[n] += val; ssacc[n] += val*val;
      }
    }
  }
#pragma unroll
  for (int n=0;n<4;++n){
    atomicAdd(&bstat[n*16+r16], sacc[n]);
    atomicAdd(&bstat[64+n*16+r16], ssacc[n]);
  }
  __syncthreads();
  if (threadIdx.x < 128) atomicAdd(&gslot[threadIdx.x], bstat[threadIdx.x]);
}

// ---- graphnorm apply on both buffers; GN finalize in prologue ----
__global__ void affine2_k(bf16* __restrict__ x1, const float* __restrict__ s1,
                          bf16* __restrict__ x2, const float* __restrict__ s2,
                          const float* __restrict__ gw, const float* __restrict__ gb,
                          const float* __restrict__ gal, int ga, int gb2, int nn){
  __shared__ float ab[256];   // s1A 0-63, s1B 64-127, s2A 128-191, s2B 192-255
  {
    int tt = threadIdx.x;
    if (tt < 128){
      const float* sl = (tt < 64) ? s1 : s2;
      int g = (tt < 64) ? ga : gb2;
      int c = tt & 63;
      float m = sl[c]/(float)NCONS, q = sl[64+c]/(float)NCONS;
      float a = gal[g*64+c];
      float var = q - 2.f*a*m*m + a*a*m*m;
      float A = rsqrtf(fmaxf(var, 0.f) + 1e-5f) * gw[g*64+c];
      ab[(tt<64?0:128)+c] = A;
      ab[(tt<64?64:192)+c] = gb[g*64+c] - a*m*A;
    }
  }
  __syncthreads();
  int i = blockIdx.x*blockDim.x + threadIdx.x;
  int stride = gridDim.x*blockDim.x;
  int tot = nn*64;
  for (; i<2*tot; i+=stride){
    if (i < tot){
      int c = i & 63;
      x1[i] = __float2bfloat16(b2f(x1[i])*ab[c] + ab[64+c]);
    } else {
      int j = i - tot;
      int c = j & 63;
      x2[j] = __float2bfloat16(b2f(x2[j])*ab[128+c] + ab[192+c]);
    }
  }
}

// ---- MFMA final MLP, race-free; QUARTER-split h1 tile (16x132 f32) so LDS
// is 33.8 KB -> 4 blocks/CU resident (was 66.5 KB -> 2; 782-block grid ran
// in two batches). kcg accumulation order unchanged -> bitwise-identical. ----
__global__ void __launch_bounds__(256) final_mfma_k(
    const bf16* __restrict__ vf0, const bf16* __restrict__ vf1, const bf16* __restrict__ vf2,
    const unsigned short* __restrict__ W1hi, const unsigned short* __restrict__ W1lo,
    const unsigned short* __restrict__ W2hi, const unsigned short* __restrict__ W2lo,
    const float* __restrict__ B1, const float* __restrict__ B2,
    const float* __restrict__ W3, const float* __restrict__ B3,
    void* __restrict__ out, int nn, const int* __restrict__ mode)
{
  __shared__ float h1l[4][16*132];   // per-wave 16x128 f32 tile, stride 132
  const short8v* W1h = (const short8v*)W1hi;
  const short8v* W1l = (const short8v*)W1lo;
  const short8v* W2h = (const short8v*)W2hi;
  const short8v* W2l = (const short8v*)W2lo;
  const unsigned short* v0p = (const unsigned short*)vf0;
  const unsigned short* v1p = (const unsigned short*)vf1;
  const unsigned short* v2p = (const unsigned short*)vf2;
  int t = threadIdx.x & 63;
  int wv = threadIdx.x >> 6;
  int r16 = t & 15, kg = t >> 4;
  int tile = blockIdx.x*4 + wv;
  bool act = (tile*16 < nn);
  int g = act ? tile*16 : 0;
  float* h1w = &h1l[wv][0];
  float b2v[8], w3v[8];
#pragma unroll
  for (int n=0;n<8;++n){ b2v[n] = B2[n*16+r16]; w3v[n] = W3[n*16+r16]; }
  float bb3 = B3[0];
  int md = *mode;

  int node = g + r16;
  short8v A1[6];
  A1[0] = *(const short8v*)(v0p + (size_t)node*64 + kg*8);
  A1[1] = *(const short8v*)(v0p + (size_t)node*64 + 32 + kg*8);
  A1[2] = *(const short8v*)(v1p + (size_t)node*64 + kg*8);
  A1[3] = *(const short8v*)(v1p + (size_t)node*64 + 32 + kg*8);
  A1[4] = *(const short8v*)(v2p + (size_t)node*64 + kg*8);
  A1[5] = *(const short8v*)(v2p + (size_t)node*64 + 32 + kg*8);
  float4v D[8];
#pragma unroll
  for (int n=0;n<8;++n) D[n] = (float4v){b2v[n],b2v[n],b2v[n],b2v[n]};

  for (int quarter=0; quarter<4; ++quarter){
    if (quarter) __syncthreads();          // drain previous quarter's reads
    // layer 1: this quarter's 128 output columns, K=192, W = hi+lo
    for (int nt=0; nt<8; ++nt){
      int ntg = quarter*8 + nt;
      float bb = B1[ntg*16 + r16];
      float4v C = (float4v){bb,bb,bb,bb};
#pragma unroll
      for (int kc=0; kc<6; ++kc){
        C = __builtin_amdgcn_mfma_f32_16x16x32_bf16(A1[kc], W1h[(kc*32+ntg)*64+t], C, 0,0,0);
        C = __builtin_amdgcn_mfma_f32_16x16x32_bf16(A1[kc], W1l[(kc*32+ntg)*64+t], C, 0,0,0);
      }
#pragma unroll
      for (int r=0;r<4;++r)
        h1w[(kg*4+r)*132 + nt*16 + r16] = fmaxf(C[r], 0.f);
    }
    __syncthreads();                       // h1 writes visible before transpose read
    short8v Ahi[4], Alo[4];
#pragma unroll
    for (int kc=0; kc<4; ++kc){
      const float* hp = h1w + r16*132 + kc*32 + kg*8;
      float4 x0 = *(const float4*)(hp);
      float4 x1 = *(const float4*)(hp+4);
      float vv[8] = {x0.x,x0.y,x0.z,x0.w,x1.x,x1.y,x1.z,x1.w};
#pragma unroll
      for (int j=0;j<8;++j){
        unsigned short hi = f2b(vv[j]);
        float rec = __builtin_bit_cast(float, (unsigned int)hi<<16);
        ((unsigned short*)&Ahi[kc])[j] = hi;
        ((unsigned short*)&Alo[kc])[j] = f2b(vv[j] - rec);
      }
    }
    // layer 2: this quarter's K-slice of 128, Ahi@Whi + Alo@Whi + Ahi@Wlo
#pragma unroll
    for (int nt2=0; nt2<8; ++nt2){
#pragma unroll
      for (int kc=0; kc<4; ++kc){
        int kcg = quarter*4 + kc;
        short8v bh = W2h[(kcg*8+nt2)*64+t];
        D[nt2] = __builtin_amdgcn_mfma_f32_16x16x32_bf16(Ahi[kc], bh, D[nt2], 0,0,0);
        D[nt2] = __builtin_amdgcn_mfma_f32_16x16x32_bf16(Alo[kc], bh, D[nt2], 0,0,0);
        D[nt2] = __builtin_amdgcn_mfma_f32_16x16x32_bf16(Ahi[kc], W2l[(kcg*8+nt2)*64+t], D[nt2], 0,0,0);
      }
    }
  }
  float part[4] = {0.f,0.f,0.f,0.f};
#pragma unroll
  for (int n=0;n<8;++n){
#pragma unroll
    for (int r=0;r<4;++r) part[r] += fmaxf(D[n][r],0.f)*w3v[n];
  }
#pragma unroll
  for (int r=0;r<4;++r){
#pragma unroll
    for (int off=1; off<16; off<<=1) part[r] += __shfl_xor(part[r], off, 64);
  }
  if (act && r16==0){
#pragma unroll
    for (int r=0;r<4;++r){
      int node_o = g + kg*4 + r;
      float val = part[r] + bb3;
      if (md) ((bf16*)out)[node_o] = __float2bfloat16(val);
      else    ((float*)out)[node_o] = val;
    }
  }
}

extern "C" void kernel_launch(void* const* d_in, const int* in_sizes, int n_in,
                              void* d_out, int out_size, void* d_ws, size_t ws_size,
                              hipStream_t stream){
  const int* ei = (const int*)d_in[36];

  char* ws = (char*)d_ws;
  float* ST = (float*)ws;                       // 4096 floats = 16 KB
  int* MODE = (int*)(ws + 16384);
  float* FBASE = (float*)(ws + 32768);
  CvtArgs ca;
  float* F[36];
  {
    int off = 0;
    for (int i=0;i<36;++i){
      ca.p[i] = d_in[i];
      ca.ofs[i] = off;
      F[i] = FBASE + off;
      off += in_sizes[i];
    }
    ca.ofs[36] = off;
  }
  unsigned short* W1Fb  = (unsigned short*)(ws + 7u*1024*1024);
  unsigned short* W2Fb  = W1Fb + 4*8192;
  unsigned short* OW1Fb = W2Fb + 4*4096;
  unsigned short* OW2Fb = OW1Fb + 4*8192;
  unsigned short* FW1H  = OW2Fb + 4*4096;
  unsigned short* FW1L  = FW1H + 98304;
  unsigned short* FW2H  = FW1L + 98304;
  unsigned short* FW2L  = FW2H + 65536;
  size_t o = 8u*1024*1024;
  float* AGG = (float*)(ws + o); o += (size_t)NCONS*64*sizeof(float);
  bf16* CFA = (bf16*)(ws + o); o += (size_t)NCONS*64*sizeof(bf16);
  bf16* CFB = (bf16*)(ws + o); o += (size_t)NCONS*64*sizeof(bf16);
  bf16* VF0 = (bf16*)(ws + o); o += (size_t)NVARS*64*sizeof(bf16);
  bf16* VF1 = (bf16*)(ws + o); o += (size_t)NVARS*64*sizeof(bf16);
  bf16* VF2 = (bf16*)(ws + o); o += (size_t)NVARS*64*sizeof(bf16);
  int* CNTCI = (int*)(ws + o); o += (size_t)NCONS*sizeof(int);
  int* CNTVI = (int*)(ws + o); o += (size_t)NVARS*sizeof(int);
  int* OFFC  = (int*)(ws + o); o += (size_t)(NCONS+1)*sizeof(int);
  int* OFFV  = (int*)(ws + o); o += (size_t)(NVARS+1)*sizeof(int);
  int* SRTC  = (int*)(ws + o); o += (size_t)NEDGE*sizeof(int);
  int* SRTV  = (int*)(ws + o); o += (size_t)NEDGE*sizeof(int);
  bf16* EAC  = (bf16*)(ws + o); o += (size_t)NEDGE*sizeof(bf16);
  bf16* EAV  = (bf16*)(ws + o); o += (size_t)NEDGE*sizeof(bf16);

  detect_k<<<1,64,0,stream>>>((const unsigned int*)d_in[0], MODE);
  convert_all_k<<<512,256,0,stream>>>(ca, FBASE, MODE);
  frag_all_k<<<384,256,0,stream>>>(F[17], F[19], F[23], F[25], W1Fb, W2Fb, OW1Fb, OW2Fb);
  frag2_k<<<384,256,0,stream>>>(F[30], FW1H, FW1L, 32, 512, 98304);
  frag2_k<<<256,256,0,stream>>>(F[32], FW2H, FW2L, 8, 128, 65536);

  zero2_k<<<128,256,0,stream>>>(ST, 4096, (float*)CNTCI, NCONS + NVARS);
  hist_k<<<1024,256,0,stream>>>(ei, CNTCI, CNTVI);
  scan2_k<<<2,1024,0,stream>>>(CNTCI, OFFC, NCONS, CNTVI, OFFV, NVARS);
  scat_k<<<1024,256,0,stream>>>(ei, F[1], CNTCI, CNTVI, SRTC, SRTV, EAC, EAV);

  col_stats3_k<<<128,256,0,stream>>>(F[0], F[2], F[1], ST);
  embed2_k<<<1024,256,0,stream>>>(F[0], F[2], ST, F[3], F[4], F[11], F[12],
                                  F[5], F[6], F[7], F[8],
                                  F[13], F[14], F[15], F[16], CFA, VF0);

  const bf16* lefts[4]  = {VF0, CFB, VF1, CFA};
  const bf16* rights[4] = {CFA, VF0, CFB, VF1};
  bf16*       outs[4]   = {CFB, VF1, CFA, VF2};
  const int*  srts[4]   = {SRTC, SRTV, SRTC, SRTV};
  const bf16* eass[4]   = {EAC, EAV, EAC, EAV};
  const int*  offss[4]  = {OFFC, OFFV, OFFC, OFFV};

  for (int l=0; l<4; ++l){
    float* slot = ST + 36 + l*256;
    float* gslot = ST + 36 + 1024 + l*256;
    msg_csr_k<<<1024,256,0,stream>>>(lefts[l], rights[l], srts[l], eass[l],
                                     ST+16, F[9], F[10], offss[l],
                                     W1Fb + l*8192, W2Fb + l*4096,
                                     F[18] + l*64,
                                     F[17] + (size_t)l*129*64 + 64*64,
                                     F[20] + l*64, AGG, slot, NCONS);
    node_mfma_k<<<782,256,0,stream>>>(AGG, rights[l], slot, F[21]+l*64, F[22]+l*64,
                                      OW1Fb + l*8192, OW2Fb + l*4096,
                                      F[24] + l*64, F[26] + l*64, outs[l], gslot, NCONS);
    if (l == 1 || l == 3){
      bf16* cfbuf = outs[l-1];
      bf16* vfbuf = outs[l];
      int ga = l-1, gb = l;
      float* gsA = ST + 36 + 1024 + ga*256;
      float* gsB = ST + 36 + 1024 + gb*256;
      affine2_k<<<1024,256,0,stream>>>(cfbuf, gsA, vfbuf, gsB,
                                       F[27], F[28], F[29], ga, gb, NCONS);
    }
  }
  final_mfma_k<<<782,256,0,stream>>>(VF0, VF1, VF2,
                                     FW1H, FW1L, FW2H, FW2L,
                                     F[31], F[33], F[34], F[35],
                                     d_out, NVARS, MODE);
}

// Round 18
// 914.649 us; speedup vs baseline: 1.5836x; 1.0778x over previous
//
#include <hip/hip_runtime.h>
#include <hip/hip_bf16.h>

typedef __hip_bfloat16 bf16;
typedef __attribute__((ext_vector_type(8))) short short8v;
typedef __attribute__((ext_vector_type(4))) float float4v;

#define NCONS 50000
#define NVARS 50000
#define NEDGE 600000

__device__ __forceinline__ float b2f(const bf16 v){ return __bfloat162float(v); }
__device__ __forceinline__ float shflf(float v, int lane){ return __shfl(v, lane, 64); }
__device__ __forceinline__ unsigned short f2b(float v){
  return __builtin_bit_cast(unsigned short, __float2bfloat16(v));
}

// ---- input-dtype sniffer (bf16 pairs vs f32) ----
__global__ void detect_k(const unsigned int* __restrict__ x, int* __restrict__ mode){
  int t = threadIdx.x;
  int hits = 0;
  for (int i=0;i<4;++i){
    unsigned w = x[t*4+i];
    unsigned e = (w>>7)&0xFFu;
    if (e >= 0x70u && e <= 0x8Fu) hits++;
  }
  for (int off=32; off>0; off>>=1) hits += __shfl_down(hits, off);
  if (t==0) *mode = (hits > 128) ? 1 : 0;
}

// ---- convert ALL 36 float inputs to f32 workspace in one launch ----
struct CvtArgs { const void* p[36]; int ofs[37]; };
__global__ void convert_all_k(CvtArgs a, float* __restrict__ dst, const int* __restrict__ mode){
  int m = *mode;
  int i = blockIdx.x*blockDim.x + threadIdx.x;
  int stride = gridDim.x*blockDim.x;
  int total = a.ofs[36];
  for (; i<total; i+=stride){
    int s = 0;
#pragma unroll
    for (int k=1;k<36;++k) s += (i >= a.ofs[k]) ? 1 : 0;
    int off = i - a.ofs[s];
    float v;
    if (m) v = b2f(((const bf16*)a.p[s])[off]);
    else   v = ((const float*)a.p[s])[off];
    dst[i] = v;
  }
}

// ---- zero ST (na floats) and CNT (nb ints) in one launch ----
__global__ void zero2_k(float* __restrict__ a, int na, float* __restrict__ b, int nb){
  int i = blockIdx.x*blockDim.x + threadIdx.x;
  int stride = gridDim.x*blockDim.x;
  for (; i<na+nb; i+=stride){
    if (i < na) a[i] = 0.f;
    else        b[i-na] = 0.f;
  }
}

// ---- CSR build: histogram, 2-block scan (cnt becomes cursor), scatter ----
__global__ void hist_k(const int* __restrict__ ei, int* __restrict__ cntc, int* __restrict__ cntv){
  int i = blockIdx.x*blockDim.x + threadIdx.x;
  int stride = gridDim.x*blockDim.x;
  for (; i<2*NEDGE; i+=stride){
    int id = ei[i];
    if (i < NEDGE) atomicAdd(&cntc[id], 1);
    else           atomicAdd(&cntv[id], 1);
  }
}

// block 0 scans cnt0/offs0[n0], block 1 scans cnt1/offs1[n1].
// int4-vectorized walks: the scalar strided version split every wave load
// into 64 transactions and chained them serially (110 us at 0.02% VALU).
// Requires n % 4 == 0 and 16B-aligned bases (both hold here).
__global__ void __launch_bounds__(1024) scan2_k(int* __restrict__ cnt0, int* __restrict__ offs0, int n0,
                                                int* __restrict__ cnt1, int* __restrict__ offs1, int n1){
  __shared__ int part[1024];
  int* cnt  = blockIdx.x ? cnt1  : cnt0;
  int* offs = blockIdx.x ? offs1 : offs0;
  int n     = blockIdx.x ? n1    : n0;
  int t = threadIdx.x;
  int chunk = (((n + 1023) >> 10) + 3) & ~3;   // per-thread chunk, multiple of 4
  int b = t*chunk;
  int e = b + chunk; if (e > n) e = n;
  int nv4 = (e > b) ? (e - b) >> 2 : 0;        // e-b is a multiple of 4 (n%4==0)
  const int4* c4 = (const int4*)(cnt + b);
  int s = 0;
  for (int i=0;i<nv4;++i){ int4 v = c4[i]; s += v.x+v.y+v.z+v.w; }
  part[t] = s;
  __syncthreads();
  for (int off=1; off<1024; off<<=1){
    int v = (t >= off) ? part[t-off] : 0;
    __syncthreads();
    part[t] += v;
    __syncthreads();
  }
  int run = (t==0) ? 0 : part[t-1];
  int4* o4 = (int4*)(offs + b);
  int4* u4 = (int4*)(cnt + b);
  for (int i=0;i<nv4;++i){
    int4 v = c4[i];
    int4 w;
    w.x = run; run += v.x;
    w.y = run; run += v.y;
    w.z = run; run += v.z;
    w.w = run; run += v.w;
    o4[i] = w;          // offsets
    u4[i] = w;          // cnt becomes cursor
  }
  if (t==1023) offs[n] = part[1023];
}

// scatter: write dst-sorted src ids and dst-sorted bf16 edge attrs directly
__global__ void scat_k(const int* __restrict__ ei, const float* __restrict__ ea,
                       int* __restrict__ curc, int* __restrict__ curv,
                       int* __restrict__ srtc, int* __restrict__ srtv,
                       bf16* __restrict__ eac, bf16* __restrict__ eav){
  int i = blockIdx.x*blockDim.x + threadIdx.x;
  int stride = gridDim.x*blockDim.x;
  for (; i<2*NEDGE; i+=stride){
    int id = ei[i];
    if (i < NEDGE){
      int p = atomicAdd(&curc[id],1);
      srtc[p] = ei[NEDGE+i];                 // variable endpoint
      eac[p] = __float2bfloat16(ea[i]);
    } else {
      int e = i - NEDGE;
      int p = atomicAdd(&curv[id],1);
      srtv[p] = ei[e];                       // constraint endpoint
      eav[p] = __float2bfloat16(ea[e]);
    }
  }
}

// ---- input col-stats: wave reduce -> block LDS reduce -> ONE atomic per
// block per address ----
template<int COLS>
__device__ __forceinline__ void col_stats_body(const float* __restrict__ x, int rows,
                                               float* __restrict__ sums, int tid, int stride,
                                               float* __restrict__ red){
  float s[COLS], ss[COLS];
#pragma unroll
  for (int c=0;c<COLS;++c){ s[c]=0.f; ss[c]=0.f; }
  for (int r=tid; r<rows; r+=stride){
#pragma unroll
    for (int c=0;c<COLS;++c){
      float v = x[r*COLS+c];
      s[c]+=v; ss[c]+=v*v;
    }
  }
#pragma unroll
  for (int c=0;c<COLS;++c){
    for (int off=32; off>0; off>>=1){ s[c]+=__shfl_down(s[c],off); ss[c]+=__shfl_down(ss[c],off); }
  }
  int wv = threadIdx.x >> 6;
  if ((threadIdx.x & 63)==0){
#pragma unroll
    for (int c=0;c<COLS;++c){ red[wv*2*COLS+c]=s[c]; red[wv*2*COLS+COLS+c]=ss[c]; }
  }
  __syncthreads();
  if (threadIdx.x < 2*COLS){
    float v = red[threadIdx.x] + red[2*COLS+threadIdx.x]
            + red[4*COLS+threadIdx.x] + red[6*COLS+threadIdx.x];
    atomicAdd(&sums[threadIdx.x], v);
  }
}

__global__ void col_stats3_k(const float* __restrict__ xc, const float* __restrict__ xv,
                             const float* __restrict__ xe, float* __restrict__ ST){
  __shared__ float red[40];
  int b = blockIdx.x;
  if (b < 32)       col_stats_body<3>(xc, NCONS, ST+0,  b*256+threadIdx.x,      32*256, red);
  else if (b < 64)  col_stats_body<5>(xv, NVARS, ST+6,  (b-32)*256+threadIdx.x, 32*256, red);
  else              col_stats_body<1>(xe, NEDGE, ST+16, (b-64)*256+threadIdx.x, 64*256, red);
}

// ---- merged embedding for BOTH node sets; input-BN finalize in prologue ----
__global__ void embed2_k(const float* __restrict__ xc, const float* __restrict__ xv,
                         const float* __restrict__ st,
                         const float* __restrict__ cbnw, const float* __restrict__ cbnb,
                         const float* __restrict__ vbnw, const float* __restrict__ vbnb,
                         const float* __restrict__ cW1, const float* __restrict__ cb1,
                         const float* __restrict__ cW2, const float* __restrict__ cb2,
                         const float* __restrict__ vW1, const float* __restrict__ vb1,
                         const float* __restrict__ vW2, const float* __restrict__ vb2,
                         bf16* __restrict__ outc, bf16* __restrict__ outv){
  __shared__ float aff[16];   // consA[3]@0 consB[3]@3 varA[5]@6 varB[5]@11
  {
    int tt = threadIdx.x;
    if (tt < 3){
      float m = st[tt]/(float)NCONS, q = st[3+tt]/(float)NCONS;
      float A = rsqrtf(fmaxf(q - m*m, 0.f) + 1e-5f)*cbnw[tt];
      aff[tt] = A; aff[3+tt] = cbnb[tt] - m*A;
    } else if (tt < 8){
      int c = tt-3;
      float m = st[6+c]/(float)NVARS, q = st[11+c]/(float)NVARS;
      float A = rsqrtf(fmaxf(q - m*m, 0.f) + 1e-5f)*vbnw[c];
      aff[6+c] = A; aff[11+c] = vbnb[c] - m*A;
    }
  }
  __syncthreads();
  int t = threadIdx.x & 63;
  int w = (blockIdx.x*blockDim.x + threadIdx.x) >> 6;
  int nw = (gridDim.x*blockDim.x) >> 6;
  for (int j = w; j < NCONS + NVARS; j += nw){
    bool isv = (j >= NCONS);
    int n = isv ? j - NCONS : j;
    const float* x  = isv ? xv : xc;
    int cin         = isv ? 5 : 3;
    const float* pA = isv ? aff+6 : aff+0;
    const float* pB = isv ? aff+11 : aff+3;
    const float* W1 = isv ? vW1 : cW1;
    const float* b1 = isv ? vb1 : cb1;
    const float* W2 = isv ? vW2 : cW2;
    const float* b2 = isv ? vb2 : cb2;
    bf16* out       = isv ? outv : outc;
    float acc = b1[t];
    for (int k=0;k<cin;++k){
      float xb = x[n*cin+k]*pA[k] + pB[k];
      acc += xb*W1[k*64+t];
    }
    float h1 = fmaxf(acc, 0.f);
    float acc2 = b2[t];
#pragma unroll
    for (int j2=0;j2<64;++j2) acc2 += shflf(h1,j2)*W2[j2*64+t];
    out[n*64+t] = __float2bfloat16(fmaxf(acc2, 0.f));
  }
}

// ---- all 16 conv-weight fragment jobs in one launch ----
__global__ void frag_all_k(const float* __restrict__ fmW1, const float* __restrict__ fmW2,
                           const float* __restrict__ omW1, const float* __restrict__ omW2,
                           unsigned short* __restrict__ W1Fb, unsigned short* __restrict__ W2Fb,
                           unsigned short* __restrict__ OW1Fb, unsigned short* __restrict__ OW2Fb){
  int i = blockIdx.x*blockDim.x + threadIdx.x;
  if (i >= 4*24576) return;
  int l = i / 24576, r = i % 24576;
  const float* src; unsigned short* dst; int e; int skip;
  if (r < 8192){       src = fmW1 + (size_t)l*129*64; dst = W1Fb  + l*8192; e = r;       skip = 64; }
  else if (r < 12288){ src = fmW2 + (size_t)l*64*64;  dst = W2Fb  + l*4096; e = r-8192;  skip = -1; }
  else if (r < 20480){ src = omW1 + (size_t)l*128*64; dst = OW1Fb + l*8192; e = r-12288; skip = -1; }
  else {               src = omW2 + (size_t)l*64*64;  dst = OW2Fb + l*4096; e = r-20480; skip = -1; }
  int j = e & 7, lane = (e>>3)&63, n = (e>>9)&3, kc = e>>11;
  int k = kc*32 + (lane>>4)*8 + j;
  int col = n*16 + (lane&15);
  int srcrow = (skip>=0 && k>=skip) ? k+1 : k;
  dst[e] = f2b(src[srcrow*64 + col]);
}

// ---- hi/lo fragmenter for final-MLP weights ----
__global__ void frag2_k(const float* __restrict__ Wsrc, unsigned short* __restrict__ Whi,
                        unsigned short* __restrict__ Wlo, int ntiles, int ncols, int tot){
  int i = blockIdx.x*blockDim.x + threadIdx.x;
  if (i>=tot) return;
  int j = i & 7, lane = (i>>3)&63, rem = i>>9;
  int nt = rem % ntiles, kc = rem / ntiles;
  int k = kc*32 + (lane>>4)*8 + j;
  int col = nt*16 + (lane&15);
  float w = Wsrc[k*ncols + col];
  unsigned short hi = f2b(w);
  float rec = __builtin_bit_cast(float, (unsigned int)hi << 16);
  Whi[i] = hi;
  Wlo[i] = f2b(w - rec);
}

// ---- CSR MFMA edge-message kernel + fused BN column stats;
// edge-BN finalize computed in prologue from raw sums. ----
__global__ void __launch_bounds__(256) msg_csr_k(
    const bf16* __restrict__ left, const bf16* __restrict__ right,
    const int* __restrict__ srt, const bf16* __restrict__ eas,
    const float* __restrict__ est, const float* __restrict__ ebnw, const float* __restrict__ ebnb,
    const int* __restrict__ offs,
    const unsigned short* __restrict__ W1F, const unsigned short* __restrict__ W2F,
    const float* __restrict__ b1, const float* __restrict__ w1e, const float* __restrict__ b2,
    float* __restrict__ agg, float* __restrict__ slot, int nn)
{
  __shared__ __align__(16) unsigned short w1l[8192];
  __shared__ __align__(16) unsigned short w2l[4096];
  __shared__ __align__(16) unsigned short h1l[4][16*72];
  __shared__ float bstat[128];
  {
    const float4* s1 = (const float4*)W1F; float4* d1 = (float4*)w1l;
    for (int i=threadIdx.x; i<1024; i+=256) d1[i] = s1[i];
    const float4* s2 = (const float4*)W2F; float4* d2 = (float4*)w2l;
    for (int i=threadIdx.x; i<512; i+=256) d2[i] = s2[i];
    if (threadIdx.x < 128) bstat[threadIdx.x] = 0.f;
  }
  __syncthreads();
  const short8v* W1v = (const short8v*)w1l;
  const short8v* W2v = (const short8v*)w2l;
  const unsigned short* rgt = (const unsigned short*)right;
  const unsigned short* lft = (const unsigned short*)left;
  int t = threadIdx.x & 63;
  int wv = threadIdx.x >> 6;
  int gw = (blockIdx.x*blockDim.x + threadIdx.x) >> 6;
  int nw = (gridDim.x*blockDim.x) >> 6;
  int r16 = t & 15, kg = t >> 4;
  float em = est[0]/(float)NEDGE, eq = est[1]/(float)NEDGE;
  float eA = rsqrtf(fmaxf(eq - em*em, 0.f) + 1e-5f)*ebnw[0];
  float eB = ebnb[0] - em*eA;
  float bb1[4], we[4], bb2[4];
#pragma unroll
  for (int n=0;n<4;++n){ bb1[n]=b1[n*16+r16]; we[n]=w1e[n*16+r16]; bb2[n]=b2[n*16+r16]; }
  unsigned short* h1w = &h1l[wv][0];
  float sacc[4] = {0.f,0.f,0.f,0.f}, ssacc[4] = {0.f,0.f,0.f,0.f};

  int chunk = (nn + nw - 1) / nw;
  int nbeg = gw * chunk;
  int nend = nbeg + chunk; if (nend > nn) nend = nn;

  for (int node = nbeg; node < nend; ++node){
    int beg = offs[node], end = offs[node+1];
    int deg = end - beg;
    float4v acc[4];
#pragma unroll
    for (int n=0;n<4;++n) acc[n] = (float4v){0.f,0.f,0.f,0.f};
    if (deg > 0){
      short8v rr0 = *(const short8v*)(rgt + (size_t)node*64 + kg*8);
      short8v rr1 = *(const short8v*)(rgt + (size_t)node*64 + 32 + kg*8);
      float4v crt[4];
#pragma unroll
      for (int n=0;n<4;++n) crt[n] = (float4v){bb1[n],bb1[n],bb1[n],bb1[n]};
#pragma unroll
      for (int n=0;n<4;++n){
        crt[n] = __builtin_amdgcn_mfma_f32_16x16x32_bf16(rr0, W1v[(0+n)*64+t], crt[n], 0,0,0);
        crt[n] = __builtin_amdgcn_mfma_f32_16x16x32_bf16(rr1, W1v[(4+n)*64+t], crt[n], 0,0,0);
      }
      for (int base = beg; base < end; base += 16){
        int idx = base + r16;
        int ic = idx < end ? idx : beg;
        int sI = srt[ic];
        float ef = b2f(eas[ic])*eA + eB;
        short8v al0 = *(const short8v*)(lft + (size_t)sI*64 + kg*8);
        short8v al1 = *(const short8v*)(lft + (size_t)sI*64 + 32 + kg*8);
        float efr[4];
#pragma unroll
        for (int r=0;r<4;++r) efr[r] = shflf(ef, kg*4+r);
        float4v c[4];
#pragma unroll
        for (int n=0;n<4;++n){
#pragma unroll
          for (int r=0;r<4;++r) c[n][r] = crt[n][r] + efr[r]*we[n];
        }
#pragma unroll
        for (int n=0;n<4;++n){
          c[n] = __builtin_amdgcn_mfma_f32_16x16x32_bf16(al0, W1v[( 8+n)*64+t], c[n], 0,0,0);
          c[n] = __builtin_amdgcn_mfma_f32_16x16x32_bf16(al1, W1v[(12+n)*64+t], c[n], 0,0,0);
        }
#pragma unroll
        for (int n=0;n<4;++n){
#pragma unroll
          for (int r=0;r<4;++r)
            h1w[(kg*4+r)*72 + n*16 + r16] = f2b(fmaxf(c[n][r], 0.f));
        }
        asm volatile("s_waitcnt lgkmcnt(0)" ::: "memory");
        __builtin_amdgcn_sched_barrier(0);
        short8v a20 = *(const short8v*)(h1w + r16*72 + kg*8);
        short8v a21 = *(const short8v*)(h1w + r16*72 + 32 + kg*8);
        float4v d[4];
#pragma unroll
        for (int n=0;n<4;++n) d[n] = (float4v){0.f,0.f,0.f,0.f};
#pragma unroll
        for (int n=0;n<4;++n){
          d[n] = __builtin_amdgcn_mfma_f32_16x16x32_bf16(a20, W2v[(0+n)*64+t], d[n], 0,0,0);
          d[n] = __builtin_amdgcn_mfma_f32_16x16x32_bf16(a21, W2v[(4+n)*64+t], d[n], 0,0,0);
        }
#pragma unroll
        for (int r=0;r<4;++r){
          float mrow = (base + kg*4 + r < end) ? 1.f : 0.f;
#pragma unroll
          for (int n=0;n<4;++n) acc[n][r] += mrow * d[n][r];
        }
      }
    }
    float tot[4];
#pragma unroll
    for (int n=0;n<4;++n){
      tot[n] = acc[n][0]+acc[n][1]+acc[n][2]+acc[n][3];
      tot[n] += __shfl_xor(tot[n], 16, 64);
      tot[n] += __shfl_xor(tot[n], 32, 64);
    }
    if (kg == 0){
      float inv = (deg>0) ? 1.f/(float)deg : 0.f;
#pragma unroll
      for (int n=0;n<4;++n){
        float val = (deg>0) ? tot[n]*inv + bb2[n] : 0.f;
        agg[(size_t)node*64 + n*16 + r16] = val;
        sacc[n] += val; ssacc[n] += val*val;
      }
    }
  }
  if (kg == 0){
#pragma unroll
    for (int n=0;n<4;++n){
      atomicAdd(&bstat[n*16+r16], sacc[n]);
      atomicAdd(&bstat[64+n*16+r16], ssacc[n]);
    }
  }
  __syncthreads();
  if (threadIdx.x < 128) atomicAdd(&slot[threadIdx.x], bstat[threadIdx.x]);
}

// ---- MFMA node-output MLP + fused GraphNorm stats; BN finalize in prologue ----
__global__ void __launch_bounds__(256) node_mfma_k(
    const float* __restrict__ agg, const bf16* __restrict__ right,
    const float* __restrict__ slot, const float* __restrict__ bnw, const float* __restrict__ bnb,
    const unsigned short* __restrict__ W1F, const unsigned short* __restrict__ W2F,
    const float* __restrict__ b1, const float* __restrict__ b2,
    bf16* __restrict__ out, float* __restrict__ gslot, int nn)
{
  __shared__ __align__(16) unsigned short w1l[8192];
  __shared__ __align__(16) unsigned short w2l[4096];
  __shared__ __align__(16) unsigned short h1l[4][16*72];
  __shared__ float bstat[128];
  __shared__ float bnAB[128];
  {
    const float4* s1 = (const float4*)W1F; float4* d1 = (float4*)w1l;
    for (int i=threadIdx.x; i<1024; i+=256) d1[i] = s1[i];
    const float4* s2 = (const float4*)W2F; float4* d2 = (float4*)w2l;
    for (int i=threadIdx.x; i<512; i+=256) d2[i] = s2[i];
    if (threadIdx.x < 128) bstat[threadIdx.x] = 0.f;
    if (threadIdx.x < 64){
      int c = threadIdx.x;
      float m = slot[c]/(float)NCONS, q = slot[64+c]/(float)NCONS;
      float A = rsqrtf(fmaxf(q - m*m, 0.f) + 1e-5f) * bnw[c];
      bnAB[c] = A; bnAB[64+c] = bnb[c] - m*A;
    }
  }
  __syncthreads();
  const short8v* W1v = (const short8v*)w1l;
  const short8v* W2v = (const short8v*)w2l;
  const unsigned short* rgt = (const unsigned short*)right;
  int t = threadIdx.x & 63;
  int wv = threadIdx.x >> 6;
  int gw = (blockIdx.x*blockDim.x + threadIdx.x) >> 6;
  int nw = (gridDim.x*blockDim.x) >> 6;
  int r16 = t & 15, kg = t >> 4;
  float pA0[8], pB0[8], pA1[8], pB1[8];
#pragma unroll
  for (int j=0;j<8;++j){
    pA0[j]=bnAB[kg*8+j];    pB0[j]=bnAB[64+kg*8+j];
    pA1[j]=bnAB[32+kg*8+j]; pB1[j]=bnAB[96+kg*8+j];
  }
  float bb1[4], bb2[4];
#pragma unroll
  for (int n=0;n<4;++n){ bb1[n]=b1[n*16+r16]; bb2[n]=b2[n*16+r16]; }
  unsigned short* h1w = &h1l[wv][0];
  float sacc[4] = {0.f,0.f,0.f,0.f}, ssacc[4] = {0.f,0.f,0.f,0.f};

  for (int g = gw*16; g < nn; g += nw*16){
    int node = g + r16;
    const float* ag = agg + (size_t)node*64;
    float4 f0 = *(const float4*)(ag + kg*8);
    float4 f1 = *(const float4*)(ag + kg*8 + 4);
    float4 f2 = *(const float4*)(ag + 32 + kg*8);
    float4 f3 = *(const float4*)(ag + 32 + kg*8 + 4);
    float v0[8] = {f0.x,f0.y,f0.z,f0.w,f1.x,f1.y,f1.z,f1.w};
    float v1[8] = {f2.x,f2.y,f2.z,f2.w,f3.x,f3.y,f3.z,f3.w};
    short8v ap0, ap1;
#pragma unroll
    for (int j=0;j<8;++j){
      ((unsigned short*)&ap0)[j] = f2b(v0[j]*pA0[j] + pB0[j]);
      ((unsigned short*)&ap1)[j] = f2b(v1[j]*pA1[j] + pB1[j]);
    }
    short8v ar0 = *(const short8v*)(rgt + (size_t)node*64 + kg*8);
    short8v ar1 = *(const short8v*)(rgt + (size_t)node*64 + 32 + kg*8);
    float4v c[4];
#pragma unroll
    for (int n=0;n<4;++n) c[n] = (float4v){bb1[n],bb1[n],bb1[n],bb1[n]};
#pragma unroll
    for (int n=0;n<4;++n){
      c[n] = __builtin_amdgcn_mfma_f32_16x16x32_bf16(ap0, W1v[( 0+n)*64+t], c[n], 0,0,0);
      c[n] = __builtin_amdgcn_mfma_f32_16x16x32_bf16(ap1, W1v[( 4+n)*64+t], c[n], 0,0,0);
      c[n] = __builtin_amdgcn_mfma_f32_16x16x32_bf16(ar0, W1v[( 8+n)*64+t], c[n], 0,0,0);
      c[n] = __builtin_amdgcn_mfma_f32_16x16x32_bf16(ar1, W1v[(12+n)*64+t], c[n], 0,0,0);
    }
#pragma unroll
    for (int n=0;n<4;++n){
#pragma unroll
      for (int r=0;r<4;++r)
        h1w[(kg*4+r)*72 + n*16 + r16] = f2b(fmaxf(c[n][r], 0.f));
    }
    asm volatile("s_waitcnt lgkmcnt(0)" ::: "memory");
    __builtin_amdgcn_sched_barrier(0);
    short8v a20 = *(const short8v*)(h1w + r16*72 + kg*8);
    short8v a21 = *(const short8v*)(h1w + r16*72 + 32 + kg*8);
    float4v d[4];
#pragma unroll
    for (int n=0;n<4;++n) d[n] = (float4v){bb2[n],bb2[n],bb2[n],bb2[n]};
#pragma unroll
    for (int n=0;n<4;++n){
      d[n] = __builtin_amdgcn_mfma_f32_16x16x32_bf16(a20, W2v[(0+n)*64+t], d[n], 0,0,0);
      d[n] = __builtin_amdgcn_mfma_f32_16x16x32_bf16(a21, W2v[(4+n)*64+t], d[n], 0,0,0);
    }
    unsigned short* op = (unsigned short*)out;
#pragma unroll
    for (int r=0;r<4;++r){
      size_t base = (size_t)(g + kg*4 + r)*64 + r16;
#pragma unroll
      for (int n=0;n<4;++n){
        float val = d[n][r];
        op[base + n*16] = f2b(val);
        sacc[n] += val; ssacc[n] += val*val;
      }
    }
  }
#pragma unroll
  for (int n=0;n<4;++n){
    atomicAdd(&bstat[n*16+r16], sacc[n]);
    atomicAdd(&bstat[64+n*16+r16], ssacc[n]);
  }
  __syncthreads();
  if (threadIdx.x < 128) atomicAdd(&gslot[threadIdx.x], bstat[threadIdx.x]);
}

// ---- graphnorm apply on both buffers; GN finalize in prologue ----
__global__ void affine2_k(bf16* __restrict__ x1, const float* __restrict__ s1,
                          bf16* __restrict__ x2, const float* __restrict__ s2,
                          const float* __restrict__ gw, const float* __restrict__ gb,
                          const float* __restrict__ gal, int ga, int gb2, int nn){
  __shared__ float ab[256];   // s1A 0-63, s1B 64-127, s2A 128-191, s2B 192-255
  {
    int tt = threadIdx.x;
    if (tt < 128){
      const float* sl = (tt < 64) ? s1 : s2;
      int g = (tt < 64) ? ga : gb2;
      int c = tt & 63;
      float m = sl[c]/(float)NCONS, q = sl[64+c]/(float)NCONS;
      float a = gal[g*64+c];
      float var = q - 2.f*a*m*m + a*a*m*m;
      float A = rsqrtf(fmaxf(var, 0.f) + 1e-5f) * gw[g*64+c];
      ab[(tt<64?0:128)+c] = A;
      ab[(tt<64?64:192)+c] = gb[g*64+c] - a*m*A;
    }
  }
  __syncthreads();
  int i = blockIdx.x*blockDim.x + threadIdx.x;
  int stride = gridDim.x*blockDim.x;
  int tot = nn*64;
  for (; i<2*tot; i+=stride){
    if (i < tot){
      int c = i & 63;
      x1[i] = __float2bfloat16(b2f(x1[i])*ab[c] + ab[64+c]);
    } else {
      int j = i - tot;
      int c = j & 63;
      x2[j] = __float2bfloat16(b2f(x2[j])*ab[128+c] + ab[192+c]);
    }
  }
}

// ---- MFMA final MLP, race-free; QUARTER-split h1 tile (16x132 f32) ----
__global__ void __launch_bounds__(256) final_mfma_k(
    const bf16* __restrict__ vf0, const bf16* __restrict__ vf1, const bf16* __restrict__ vf2,
    const unsigned short* __restrict__ W1hi, const unsigned short* __restrict__ W1lo,
    const unsigned short* __restrict__ W2hi, const unsigned short* __restrict__ W2lo,
    const float* __restrict__ B1, const float* __restrict__ B2,
    const float* __restrict__ W3, const float* __restrict__ B3,
    void* __restrict__ out, int nn, const int* __restrict__ mode)
{
  __shared__ float h1l[4][16*132];   // per-wave 16x128 f32 tile, stride 132
  const short8v* W1h = (const short8v*)W1hi;
  const short8v* W1l = (const short8v*)W1lo;
  const short8v* W2h = (const short8v*)W2hi;
  const short8v* W2l = (const short8v*)W2lo;
  const unsigned short* v0p = (const unsigned short*)vf0;
  const unsigned short* v1p = (const unsigned short*)vf1;
  const unsigned short* v2p = (const unsigned short*)vf2;
  int t = threadIdx.x & 63;
  int wv = threadIdx.x >> 6;
  int r16 = t & 15, kg = t >> 4;
  int tile = blockIdx.x*4 + wv;
  bool act = (tile*16 < nn);
  int g = act ? tile*16 : 0;
  float* h1w = &h1l[wv][0];
  float b2v[8], w3v[8];
#pragma unroll
  for (int n=0;n<8;++n){ b2v[n] = B2[n*16+r16]; w3v[n] = W3[n*16+r16]; }
  float bb3 = B3[0];
  int md = *mode;

  int node = g + r16;
  short8v A1[6];
  A1[0] = *(const short8v*)(v0p + (size_t)node*64 + kg*8);
  A1[1] = *(const short8v*)(v0p + (size_t)node*64 + 32 + kg*8);
  A1[2] = *(const short8v*)(v1p + (size_t)node*64 + kg*8);
  A1[3] = *(const short8v*)(v1p + (size_t)node*64 + 32 + kg*8);
  A1[4] = *(const short8v*)(v2p + (size_t)node*64 + kg*8);
  A1[5] = *(const short8v*)(v2p + (size_t)node*64 + 32 + kg*8);
  float4v D[8];
#pragma unroll
  for (int n=0;n<8;++n) D[n] = (float4v){b2v[n],b2v[n],b2v[n],b2v[n]};

  for (int quarter=0; quarter<4; ++quarter){
    if (quarter) __syncthreads();
    for (int nt=0; nt<8; ++nt){
      int ntg = quarter*8 + nt;
      float bb = B1[ntg*16 + r16];
      float4v C = (float4v){bb,bb,bb,bb};
#pragma unroll
      for (int kc=0; kc<6; ++kc){
        C = __builtin_amdgcn_mfma_f32_16x16x32_bf16(A1[kc], W1h[(kc*32+ntg)*64+t], C, 0,0,0);
        C = __builtin_amdgcn_mfma_f32_16x16x32_bf16(A1[kc], W1l[(kc*32+ntg)*64+t], C, 0,0,0);
      }
#pragma unroll
      for (int r=0;r<4;++r)
        h1w[(kg*4+r)*132 + nt*16 + r16] = fmaxf(C[r], 0.f);
    }
    __syncthreads();
    short8v Ahi[4], Alo[4];
#pragma unroll
    for (int kc=0; kc<4; ++kc){
      const float* hp = h1w + r16*132 + kc*32 + kg*8;
      float4 x0 = *(const float4*)(hp);
      float4 x1 = *(const float4*)(hp+4);
      float vv[8] = {x0.x,x0.y,x0.z,x0.w,x1.x,x1.y,x1.z,x1.w};
#pragma unroll
      for (int j=0;j<8;++j){
        unsigned short hi = f2b(vv[j]);
        float rec = __builtin_bit_cast(float, (unsigned int)hi<<16);
        ((unsigned short*)&Ahi[kc])[j] = hi;
        ((unsigned short*)&Alo[kc])[j] = f2b(vv[j] - rec);
      }
    }
#pragma unroll
    for (int nt2=0; nt2<8; ++nt2){
#pragma unroll
      for (int kc=0; kc<4; ++kc){
        int kcg = quarter*4 + kc;
        short8v bh = W2h[(kcg*8+nt2)*64+t];
        D[nt2] = __builtin_amdgcn_mfma_f32_16x16x32_bf16(Ahi[kc], bh, D[nt2], 0,0,0);
        D[nt2] = __builtin_amdgcn_mfma_f32_16x16x32_bf16(Alo[kc], bh, D[nt2], 0,0,0);
        D[nt2] = __builtin_amdgcn_mfma_f32_16x16x32_bf16(Ahi[kc], W2l[(kcg*8+nt2)*64+t], D[nt2], 0,0,0);
      }
    }
  }
  float part[4] = {0.f,0.f,0.f,0.f};
#pragma unroll
  for (int n=0;n<8;++n){
#pragma unroll
    for (int r=0;r<4;++r) part[r] += fmaxf(D[n][r],0.f)*w3v[n];
  }
#pragma unroll
  for (int r=0;r<4;++r){
#pragma unroll
    for (int off=1; off<16; off<<=1) part[r] += __shfl_xor(part[r], off, 64);
  }
  if (act && r16==0){
#pragma unroll
    for (int r=0;r<4;++r){
      int node_o = g + kg*4 + r;
      float val = part[r] + bb3;
      if (md) ((bf16*)out)[node_o] = __float2bfloat16(val);
      else    ((float*)out)[node_o] = val;
    }
  }
}

extern "C" void kernel_launch(void* const* d_in, const int* in_sizes, int n_in,
                              void* d_out, int out_size, void* d_ws, size_t ws_size,
                              hipStream_t stream){
  const int* ei = (const int*)d_in[36];

  char* ws = (char*)d_ws;
  float* ST = (float*)ws;                       // 4096 floats = 16 KB
  int* MODE = (int*)(ws + 16384);
  float* FBASE = (float*)(ws + 32768);
  CvtArgs ca;
  float* F[36];
  {
    int off = 0;
    for (int i=0;i<36;++i){
      ca.p[i] = d_in[i];
      ca.ofs[i] = off;
      F[i] = FBASE + off;
      off += in_sizes[i];
    }
    ca.ofs[36] = off;
  }
  unsigned short* W1Fb  = (unsigned short*)(ws + 7u*1024*1024);
  unsigned short* W2Fb  = W1Fb + 4*8192;
  unsigned short* OW1Fb = W2Fb + 4*4096;
  unsigned short* OW2Fb = OW1Fb + 4*8192;
  unsigned short* FW1H  = OW2Fb + 4*4096;
  unsigned short* FW1L  = FW1H + 98304;
  unsigned short* FW2H  = FW1L + 98304;
  unsigned short* FW2L  = FW2H + 65536;
  size_t o = 8u*1024*1024;
  float* AGG = (float*)(ws + o); o += (size_t)NCONS*64*sizeof(float);
  bf16* CFA = (bf16*)(ws + o); o += (size_t)NCONS*64*sizeof(bf16);
  bf16* CFB = (bf16*)(ws + o); o += (size_t)NCONS*64*sizeof(bf16);
  bf16* VF0 = (bf16*)(ws + o); o += (size_t)NVARS*64*sizeof(bf16);
  bf16* VF1 = (bf16*)(ws + o); o += (size_t)NVARS*64*sizeof(bf16);
  bf16* VF2 = (bf16*)(ws + o); o += (size_t)NVARS*64*sizeof(bf16);
  int* CNTCI = (int*)(ws + o); o += (size_t)NCONS*sizeof(int);
  int* CNTVI = (int*)(ws + o); o += (size_t)NVARS*sizeof(int);
  int* OFFC  = (int*)(ws + o); o += (size_t)(NCONS+4)*sizeof(int);   // +4 pad keeps OFFV 16B-aligned
  int* OFFV  = (int*)(ws + o); o += (size_t)(NVARS+4)*sizeof(int);
  int* SRTC  = (int*)(ws + o); o += (size_t)NEDGE*sizeof(int);
  int* SRTV  = (int*)(ws + o); o += (size_t)NEDGE*sizeof(int);
  bf16* EAC  = (bf16*)(ws + o); o += (size_t)NEDGE*sizeof(bf16);
  bf16* EAV  = (bf16*)(ws + o); o += (size_t)NEDGE*sizeof(bf16);

  detect_k<<<1,64,0,stream>>>((const unsigned int*)d_in[0], MODE);
  convert_all_k<<<512,256,0,stream>>>(ca, FBASE, MODE);
  frag_all_k<<<384,256,0,stream>>>(F[17], F[19], F[23], F[25], W1Fb, W2Fb, OW1Fb, OW2Fb);
  frag2_k<<<384,256,0,stream>>>(F[30], FW1H, FW1L, 32, 512, 98304);
  frag2_k<<<256,256,0,stream>>>(F[32], FW2H, FW2L, 8, 128, 65536);

  zero2_k<<<128,256,0,stream>>>(ST, 4096, (float*)CNTCI, NCONS + NVARS);
  hist_k<<<1024,256,0,stream>>>(ei, CNTCI, CNTVI);
  scan2_k<<<2,1024,0,stream>>>(CNTCI, OFFC, NCONS, CNTVI, OFFV, NVARS);
  scat_k<<<1024,256,0,stream>>>(ei, F[1], CNTCI, CNTVI, SRTC, SRTV, EAC, EAV);

  col_stats3_k<<<128,256,0,stream>>>(F[0], F[2], F[1], ST);
  embed2_k<<<1024,256,0,stream>>>(F[0], F[2], ST, F[3], F[4], F[11], F[12],
                                  F[5], F[6], F[7], F[8],
                                  F[13], F[14], F[15], F[16], CFA, VF0);

  const bf16* lefts[4]  = {VF0, CFB, VF1, CFA};
  const bf16* rights[4] = {CFA, VF0, CFB, VF1};
  bf16*       outs[4]   = {CFB, VF1, CFA, VF2};
  const int*  srts[4]   = {SRTC, SRTV, SRTC, SRTV};
  const bf16* eass[4]   = {EAC, EAV, EAC, EAV};
  const int*  offss[4]  = {OFFC, OFFV, OFFC, OFFV};

  for (int l=0; l<4; ++l){
    float* slot = ST + 36 + l*256;
    float* gslot = ST + 36 + 1024 + l*256;
    msg_csr_k<<<1024,256,0,stream>>>(lefts[l], rights[l], srts[l], eass[l],
                                     ST+16, F[9], F[10], offss[l],
                                     W1Fb + l*8192, W2Fb + l*4096,
                                     F[18] + l*64,
                                     F[17] + (size_t)l*129*64 + 64*64,
                                     F[20] + l*64, AGG, slot, NCONS);
    node_mfma_k<<<782,256,0,stream>>>(AGG, rights[l], slot, F[21]+l*64, F[22]+l*64,
                                      OW1Fb + l*8192, OW2Fb + l*4096,
                                      F[24] + l*64, F[26] + l*64, outs[l], gslot, NCONS);
    if (l == 1 || l == 3){
      bf16* cfbuf = outs[l-1];
      bf16* vfbuf = outs[l];
      int ga = l-1, gb = l;
      float* gsA = ST + 36 + 1024 + ga*256;
      float* gsB = ST + 36 + 1024 + gb*256;
      affine2_k<<<1024,256,0,stream>>>(cfbuf, gsA, vfbuf, gsB,
                                       F[27], F[28], F[29], ga, gb, NCONS);
    }
  }
  final_mfma_k<<<782,256,0,stream>>>(VF0, VF1, VF2,
                                     FW1H, FW1L, FW2H, FW2L,
                                     F[31], F[33], F[34], F[35],
                                     d_out, NVARS, MODE);
}

// Round 19
// 899.797 us; speedup vs baseline: 1.6098x; 1.0165x over previous
//
#include <hip/hip_runtime.h>
#include <hip/hip_bf16.h>

typedef __hip_bfloat16 bf16;
typedef __attribute__((ext_vector_type(8))) short short8v;
typedef __attribute__((ext_vector_type(4))) float float4v;

#define NCONS 50000
#define NVARS 50000
#define NEDGE 600000

__device__ __forceinline__ float b2f(const bf16 v){ return __bfloat162float(v); }
__device__ __forceinline__ float shflf(float v, int lane){ return __shfl(v, lane, 64); }
__device__ __forceinline__ unsigned short f2b(float v){
  return __builtin_bit_cast(unsigned short, __float2bfloat16(v));
}

// ---- input-dtype sniffer (bf16 pairs vs f32) ----
__global__ void detect_k(const unsigned int* __restrict__ x, int* __restrict__ mode){
  int t = threadIdx.x;
  int hits = 0;
  for (int i=0;i<4;++i){
    unsigned w = x[t*4+i];
    unsigned e = (w>>7)&0xFFu;
    if (e >= 0x70u && e <= 0x8Fu) hits++;
  }
  for (int off=32; off>0; off>>=1) hits += __shfl_down(hits, off);
  if (t==0) *mode = (hits > 128) ? 1 : 0;
}

// ---- convert ALL 36 float inputs to f32 workspace in one launch ----
struct CvtArgs { const void* p[36]; int ofs[37]; };
__global__ void convert_all_k(CvtArgs a, float* __restrict__ dst, const int* __restrict__ mode){
  int m = *mode;
  int i = blockIdx.x*blockDim.x + threadIdx.x;
  int stride = gridDim.x*blockDim.x;
  int total = a.ofs[36];
  for (; i<total; i+=stride){
    int s = 0;
#pragma unroll
    for (int k=1;k<36;++k) s += (i >= a.ofs[k]) ? 1 : 0;
    int off = i - a.ofs[s];
    float v;
    if (m) v = b2f(((const bf16*)a.p[s])[off]);
    else   v = ((const float*)a.p[s])[off];
    dst[i] = v;
  }
}

// ---- zero ST (na floats) and CNT (nb ints) in one launch ----
__global__ void zero2_k(float* __restrict__ a, int na, float* __restrict__ b, int nb){
  int i = blockIdx.x*blockDim.x + threadIdx.x;
  int stride = gridDim.x*blockDim.x;
  for (; i<na+nb; i+=stride){
    if (i < na) a[i] = 0.f;
    else        b[i-na] = 0.f;
  }
}

// ---- CSR build: histogram, 2-block scan (cnt becomes cursor), scatter ----
__global__ void hist_k(const int* __restrict__ ei, int* __restrict__ cntc, int* __restrict__ cntv){
  int i = blockIdx.x*blockDim.x + threadIdx.x;
  int stride = gridDim.x*blockDim.x;
  for (; i<2*NEDGE; i+=stride){
    int id = ei[i];
    if (i < NEDGE) atomicAdd(&cntc[id], 1);
    else           atomicAdd(&cntv[id], 1);
  }
}

// block 0 scans cnt0/offs0[n0], block 1 scans cnt1/offs1[n1] (int4 walks).
__global__ void __launch_bounds__(1024) scan2_k(int* __restrict__ cnt0, int* __restrict__ offs0, int n0,
                                                int* __restrict__ cnt1, int* __restrict__ offs1, int n1){
  __shared__ int part[1024];
  int* cnt  = blockIdx.x ? cnt1  : cnt0;
  int* offs = blockIdx.x ? offs1 : offs0;
  int n     = blockIdx.x ? n1    : n0;
  int t = threadIdx.x;
  int chunk = (((n + 1023) >> 10) + 3) & ~3;
  int b = t*chunk;
  int e = b + chunk; if (e > n) e = n;
  int nv4 = (e > b) ? (e - b) >> 2 : 0;
  const int4* c4 = (const int4*)(cnt + b);
  int s = 0;
  for (int i=0;i<nv4;++i){ int4 v = c4[i]; s += v.x+v.y+v.z+v.w; }
  part[t] = s;
  __syncthreads();
  for (int off=1; off<1024; off<<=1){
    int v = (t >= off) ? part[t-off] : 0;
    __syncthreads();
    part[t] += v;
    __syncthreads();
  }
  int run = (t==0) ? 0 : part[t-1];
  int4* o4 = (int4*)(offs + b);
  int4* u4 = (int4*)(cnt + b);
  for (int i=0;i<nv4;++i){
    int4 v = c4[i];
    int4 w;
    w.x = run; run += v.x;
    w.y = run; run += v.y;
    w.z = run; run += v.z;
    w.w = run; run += v.w;
    o4[i] = w;
    u4[i] = w;
  }
  if (t==1023) offs[n] = part[1023];
}

// scatter: write dst-sorted src ids and dst-sorted bf16 edge attrs directly
__global__ void scat_k(const int* __restrict__ ei, const float* __restrict__ ea,
                       int* __restrict__ curc, int* __restrict__ curv,
                       int* __restrict__ srtc, int* __restrict__ srtv,
                       bf16* __restrict__ eac, bf16* __restrict__ eav){
  int i = blockIdx.x*blockDim.x + threadIdx.x;
  int stride = gridDim.x*blockDim.x;
  for (; i<2*NEDGE; i+=stride){
    int id = ei[i];
    if (i < NEDGE){
      int p = atomicAdd(&curc[id],1);
      srtc[p] = ei[NEDGE+i];
      eac[p] = __float2bfloat16(ea[i]);
    } else {
      int e = i - NEDGE;
      int p = atomicAdd(&curv[id],1);
      srtv[p] = ei[e];
      eav[p] = __float2bfloat16(ea[e]);
    }
  }
}

// ---- input col-stats: wave reduce -> block LDS reduce -> one atomic/block ----
template<int COLS>
__device__ __forceinline__ void col_stats_body(const float* __restrict__ x, int rows,
                                               float* __restrict__ sums, int tid, int stride,
                                               float* __restrict__ red){
  float s[COLS], ss[COLS];
#pragma unroll
  for (int c=0;c<COLS;++c){ s[c]=0.f; ss[c]=0.f; }
  for (int r=tid; r<rows; r+=stride){
#pragma unroll
    for (int c=0;c<COLS;++c){
      float v = x[r*COLS+c];
      s[c]+=v; ss[c]+=v*v;
    }
  }
#pragma unroll
  for (int c=0;c<COLS;++c){
    for (int off=32; off>0; off>>=1){ s[c]+=__shfl_down(s[c],off); ss[c]+=__shfl_down(ss[c],off); }
  }
  int wv = threadIdx.x >> 6;
  if ((threadIdx.x & 63)==0){
#pragma unroll
    for (int c=0;c<COLS;++c){ red[wv*2*COLS+c]=s[c]; red[wv*2*COLS+COLS+c]=ss[c]; }
  }
  __syncthreads();
  if (threadIdx.x < 2*COLS){
    float v = red[threadIdx.x] + red[2*COLS+threadIdx.x]
            + red[4*COLS+threadIdx.x] + red[6*COLS+threadIdx.x];
    atomicAdd(&sums[threadIdx.x], v);
  }
}

__global__ void col_stats3_k(const float* __restrict__ xc, const float* __restrict__ xv,
                             const float* __restrict__ xe, float* __restrict__ ST){
  __shared__ float red[40];
  int b = blockIdx.x;
  if (b < 32)       col_stats_body<3>(xc, NCONS, ST+0,  b*256+threadIdx.x,      32*256, red);
  else if (b < 64)  col_stats_body<5>(xv, NVARS, ST+6,  (b-32)*256+threadIdx.x, 32*256, red);
  else              col_stats_body<1>(xe, NEDGE, ST+16, (b-64)*256+threadIdx.x, 64*256, red);
}

// ---- merged embedding for BOTH node sets; input-BN finalize in prologue ----
__global__ void embed2_k(const float* __restrict__ xc, const float* __restrict__ xv,
                         const float* __restrict__ st,
                         const float* __restrict__ cbnw, const float* __restrict__ cbnb,
                         const float* __restrict__ vbnw, const float* __restrict__ vbnb,
                         const float* __restrict__ cW1, const float* __restrict__ cb1,
                         const float* __restrict__ cW2, const float* __restrict__ cb2,
                         const float* __restrict__ vW1, const float* __restrict__ vb1,
                         const float* __restrict__ vW2, const float* __restrict__ vb2,
                         bf16* __restrict__ outc, bf16* __restrict__ outv){
  __shared__ float aff[16];
  {
    int tt = threadIdx.x;
    if (tt < 3){
      float m = st[tt]/(float)NCONS, q = st[3+tt]/(float)NCONS;
      float A = rsqrtf(fmaxf(q - m*m, 0.f) + 1e-5f)*cbnw[tt];
      aff[tt] = A; aff[3+tt] = cbnb[tt] - m*A;
    } else if (tt < 8){
      int c = tt-3;
      float m = st[6+c]/(float)NVARS, q = st[11+c]/(float)NVARS;
      float A = rsqrtf(fmaxf(q - m*m, 0.f) + 1e-5f)*vbnw[c];
      aff[6+c] = A; aff[11+c] = vbnb[c] - m*A;
    }
  }
  __syncthreads();
  int t = threadIdx.x & 63;
  int w = (blockIdx.x*blockDim.x + threadIdx.x) >> 6;
  int nw = (gridDim.x*blockDim.x) >> 6;
  for (int j = w; j < NCONS + NVARS; j += nw){
    bool isv = (j >= NCONS);
    int n = isv ? j - NCONS : j;
    const float* x  = isv ? xv : xc;
    int cin         = isv ? 5 : 3;
    const float* pA = isv ? aff+6 : aff+0;
    const float* pB = isv ? aff+11 : aff+3;
    const float* W1 = isv ? vW1 : cW1;
    const float* b1 = isv ? vb1 : cb1;
    const float* W2 = isv ? vW2 : cW2;
    const float* b2 = isv ? vb2 : cb2;
    bf16* out       = isv ? outv : outc;
    float acc = b1[t];
    for (int k=0;k<cin;++k){
      float xb = x[n*cin+k]*pA[k] + pB[k];
      acc += xb*W1[k*64+t];
    }
    float h1 = fmaxf(acc, 0.f);
    float acc2 = b2[t];
#pragma unroll
    for (int j2=0;j2<64;++j2) acc2 += shflf(h1,j2)*W2[j2*64+t];
    out[n*64+t] = __float2bfloat16(fmaxf(acc2, 0.f));
  }
}

// ---- all 16 conv-weight fragment jobs in one launch ----
__global__ void frag_all_k(const float* __restrict__ fmW1, const float* __restrict__ fmW2,
                           const float* __restrict__ omW1, const float* __restrict__ omW2,
                           unsigned short* __restrict__ W1Fb, unsigned short* __restrict__ W2Fb,
                           unsigned short* __restrict__ OW1Fb, unsigned short* __restrict__ OW2Fb){
  int i = blockIdx.x*blockDim.x + threadIdx.x;
  if (i >= 4*24576) return;
  int l = i / 24576, r = i % 24576;
  const float* src; unsigned short* dst; int e; int skip;
  if (r < 8192){       src = fmW1 + (size_t)l*129*64; dst = W1Fb  + l*8192; e = r;       skip = 64; }
  else if (r < 12288){ src = fmW2 + (size_t)l*64*64;  dst = W2Fb  + l*4096; e = r-8192;  skip = -1; }
  else if (r < 20480){ src = omW1 + (size_t)l*128*64; dst = OW1Fb + l*8192; e = r-12288; skip = -1; }
  else {               src = omW2 + (size_t)l*64*64;  dst = OW2Fb + l*4096; e = r-20480; skip = -1; }
  int j = e & 7, lane = (e>>3)&63, n = (e>>9)&3, kc = e>>11;
  int k = kc*32 + (lane>>4)*8 + j;
  int col = n*16 + (lane&15);
  int srcrow = (skip>=0 && k>=skip) ? k+1 : k;
  dst[e] = f2b(src[srcrow*64 + col]);
}

// ---- hi/lo fragmenter for final-MLP weights ----
__global__ void frag2_k(const float* __restrict__ Wsrc, unsigned short* __restrict__ Whi,
                        unsigned short* __restrict__ Wlo, int ntiles, int ncols, int tot){
  int i = blockIdx.x*blockDim.x + threadIdx.x;
  if (i>=tot) return;
  int j = i & 7, lane = (i>>3)&63, rem = i>>9;
  int nt = rem % ntiles, kc = rem / ntiles;
  int k = kc*32 + (lane>>4)*8 + j;
  int col = nt*16 + (lane&15);
  float w = Wsrc[k*ncols + col];
  unsigned short hi = f2b(w);
  float rec = __builtin_bit_cast(float, (unsigned int)hi << 16);
  Whi[i] = hi;
  Wlo[i] = f2b(w - rec);
}

// ---- CSR MFMA edge-message kernel + fused BN column stats.
// Software-pipelined over nodes: next node's right-row + first-tile gathers
// issue while the current node computes (gather latency hides under MFMA +
// LDS roundtrip). Arithmetic order unchanged -> bitwise-identical output. ----
__global__ void __launch_bounds__(256) msg_csr_k(
    const bf16* __restrict__ left, const bf16* __restrict__ right,
    const int* __restrict__ srt, const bf16* __restrict__ eas,
    const float* __restrict__ est, const float* __restrict__ ebnw, const float* __restrict__ ebnb,
    const int* __restrict__ offs,
    const unsigned short* __restrict__ W1F, const unsigned short* __restrict__ W2F,
    const float* __restrict__ b1, const float* __restrict__ w1e, const float* __restrict__ b2,
    float* __restrict__ agg, float* __restrict__ slot, int nn)
{
  __shared__ __align__(16) unsigned short w1l[8192];
  __shared__ __align__(16) unsigned short w2l[4096];
  __shared__ __align__(16) unsigned short h1l[4][16*72];
  __shared__ float bstat[128];
  {
    const float4* s1 = (const float4*)W1F; float4* d1 = (float4*)w1l;
    for (int i=threadIdx.x; i<1024; i+=256) d1[i] = s1[i];
    const float4* s2 = (const float4*)W2F; float4* d2 = (float4*)w2l;
    for (int i=threadIdx.x; i<512; i+=256) d2[i] = s2[i];
    if (threadIdx.x < 128) bstat[threadIdx.x] = 0.f;
  }
  __syncthreads();
  const short8v* W1v = (const short8v*)w1l;
  const short8v* W2v = (const short8v*)w2l;
  const unsigned short* rgt = (const unsigned short*)right;
  const unsigned short* lft = (const unsigned short*)left;
  int t = threadIdx.x & 63;
  int wv = threadIdx.x >> 6;
  int gw = (blockIdx.x*blockDim.x + threadIdx.x) >> 6;
  int nw = (gridDim.x*blockDim.x) >> 6;
  int r16 = t & 15, kg = t >> 4;
  float em = est[0]/(float)NEDGE, eq = est[1]/(float)NEDGE;
  float eA = rsqrtf(fmaxf(eq - em*em, 0.f) + 1e-5f)*ebnw[0];
  float eB = ebnb[0] - em*eA;
  float bb1[4], we[4], bb2[4];
#pragma unroll
  for (int n=0;n<4;++n){ bb1[n]=b1[n*16+r16]; we[n]=w1e[n*16+r16]; bb2[n]=b2[n*16+r16]; }
  unsigned short* h1w = &h1l[wv][0];
  float sacc[4] = {0.f,0.f,0.f,0.f}, ssacc[4] = {0.f,0.f,0.f,0.f};

  int chunk = (nn + nw - 1) / nw;
  int nbeg = gw * chunk;
  int nend = nbeg + chunk; if (nend > nn) nend = nn;

  // prime the pipeline with the first node's operands
  int cbeg = 0, cend = 0;
  short8v rr0, rr1, al0, al1;
  bf16 efb;
  if (nbeg < nend){
    cbeg = offs[nbeg]; cend = offs[nbeg+1];
    if (cend > cbeg){
      rr0 = *(const short8v*)(rgt + (size_t)nbeg*64 + kg*8);
      rr1 = *(const short8v*)(rgt + (size_t)nbeg*64 + 32 + kg*8);
      int ic = (cbeg + r16 < cend) ? cbeg + r16 : cbeg;
      int sI = srt[ic];
      efb = eas[ic];
      al0 = *(const short8v*)(lft + (size_t)sI*64 + kg*8);
      al1 = *(const short8v*)(lft + (size_t)sI*64 + 32 + kg*8);
    }
  }

  for (int node = nbeg; node < nend; ++node){
    int beg = cbeg, end = cend;
    int deg = end - beg;
    // issue NEXT node's loads before computing the current one
    int nnode = node + 1;
    short8v prr0, prr1, pal0, pal1;
    bf16 pefb;
    int pend = 0;
    if (nnode < nend){
      pend = offs[nnode+1];
      if (pend > end){
        prr0 = *(const short8v*)(rgt + (size_t)nnode*64 + kg*8);
        prr1 = *(const short8v*)(rgt + (size_t)nnode*64 + 32 + kg*8);
        int pic = (end + r16 < pend) ? end + r16 : end;
        int psI = srt[pic];
        pefb = eas[pic];
        pal0 = *(const short8v*)(lft + (size_t)psI*64 + kg*8);
        pal1 = *(const short8v*)(lft + (size_t)psI*64 + 32 + kg*8);
      }
    }

    float4v acc[4];
#pragma unroll
    for (int n=0;n<4;++n) acc[n] = (float4v){0.f,0.f,0.f,0.f};
    if (deg > 0){
      float4v crt[4];
#pragma unroll
      for (int n=0;n<4;++n) crt[n] = (float4v){bb1[n],bb1[n],bb1[n],bb1[n]};
#pragma unroll
      for (int n=0;n<4;++n){
        crt[n] = __builtin_amdgcn_mfma_f32_16x16x32_bf16(rr0, W1v[(0+n)*64+t], crt[n], 0,0,0);
        crt[n] = __builtin_amdgcn_mfma_f32_16x16x32_bf16(rr1, W1v[(4+n)*64+t], crt[n], 0,0,0);
      }
      for (int base = beg; base < end; base += 16){
        short8v a_l0, a_l1;
        float ef;
        if (base == beg){
          a_l0 = al0; a_l1 = al1; ef = b2f(efb)*eA + eB;
        } else {
          int idx = base + r16;
          int ic = idx < end ? idx : beg;
          int sI = srt[ic];
          ef = b2f(eas[ic])*eA + eB;
          a_l0 = *(const short8v*)(lft + (size_t)sI*64 + kg*8);
          a_l1 = *(const short8v*)(lft + (size_t)sI*64 + 32 + kg*8);
        }
        float efr[4];
#pragma unroll
        for (int r=0;r<4;++r) efr[r] = shflf(ef, kg*4+r);
        float4v c[4];
#pragma unroll
        for (int n=0;n<4;++n){
#pragma unroll
          for (int r=0;r<4;++r) c[n][r] = crt[n][r] + efr[r]*we[n];
        }
#pragma unroll
        for (int n=0;n<4;++n){
          c[n] = __builtin_amdgcn_mfma_f32_16x16x32_bf16(a_l0, W1v[( 8+n)*64+t], c[n], 0,0,0);
          c[n] = __builtin_amdgcn_mfma_f32_16x16x32_bf16(a_l1, W1v[(12+n)*64+t], c[n], 0,0,0);
        }
#pragma unroll
        for (int n=0;n<4;++n){
#pragma unroll
          for (int r=0;r<4;++r)
            h1w[(kg*4+r)*72 + n*16 + r16] = f2b(fmaxf(c[n][r], 0.f));
        }
        asm volatile("s_waitcnt lgkmcnt(0)" ::: "memory");
        __builtin_amdgcn_sched_barrier(0);
        short8v a20 = *(const short8v*)(h1w + r16*72 + kg*8);
        short8v a21 = *(const short8v*)(h1w + r16*72 + 32 + kg*8);
        float4v d[4];
#pragma unroll
        for (int n=0;n<4;++n) d[n] = (float4v){0.f,0.f,0.f,0.f};
#pragma unroll
        for (int n=0;n<4;++n){
          d[n] = __builtin_amdgcn_mfma_f32_16x16x32_bf16(a20, W2v[(0+n)*64+t], d[n], 0,0,0);
          d[n] = __builtin_amdgcn_mfma_f32_16x16x32_bf16(a21, W2v[(4+n)*64+t], d[n], 0,0,0);
        }
#pragma unroll
        for (int r=0;r<4;++r){
          float mrow = (base + kg*4 + r < end) ? 1.f : 0.f;
#pragma unroll
          for (int n=0;n<4;++n) acc[n][r] += mrow * d[n][r];
        }
      }
    }
    float tot[4];
#pragma unroll
    for (int n=0;n<4;++n){
      tot[n] = acc[n][0]+acc[n][1]+acc[n][2]+acc[n][3];
      tot[n] += __shfl_xor(tot[n], 16, 64);
      tot[n] += __shfl_xor(tot[n], 32, 64);
    }
    if (kg == 0){
      float inv = (deg>0) ? 1.f/(float)deg : 0.f;
#pragma unroll
      for (int n=0;n<4;++n){
        float val = (deg>0) ? tot[n]*inv + bb2[n] : 0.f;
        agg[(size_t)node*64 + n*16 + r16] = val;
        sacc[n] += val; ssacc[n] += val*val;
      }
    }
    // rotate pipeline state
    cbeg = end; cend = pend;
    rr0 = prr0; rr1 = prr1; al0 = pal0; al1 = pal1; efb = pefb;
  }
  if (kg == 0){
#pragma unroll
    for (int n=0;n<4;++n){
      atomicAdd(&bstat[n*16+r16], sacc[n]);
      atomicAdd(&bstat[64+n*16+r16], ssacc[n]);
    }
  }
  __syncthreads();
  if (threadIdx.x < 128) atomicAdd(&slot[threadIdx.x], bstat[threadIdx.x]);
}

// ---- MFMA node-output MLP + fused GraphNorm stats; BN finalize in prologue ----
__global__ void __launch_bounds__(256) node_mfma_k(
    const float* __restrict__ agg, const bf16* __restrict__ right,
    const float* __restrict__ slot, const float* __restrict__ bnw, const float* __restrict__ bnb,
    const unsigned short* __restrict__ W1F, const unsigned short* __restrict__ W2F,
    const float* __restrict__ b1, const float* __restrict__ b2,
    bf16* __restrict__ out, float* __restrict__ gslot, int nn)
{
  __shared__ __align__(16) unsigned short w1l[8192];
  __shared__ __align__(16) unsigned short w2l[4096];
  __shared__ __align__(16) unsigned short h1l[4][16*72];
  __shared__ float bstat[128];
  __shared__ float bnAB[128];
  {
    const float4* s1 = (const float4*)W1F; float4* d1 = (float4*)w1l;
    for (int i=threadIdx.x; i<1024; i+=256) d1[i] = s1[i];
    const float4* s2 = (const float4*)W2F; float4* d2 = (float4*)w2l;
    for (int i=threadIdx.x; i<512; i+=256) d2[i] = s2[i];
    if (threadIdx.x < 128) bstat[threadIdx.x] = 0.f;
    if (threadIdx.x < 64){
      int c = threadIdx.x;
      float m = slot[c]/(float)NCONS, q = slot[64+c]/(float)NCONS;
      float A = rsqrtf(fmaxf(q - m*m, 0.f) + 1e-5f) * bnw[c];
      bnAB[c] = A; bnAB[64+c] = bnb[c] - m*A;
    }
  }
  __syncthreads();
  const short8v* W1v = (const short8v*)w1l;
  const short8v* W2v = (const short8v*)w2l;
  const unsigned short* rgt = (const unsigned short*)right;
  int t = threadIdx.x & 63;
  int wv = threadIdx.x >> 6;
  int gw = (blockIdx.x*blockDim.x + threadIdx.x) >> 6;
  int nw = (gridDim.x*blockDim.x) >> 6;
  int r16 = t & 15, kg = t >> 4;
  float pA0[8], pB0[8], pA1[8], pB1[8];
#pragma unroll
  for (int j=0;j<8;++j){
    pA0[j]=bnAB[kg*8+j];    pB0[j]=bnAB[64+kg*8+j];
    pA1[j]=bnAB[32+kg*8+j]; pB1[j]=bnAB[96+kg*8+j];
  }
  float bb1[4], bb2[4];
#pragma unroll
  for (int n=0;n<4;++n){ bb1[n]=b1[n*16+r16]; bb2[n]=b2[n*16+r16]; }
  unsigned short* h1w = &h1l[wv][0];
  float sacc[4] = {0.f,0.f,0.f,0.f}, ssacc[4] = {0.f,0.f,0.f,0.f};

  for (int g = gw*16; g < nn; g += nw*16){
    int node = g + r16;
    const float* ag = agg + (size_t)node*64;
    float4 f0 = *(const float4*)(ag + kg*8);
    float4 f1 = *(const float4*)(ag + kg*8 + 4);
    float4 f2 = *(const float4*)(ag + 32 + kg*8);
    float4 f3 = *(const float4*)(ag + 32 + kg*8 + 4);
    float v0[8] = {f0.x,f0.y,f0.z,f0.w,f1.x,f1.y,f1.z,f1.w};
    float v1[8] = {f2.x,f2.y,f2.z,f2.w,f3.x,f3.y,f3.z,f3.w};
    short8v ap0, ap1;
#pragma unroll
    for (int j=0;j<8;++j){
      ((unsigned short*)&ap0)[j] = f2b(v0[j]*pA0[j] + pB0[j]);
      ((unsigned short*)&ap1)[j] = f2b(v1[j]*pA1[j] + pB1[j]);
    }
    short8v ar0 = *(const short8v*)(rgt + (size_t)node*64 + kg*8);
    short8v ar1 = *(const short8v*)(rgt + (size_t)node*64 + 32 + kg*8);
    float4v c[4];
#pragma unroll
    for (int n=0;n<4;++n) c[n] = (float4v){bb1[n],bb1[n],bb1[n],bb1[n]};
#pragma unroll
    for (int n=0;n<4;++n){
      c[n] = __builtin_amdgcn_mfma_f32_16x16x32_bf16(ap0, W1v[( 0+n)*64+t], c[n], 0,0,0);
      c[n] = __builtin_amdgcn_mfma_f32_16x16x32_bf16(ap1, W1v[( 4+n)*64+t], c[n], 0,0,0);
      c[n] = __builtin_amdgcn_mfma_f32_16x16x32_bf16(ar0, W1v[( 8+n)*64+t], c[n], 0,0,0);
      c[n] = __builtin_amdgcn_mfma_f32_16x16x32_bf16(ar1, W1v[(12+n)*64+t], c[n], 0,0,0);
    }
#pragma unroll
    for (int n=0;n<4;++n){
#pragma unroll
      for (int r=0;r<4;++r)
        h1w[(kg*4+r)*72 + n*16 + r16] = f2b(fmaxf(c[n][r], 0.f));
    }
    asm volatile("s_waitcnt lgkmcnt(0)" ::: "memory");
    __builtin_amdgcn_sched_barrier(0);
    short8v a20 = *(const short8v*)(h1w + r16*72 + kg*8);
    short8v a21 = *(const short8v*)(h1w + r16*72 + 32 + kg*8);
    float4v d[4];
#pragma unroll
    for (int n=0;n<4;++n) d[n] = (float4v){bb2[n],bb2[n],bb2[n],bb2[n]};
#pragma unroll
    for (int n=0;n<4;++n){
      d[n] = __builtin_amdgcn_mfma_f32_16x16x32_bf16(a20, W2v[(0+n)*64+t], d[n], 0,0,0);
      d[n] = __builtin_amdgcn_mfma_f32_16x16x32_bf16(a21, W2v[(4+n)*64+t], d[n], 0,0,0);
    }
    unsigned short* op = (unsigned short*)out;
#pragma unroll
    for (int r=0;r<4;++r){
      size_t base = (size_t)(g + kg*4 + r)*64 + r16;
#pragma unroll
      for (int n=0;n<4;++n){
        float val = d[n][r];
        op[base + n*16] = f2b(val);
        sacc[n] += val; ssacc[n] += val*val;
      }
    }
  }
#pragma unroll
  for (int n=0;n<4;++n){
    atomicAdd(&bstat[n*16+r16], sacc[n]);
    atomicAdd(&bstat[64+n*16+r16], ssacc[n]);
  }
  __syncthreads();
  if (threadIdx.x < 128) atomicAdd(&gslot[threadIdx.x], bstat[threadIdx.x]);
}

// ---- graphnorm apply on both buffers; GN finalize in prologue ----
__global__ void affine2_k(bf16* __restrict__ x1, const float* __restrict__ s1,
                          bf16* __restrict__ x2, const float* __restrict__ s2,
                          const float* __restrict__ gw, const float* __restrict__ gb,
                          const float* __restrict__ gal, int ga, int gb2, int nn){
  __shared__ float ab[256];
  {
    int tt = threadIdx.x;
    if (tt < 128){
      const float* sl = (tt < 64) ? s1 : s2;
      int g = (tt < 64) ? ga : gb2;
      int c = tt & 63;
      float m = sl[c]/(float)NCONS, q = sl[64+c]/(float)NCONS;
      float a = gal[g*64+c];
      float var = q - 2.f*a*m*m + a*a*m*m;
      float A = rsqrtf(fmaxf(var, 0.f) + 1e-5f) * gw[g*64+c];
      ab[(tt<64?0:128)+c] = A;
      ab[(tt<64?64:192)+c] = gb[g*64+c] - a*m*A;
    }
  }
  __syncthreads();
  int i = blockIdx.x*blockDim.x + threadIdx.x;
  int stride = gridDim.x*blockDim.x;
  int tot = nn*64;
  for (; i<2*tot; i+=stride){
    if (i < tot){
      int c = i & 63;
      x1[i] = __float2bfloat16(b2f(x1[i])*ab[c] + ab[64+c]);
    } else {
      int j = i - tot;
      int c = j & 63;
      x2[j] = __float2bfloat16(b2f(x2[j])*ab[128+c] + ab[192+c]);
    }
  }
}

// ---- MFMA final MLP, race-free; QUARTER-split h1 tile (16x132 f32) ----
__global__ void __launch_bounds__(256) final_mfma_k(
    const bf16* __restrict__ vf0, const bf16* __restrict__ vf1, const bf16* __restrict__ vf2,
    const unsigned short* __restrict__ W1hi, const unsigned short* __restrict__ W1lo,
    const unsigned short* __restrict__ W2hi, const unsigned short* __restrict__ W2lo,
    const float* __restrict__ B1, const float* __restrict__ B2,
    const float* __restrict__ W3, const float* __restrict__ B3,
    void* __restrict__ out, int nn, const int* __restrict__ mode)
{
  __shared__ float h1l[4][16*132];
  const short8v* W1h = (const short8v*)W1hi;
  const short8v* W1l = (const short8v*)W1lo;
  const short8v* W2h = (const short8v*)W2hi;
  const short8v* W2l = (const short8v*)W2lo;
  const unsigned short* v0p = (const unsigned short*)vf0;
  const unsigned short* v1p = (const unsigned short*)vf1;
  const unsigned short* v2p = (const unsigned short*)vf2;
  int t = threadIdx.x & 63;
  int wv = threadIdx.x >> 6;
  int r16 = t & 15, kg = t >> 4;
  int tile = blockIdx.x*4 + wv;
  bool act = (tile*16 < nn);
  int g = act ? tile*16 : 0;
  float* h1w = &h1l[wv][0];
  float b2v[8], w3v[8];
#pragma unroll
  for (int n=0;n<8;++n){ b2v[n] = B2[n*16+r16]; w3v[n] = W3[n*16+r16]; }
  float bb3 = B3[0];
  int md = *mode;

  int node = g + r16;
  short8v A1[6];
  A1[0] = *(const short8v*)(v0p + (size_t)node*64 + kg*8);
  A1[1] = *(const short8v*)(v0p + (size_t)node*64 + 32 + kg*8);
  A1[2] = *(const short8v*)(v1p + (size_t)node*64 + kg*8);
  A1[3] = *(const short8v*)(v1p + (size_t)node*64 + 32 + kg*8);
  A1[4] = *(const short8v*)(v2p + (size_t)node*64 + kg*8);
  A1[5] = *(const short8v*)(v2p + (size_t)node*64 + 32 + kg*8);
  float4v D[8];
#pragma unroll
  for (int n=0;n<8;++n) D[n] = (float4v){b2v[n],b2v[n],b2v[n],b2v[n]};

  for (int quarter=0; quarter<4; ++quarter){
    if (quarter) __syncthreads();
    for (int nt=0; nt<8; ++nt){
      int ntg = quarter*8 + nt;
      float bb = B1[ntg*16 + r16];
      float4v C = (float4v){bb,bb,bb,bb};
#pragma unroll
      for (int kc=0; kc<6; ++kc){
        C = __builtin_amdgcn_mfma_f32_16x16x32_bf16(A1[kc], W1h[(kc*32+ntg)*64+t], C, 0,0,0);
        C = __builtin_amdgcn_mfma_f32_16x16x32_bf16(A1[kc], W1l[(kc*32+ntg)*64+t], C, 0,0,0);
      }
#pragma unroll
      for (int r=0;r<4;++r)
        h1w[(kg*4+r)*132 + nt*16 + r16] = fmaxf(C[r], 0.f);
    }
    __syncthreads();
    short8v Ahi[4], Alo[4];
#pragma unroll
    for (int kc=0; kc<4; ++kc){
      const float* hp = h1w + r16*132 + kc*32 + kg*8;
      float4 x0 = *(const float4*)(hp);
      float4 x1 = *(const float4*)(hp+4);
      float vv[8] = {x0.x,x0.y,x0.z,x0.w,x1.x,x1.y,x1.z,x1.w};
#pragma unroll
      for (int j=0;j<8;++j){
        unsigned short hi = f2b(vv[j]);
        float rec = __builtin_bit_cast(float, (unsigned int)hi<<16);
        ((unsigned short*)&Ahi[kc])[j] = hi;
        ((unsigned short*)&Alo[kc])[j] = f2b(vv[j] - rec);
      }
    }
#pragma unroll
    for (int nt2=0; nt2<8; ++nt2){
#pragma unroll
      for (int kc=0; kc<4; ++kc){
        int kcg = quarter*4 + kc;
        short8v bh = W2h[(kcg*8+nt2)*64+t];
        D[nt2] = __builtin_amdgcn_mfma_f32_16x16x32_bf16(Ahi[kc], bh, D[nt2], 0,0,0);
        D[nt2] = __builtin_amdgcn_mfma_f32_16x16x32_bf16(Alo[kc], bh, D[nt2], 0,0,0);
        D[nt2] = __builtin_amdgcn_mfma_f32_16x16x32_bf16(Ahi[kc], W2l[(kcg*8+nt2)*64+t], D[nt2], 0,0,0);
      }
    }
  }
  float part[4] = {0.f,0.f,0.f,0.f};
#pragma unroll
  for (int n=0;n<8;++n){
#pragma unroll
    for (int r=0;r<4;++r) part[r] += fmaxf(D[n][r],0.f)*w3v[n];
  }
#pragma unroll
  for (int r=0;r<4;++r){
#pragma unroll
    for (int off=1; off<16; off<<=1) part[r] += __shfl_xor(part[r], off, 64);
  }
  if (act && r16==0){
#pragma unroll
    for (int r=0;r<4;++r){
      int node_o = g + kg*4 + r;
      float val = part[r] + bb3;
      if (md) ((bf16*)out)[node_o] = __float2bfloat16(val);
      else    ((float*)out)[node_o] = val;
    }
  }
}

extern "C" void kernel_launch(void* const* d_in, const int* in_sizes, int n_in,
                              void* d_out, int out_size, void* d_ws, size_t ws_size,
                              hipStream_t stream){
  const int* ei = (const int*)d_in[36];

  char* ws = (char*)d_ws;
  float* ST = (float*)ws;                       // 4096 floats = 16 KB
  int* MODE = (int*)(ws + 16384);
  float* FBASE = (float*)(ws + 32768);
  CvtArgs ca;
  float* F[36];
  {
    int off = 0;
    for (int i=0;i<36;++i){
      ca.p[i] = d_in[i];
      ca.ofs[i] = off;
      F[i] = FBASE + off;
      off += in_sizes[i];
    }
    ca.ofs[36] = off;
  }
  unsigned short* W1Fb  = (unsigned short*)(ws + 7u*1024*1024);
  unsigned short* W2Fb  = W1Fb + 4*8192;
  unsigned short* OW1Fb = W2Fb + 4*4096;
  unsigned short* OW2Fb = OW1Fb + 4*8192;
  unsigned short* FW1H  = OW2Fb + 4*4096;
  unsigned short* FW1L  = FW1H + 98304;
  unsigned short* FW2H  = FW1L + 98304;
  unsigned short* FW2L  = FW2H + 65536;
  size_t o = 8u*1024*1024;
  float* AGG = (float*)(ws + o); o += (size_t)NCONS*64*sizeof(float);
  bf16* CFA = (bf16*)(ws + o); o += (size_t)NCONS*64*sizeof(bf16);
  bf16* CFB = (bf16*)(ws + o); o += (size_t)NCONS*64*sizeof(bf16);
  bf16* VF0 = (bf16*)(ws + o); o += (size_t)NVARS*64*sizeof(bf16);
  bf16* VF1 = (bf16*)(ws + o); o += (size_t)NVARS*64*sizeof(bf16);
  bf16* VF2 = (bf16*)(ws + o); o += (size_t)NVARS*64*sizeof(bf16);
  int* CNTCI = (int*)(ws + o); o += (size_t)NCONS*sizeof(int);
  int* CNTVI = (int*)(ws + o); o += (size_t)NVARS*sizeof(int);
  int* OFFC  = (int*)(ws + o); o += (size_t)(NCONS+4)*sizeof(int);
  int* OFFV  = (int*)(ws + o); o += (size_t)(NVARS+4)*sizeof(int);
  int* SRTC  = (int*)(ws + o); o += (size_t)NEDGE*sizeof(int);
  int* SRTV  = (int*)(ws + o); o += (size_t)NEDGE*sizeof(int);
  bf16* EAC  = (bf16*)(ws + o); o += (size_t)NEDGE*sizeof(bf16);
  bf16* EAV  = (bf16*)(ws + o); o += (size_t)NEDGE*sizeof(bf16);

  detect_k<<<1,64,0,stream>>>((const unsigned int*)d_in[0], MODE);
  convert_all_k<<<512,256,0,stream>>>(ca, FBASE, MODE);
  frag_all_k<<<384,256,0,stream>>>(F[17], F[19], F[23], F[25], W1Fb, W2Fb, OW1Fb, OW2Fb);
  frag2_k<<<384,256,0,stream>>>(F[30], FW1H, FW1L, 32, 512, 98304);
  frag2_k<<<256,256,0,stream>>>(F[32], FW2H, FW2L, 8, 128, 65536);

  zero2_k<<<128,256,0,stream>>>(ST, 4096, (float*)CNTCI, NCONS + NVARS);
  hist_k<<<1024,256,0,stream>>>(ei, CNTCI, CNTVI);
  scan2_k<<<2,1024,0,stream>>>(CNTCI, OFFC, NCONS, CNTVI, OFFV, NVARS);
  scat_k<<<1024,256,0,stream>>>(ei, F[1], CNTCI, CNTVI, SRTC, SRTV, EAC, EAV);

  col_stats3_k<<<128,256,0,stream>>>(F[0], F[2], F[1], ST);
  embed2_k<<<1024,256,0,stream>>>(F[0], F[2], ST, F[3], F[4], F[11], F[12],
                                  F[5], F[6], F[7], F[8],
                                  F[13], F[14], F[15], F[16], CFA, VF0);

  const bf16* lefts[4]  = {VF0, CFB, VF1, CFA};
  const bf16* rights[4] = {CFA, VF0, CFB, VF1};
  bf16*       outs[4]   = {CFB, VF1, CFA, VF2};
  const int*  srts[4]   = {SRTC, SRTV, SRTC, SRTV};
  const bf16* eass[4]   = {EAC, EAV, EAC, EAV};
  const int*  offss[4]  = {OFFC, OFFV, OFFC, OFFV};

  for (int l=0; l<4; ++l){
    float* slot = ST + 36 + l*256;
    float* gslot = ST + 36 + 1024 + l*256;
    msg_csr_k<<<1024,256,0,stream>>>(lefts[l], rights[l], srts[l], eass[l],
                                     ST+16, F[9], F[10], offss[l],
                                     W1Fb + l*8192, W2Fb + l*4096,
                                     F[18] + l*64,
                                     F[17] + (size_t)l*129*64 + 64*64,
                                     F[20] + l*64, AGG, slot, NCONS);
    node_mfma_k<<<782,256,0,stream>>>(AGG, rights[l], slot, F[21]+l*64, F[22]+l*64,
                                      OW1Fb + l*8192, OW2Fb + l*4096,
                                      F[24] + l*64, F[26] + l*64, outs[l], gslot, NCONS);
    if (l == 1 || l == 3){
      bf16* cfbuf = outs[l-1];
      bf16* vfbuf = outs[l];
      int ga = l-1, gb = l;
      float* gsA = ST + 36 + 1024 + ga*256;
      float* gsB = ST + 36 + 1024 + gb*256;
      affine2_k<<<1024,256,0,stream>>>(cfbuf, gsA, vfbuf, gsB,
                                       F[27], F[28], F[29], ga, gb, NCONS);
    }
  }
  final_mfma_k<<<782,256,0,stream>>>(VF0, VF1, VF2,
                                     FW1H, FW1L, FW2H, FW2L,
                                     F[31], F[33], F[34], F[35],
                                     d_out, NVARS, MODE);
}